// Round 1
// baseline (7360.161 us; speedup 1.0000x reference)
//
#include <hip/hip_runtime.h>
#include <math.h>

#define TT   1024
#define DD   768
#define HH   12
#define HDIM 64
#define LLAY 6
#define DFFN 3072
#define BB   2
#define NTOK (BB*TT)   // 2048

// ---------------- embedding: x[b,t,:] = tok[idx[b,t]] + pos[t] ----------------
__global__ __launch_bounds__(256) void embed_kernel(const int* __restrict__ idx,
                                                    const float* __restrict__ tok,
                                                    const float* __restrict__ pos,
                                                    float* __restrict__ x) {
    int bt = blockIdx.x;
    int t  = bt % TT;
    int id = idx[bt];
    const float* te = tok + (size_t)id * DD;
    const float* pe = pos + (size_t)t * DD;
    float* xr = x + (size_t)bt * DD;
    for (int d = threadIdx.x; d < DD; d += 256) xr[d] = te[d] + pe[d];
}

// ---------------- layernorm (population var, eps=1e-5) ----------------
__global__ __launch_bounds__(256) void ln_kernel(const float* __restrict__ in,
                                                 const float* __restrict__ g,
                                                 const float* __restrict__ b,
                                                 float* __restrict__ out) {
    int row = blockIdx.x;
    const float* xr = in + (size_t)row * DD;
    float s = 0.f, s2 = 0.f;
    for (int d = threadIdx.x; d < DD; d += 256) { float v = xr[d]; s += v; s2 += v * v; }
    for (int off = 32; off; off >>= 1) { s += __shfl_down(s, off); s2 += __shfl_down(s2, off); }
    __shared__ float aS[4], aS2[4];
    __shared__ float mu_s, rs_s;
    int wid = threadIdx.x >> 6, lane = threadIdx.x & 63;
    if (lane == 0) { aS[wid] = s; aS2[wid] = s2; }
    __syncthreads();
    if (threadIdx.x == 0) {
        float t1 = aS[0] + aS[1] + aS[2] + aS[3];
        float t2 = aS2[0] + aS2[1] + aS2[2] + aS2[3];
        float mu = t1 / (float)DD;
        float var = t2 / (float)DD - mu * mu;
        mu_s = mu; rs_s = rsqrtf(var + 1e-5f);
    }
    __syncthreads();
    float mu = mu_s, rs = rs_s;
    float* orow = out + (size_t)row * DD;
    for (int d = threadIdx.x; d < DD; d += 256)
        orow[d] = (xr[d] - mu) * rs * g[d] + b[d];
}

// ---------------- SGEMM: C = epi(A[M,K] @ B[K,N] + bias) ----------------
// EPI: 0 = plain, 1 = +bias, 2 = +bias +res, 3 = +bias then exact GELU
template<int EPI>
__global__ __launch_bounds__(256) void sgemm_kernel(const float* __restrict__ A,
                                                    const float* __restrict__ B,
                                                    const float* __restrict__ bias,
                                                    const float* __restrict__ res,
                                                    float* __restrict__ C,
                                                    int M, int N, int K) {
    __shared__ float As[16][68];   // [k][m], pad to keep float4 alignment (272B rows)
    __shared__ float Bs[16][68];   // [k][n]
    int bm = blockIdx.y * 64, bn = blockIdx.x * 64;
    int tid = threadIdx.x;
    int tx = tid & 15, ty = tid >> 4;
    float acc[4][4] = {};

    int am = tid >> 2, ak = (tid & 3) * 4;       // A loader: row am, 4 k's
    int bk = tid >> 4, bn4 = (tid & 15) * 4;     // B loader: row bk, 4 n's
    const float* Arow = A + (size_t)(bm + am) * K + ak;
    const float* Brow = B + (size_t)bk * N + bn + bn4;

    for (int k0 = 0; k0 < K; k0 += 16) {
        __syncthreads();
        float4 av = *(const float4*)(Arow + k0);
        As[ak + 0][am] = av.x; As[ak + 1][am] = av.y;
        As[ak + 2][am] = av.z; As[ak + 3][am] = av.w;
        *(float4*)&Bs[bk][bn4] = *(const float4*)(Brow + (size_t)k0 * N);
        __syncthreads();
#pragma unroll
        for (int k = 0; k < 16; ++k) {
            float4 a4 = *(const float4*)&As[k][ty * 4];
            float4 b4 = *(const float4*)&Bs[k][tx * 4];
            float a[4] = {a4.x, a4.y, a4.z, a4.w};
            float bb[4] = {b4.x, b4.y, b4.z, b4.w};
#pragma unroll
            for (int i = 0; i < 4; ++i)
#pragma unroll
                for (int j = 0; j < 4; ++j) acc[i][j] += a[i] * bb[j];
        }
    }
#pragma unroll
    for (int i = 0; i < 4; ++i) {
        int m = bm + ty * 4 + i;
        float* crow = C + (size_t)m * N;
#pragma unroll
        for (int j = 0; j < 4; ++j) {
            int n = bn + tx * 4 + j;
            float v = acc[i][j];
            if (EPI >= 1) v += bias[n];
            if (EPI == 2) v += res[(size_t)m * N + n];
            if (EPI == 3) v = 0.5f * v * (1.f + erff(v * 0.70710678118654752f));
            crow[n] = v;
        }
    }
}

// ---------------- attention: per (b,h), 16 q-rows per block, online softmax ----
// qkv layout: [B*T][2304], Q col = h*64+d, K col = 768+h*64+d, V col = 1536+h*64+d
__global__ __launch_bounds__(256) void attn_kernel(const float* __restrict__ qkv,
                                                   float* __restrict__ o) {
    int bh = blockIdx.y;                 // 0..23
    int b  = bh / HH, h = bh % HH;
    int q0 = blockIdx.x * 16;
    int tid = threadIdx.x;
    int wid = tid >> 6, lane = tid & 63;

    __shared__ float qs[16][65];
    __shared__ float Kc[64][65];
    __shared__ float Vc[64][65];

    const size_t basebt = (size_t)b * TT;

    for (int i = tid; i < 16 * 64; i += 256) {
        int r = i >> 6, d = i & 63;
        qs[r][d] = qkv[(basebt + q0 + r) * 2304 + h * 64 + d] * 0.125f; // 1/sqrt(64)
    }

    float m[4], l[4], acc[4];
#pragma unroll
    for (int r = 0; r < 4; ++r) { m[r] = -1e30f; l[r] = 0.f; acc[r] = 0.f; }

    int qmax = q0 + 15;
    for (int k0 = 0; k0 <= qmax; k0 += 64) {
        __syncthreads();
        for (int i = tid; i < 64 * 64; i += 256) {
            int j = i >> 6, d = i & 63;
            size_t src = (basebt + k0 + j) * 2304 + h * 64 + d;
            Kc[j][d] = qkv[src + 768];
            Vc[j][d] = qkv[src + 1536];
        }
        __syncthreads();
#pragma unroll
        for (int r = 0; r < 4; ++r) {
            int q = q0 + wid * 4 + r;
            if (k0 > q) continue;                 // wave-uniform
            float s = 0.f;
#pragma unroll
            for (int d = 0; d < 64; ++d) s += qs[wid * 4 + r][d] * Kc[lane][d];
            bool masked = (k0 + lane > q);
            if (masked) s = -1e30f;
            float cm = s;
            for (int off = 32; off; off >>= 1) cm = fmaxf(cm, __shfl_xor(cm, off));
            float mn = fmaxf(m[r], cm);
            float sc = __expf(m[r] - mn);
            float p = masked ? 0.f : __expf(s - mn);
            float ps = p;
            for (int off = 32; off; off >>= 1) ps += __shfl_xor(ps, off);
            l[r] = l[r] * sc + ps;
            float a = acc[r] * sc;
            for (int j = 0; j < 64; ++j) {
                float pj = __shfl(p, j);
                a += pj * Vc[j][lane];
            }
            acc[r] = a;
            m[r] = mn;
        }
    }
#pragma unroll
    for (int r = 0; r < 4; ++r) {
        int q = q0 + wid * 4 + r;
        o[(basebt + q) * DD + h * 64 + lane] = acc[r] / l[r];
    }
}

// ---------------- launcher ----------------
extern "C" void kernel_launch(void* const* d_in, const int* in_sizes, int n_in,
                              void* d_out, int out_size, void* d_ws, size_t ws_size,
                              hipStream_t stream) {
    (void)in_sizes; (void)n_in; (void)out_size; (void)ws_size;
    const int*   idx  = (const int*)d_in[0];
    const float* tok  = (const float*)d_in[1];
    const float* pos  = (const float*)d_in[2];
    const float* Wqkv = (const float*)d_in[3];
    const float* bqkv = (const float*)d_in[4];
    const float* Wo   = (const float*)d_in[5];
    const float* bo   = (const float*)d_in[6];
    const float* ln1g = (const float*)d_in[7];
    const float* ln1b = (const float*)d_in[8];
    const float* ln2g = (const float*)d_in[9];
    const float* ln2b = (const float*)d_in[10];
    const float* W1   = (const float*)d_in[11];
    const float* b1   = (const float*)d_in[12];
    const float* W2   = (const float*)d_in[13];
    const float* b2   = (const float*)d_in[14];
    const float* lnfg = (const float*)d_in[15];
    const float* lnfb = (const float*)d_in[16];
    const float* Wlm  = (const float*)d_in[17];
    float* out = (float*)d_out;

    char* ws = (char*)d_ws;
    const size_t XB  = (size_t)NTOK * DD * 4;         // 6,291,456
    float* x     = (float*)(ws);
    float* hbuf  = (float*)(ws + XB);
    float* big   = (float*)(ws + 2 * XB);             // qkv (18.9MB) / ffn1 (25.2MB), never live together
    float* attno = (float*)(ws + 2 * XB + (size_t)NTOK * DFFN * 4);

    embed_kernel<<<NTOK, 256, 0, stream>>>(idx, tok, pos, x);

    for (int l = 0; l < LLAY; ++l) {
        ln_kernel<<<NTOK, 256, 0, stream>>>(x, ln1g + l * DD, ln1b + l * DD, hbuf);
        sgemm_kernel<1><<<dim3(3 * DD / 64, NTOK / 64), 256, 0, stream>>>(
            hbuf, Wqkv + (size_t)l * DD * 3 * DD, bqkv + (size_t)l * 3 * DD, nullptr,
            big, NTOK, 3 * DD, DD);
        attn_kernel<<<dim3(TT / 16, BB * HH), 256, 0, stream>>>(big, attno);
        sgemm_kernel<2><<<dim3(DD / 64, NTOK / 64), 256, 0, stream>>>(
            attno, Wo + (size_t)l * DD * DD, bo + (size_t)l * DD, x,
            x, NTOK, DD, DD);
        ln_kernel<<<NTOK, 256, 0, stream>>>(x, ln2g + l * DD, ln2b + l * DD, hbuf);
        sgemm_kernel<3><<<dim3(DFFN / 64, NTOK / 64), 256, 0, stream>>>(
            hbuf, W1 + (size_t)l * DD * DFFN, b1 + (size_t)l * DFFN, nullptr,
            big, NTOK, DFFN, DD);
        sgemm_kernel<2><<<dim3(DD / 64, NTOK / 64), 256, 0, stream>>>(
            big, W2 + (size_t)l * DFFN * DD, b2 + (size_t)l * DD, x,
            x, NTOK, DD, DFFN);
    }
    ln_kernel<<<NTOK, 256, 0, stream>>>(x, lnfg, lnfb, hbuf);
    sgemm_kernel<0><<<dim3(32000 / 64, NTOK / 64), 256, 0, stream>>>(
        hbuf, Wlm, nullptr, nullptr, out, NTOK, 32000, DD);
}

// Round 2
// 4874.148 us; speedup vs baseline: 1.5100x; 1.5100x over previous
//
#include <hip/hip_runtime.h>
#include <math.h>

#define TT   1024
#define DD   768
#define HH   12
#define LLAY 6
#define DFFN 3072
#define BB   2
#define NTOK (BB*TT)   // 2048

typedef __bf16 bf16;
typedef __attribute__((ext_vector_type(8))) __bf16 bf16x8;
typedef __attribute__((ext_vector_type(4))) __bf16 bf16x4;
typedef __attribute__((ext_vector_type(4))) float f32x4;

// ---------------- embedding ----------------
__global__ __launch_bounds__(256) void embed_kernel(const int* __restrict__ idx,
                                                    const float* __restrict__ tok,
                                                    const float* __restrict__ pos,
                                                    float* __restrict__ x) {
    int bt = blockIdx.x;
    int t  = bt % TT;
    int id = idx[bt];
    const float* te = tok + (size_t)id * DD;
    const float* pe = pos + (size_t)t * DD;
    float* xr = x + (size_t)bt * DD;
    for (int d = threadIdx.x; d < DD; d += 256) xr[d] = te[d] + pe[d];
}

// ---------------- layernorm: f32 in -> bf16 out ----------------
__global__ __launch_bounds__(256) void ln_kernel(const float* __restrict__ in,
                                                 const float* __restrict__ g,
                                                 const float* __restrict__ b,
                                                 bf16* __restrict__ out) {
    int row = blockIdx.x;
    const float* xr = in + (size_t)row * DD;
    float s = 0.f, s2 = 0.f;
    for (int d = threadIdx.x; d < DD; d += 256) { float v = xr[d]; s += v; s2 += v * v; }
    for (int off = 32; off; off >>= 1) { s += __shfl_down(s, off); s2 += __shfl_down(s2, off); }
    __shared__ float aS[4], aS2[4];
    __shared__ float mu_s, rs_s;
    int wid = threadIdx.x >> 6, lane = threadIdx.x & 63;
    if (lane == 0) { aS[wid] = s; aS2[wid] = s2; }
    __syncthreads();
    if (threadIdx.x == 0) {
        float t1 = aS[0] + aS[1] + aS[2] + aS[3];
        float t2 = aS2[0] + aS2[1] + aS2[2] + aS2[3];
        float mu = t1 / (float)DD;
        float var = t2 / (float)DD - mu * mu;
        mu_s = mu; rs_s = rsqrtf(var + 1e-5f);
    }
    __syncthreads();
    float mu = mu_s, rs = rs_s;
    bf16* orow = out + (size_t)row * DD;
    for (int d = threadIdx.x; d < DD; d += 256)
        orow[d] = (bf16)((xr[d] - mu) * rs * g[d] + b[d]);
}

// ---------------- weight transpose+convert: f32 [K][N] -> bf16 [N][K] ----------
__global__ __launch_bounds__(256) void convT_kernel(const float* __restrict__ in,
                                                    bf16* __restrict__ out,
                                                    int K, int N) {
    __shared__ float tile[32][33];
    int n0 = blockIdx.x * 32, k0 = blockIdx.y * 32;
    int tn = threadIdx.x & 31, tk = threadIdx.x >> 5;   // tk 0..7
#pragma unroll
    for (int i = 0; i < 4; ++i)
        tile[tk + i * 8][tn] = in[(size_t)(k0 + tk + i * 8) * N + n0 + tn];
    __syncthreads();
#pragma unroll
    for (int i = 0; i < 4; ++i)
        out[(size_t)(n0 + tk + i * 8) * K + k0 + tn] = (bf16)tile[tn][tk + i * 8];
}

// ---------------- bf16 MFMA GEMM: C = epi(A[M,K] @ Bt[N,K]^T + bias) ----------
// EPI: 0 = plain f32 out, 1 = +bias bf16 out, 2 = +bias +res(f32) f32 out, 3 = +bias GELU bf16 out
template<int BM, int EPI>
__global__ __launch_bounds__(256) void mgemm(const bf16* __restrict__ A,
                                             const bf16* __restrict__ Bt,
                                             const float* __restrict__ bias,
                                             const float* __restrict__ res,
                                             void* __restrict__ Cout,
                                             int M, int N, int K) {
    constexpr int MF = BM / 32;       // M frags per wave (wave tile BM/2 x 64)
    constexpr int NF = 4;
    constexpr int AIT = BM / 64;      // A staging iterations
    __shared__ bf16 As[BM * 32];
    __shared__ bf16 Bs[128 * 32];
    int bm = blockIdx.y * BM, bn = blockIdx.x * 128;
    int tid = threadIdx.x;
    int lane = tid & 63;
    int wid = tid >> 6;
    int wr = wid >> 1, wc = wid & 1;

    f32x4 acc[MF][NF];
#pragma unroll
    for (int m = 0; m < MF; ++m)
#pragma unroll
        for (int n = 0; n < NF; ++n) acc[m][n] = (f32x4){0.f, 0.f, 0.f, 0.f};

    int srow = tid >> 2, skoff = (tid & 3) * 8;
    const bf16* Ag = A + (size_t)(bm + srow) * K + skoff;
    const bf16* Bg = Bt + (size_t)(bn + srow) * K + skoff;

    uint4 ra[AIT], rb[2];
#pragma unroll
    for (int it = 0; it < AIT; ++it) ra[it] = *(const uint4*)(Ag + (size_t)it * 64 * K);
    rb[0] = *(const uint4*)(Bg);
    rb[1] = *(const uint4*)(Bg + (size_t)64 * K);

    int l15 = lane & 15, kq = (lane >> 4) * 8;

    for (int k0 = 0; k0 < K; k0 += 32) {
        __syncthreads();
#pragma unroll
        for (int it = 0; it < AIT; ++it)
            *(uint4*)&As[(it * 64 + srow) * 32 + skoff] = ra[it];
        *(uint4*)&Bs[srow * 32 + skoff] = rb[0];
        *(uint4*)&Bs[(64 + srow) * 32 + skoff] = rb[1];
        __syncthreads();
        int kn = k0 + 32;
        if (kn < K) {
#pragma unroll
            for (int it = 0; it < AIT; ++it) ra[it] = *(const uint4*)(Ag + (size_t)it * 64 * K + kn);
            rb[0] = *(const uint4*)(Bg + kn);
            rb[1] = *(const uint4*)(Bg + (size_t)64 * K + kn);
        }
        bf16x8 af[MF], bfv[NF];
#pragma unroll
        for (int m = 0; m < MF; ++m)
            af[m] = *(const bf16x8*)&As[(wr * (BM / 2) + m * 16 + l15) * 32 + kq];
#pragma unroll
        for (int n = 0; n < NF; ++n)
            bfv[n] = *(const bf16x8*)&Bs[(wc * 64 + n * 16 + l15) * 32 + kq];
#pragma unroll
        for (int m = 0; m < MF; ++m)
#pragma unroll
            for (int n = 0; n < NF; ++n)
                acc[m][n] = __builtin_amdgcn_mfma_f32_16x16x32_bf16(af[m], bfv[n], acc[m][n], 0, 0, 0);
    }

    int lq = (lane >> 4) * 4;
#pragma unroll
    for (int m = 0; m < MF; ++m) {
#pragma unroll
        for (int n = 0; n < NF; ++n) {
            int col = bn + wc * 64 + n * 16 + l15;
            float bv = (EPI >= 1) ? bias[col] : 0.f;
#pragma unroll
            for (int j = 0; j < 4; ++j) {
                int row = bm + wr * (BM / 2) + m * 16 + lq + j;
                float v = acc[m][n][j] + bv;
                if (EPI == 2) {
                    ((float*)Cout)[(size_t)row * N + col] = v + res[(size_t)row * N + col];
                } else if (EPI == 3) {
                    v = 0.5f * v * (1.f + erff(v * 0.70710678118654752f));
                    ((bf16*)Cout)[(size_t)row * N + col] = (bf16)v;
                } else if (EPI == 1) {
                    ((bf16*)Cout)[(size_t)row * N + col] = (bf16)v;
                } else {
                    ((float*)Cout)[(size_t)row * N + col] = v;
                }
            }
        }
    }
}

// ---------------- attention: bf16 qkv in, bf16 o out, f32 math ----------------
__global__ __launch_bounds__(256) void attn_kernel(const bf16* __restrict__ qkv,
                                                   bf16* __restrict__ o) {
    int bh = blockIdx.y;
    int b  = bh / HH, h = bh % HH;
    int q0 = blockIdx.x * 16;
    int tid = threadIdx.x;
    int wid = tid >> 6, lane = tid & 63;

    __shared__ float qs[16][65];
    __shared__ float Kc[64][65];
    __shared__ float Vc[64][65];

    const size_t basebt = (size_t)b * TT;

    {
        int r = tid >> 4, d4 = (tid & 15) * 4;
        bf16x4 v = *(const bf16x4*)&qkv[(basebt + q0 + r) * 2304 + h * 64 + d4];
#pragma unroll
        for (int j = 0; j < 4; ++j) qs[r][d4 + j] = (float)v[j] * 0.125f;
    }

    float m[4], l[4], acc[4];
#pragma unroll
    for (int r = 0; r < 4; ++r) { m[r] = -1e30f; l[r] = 0.f; acc[r] = 0.f; }

    int qmax = q0 + 15;
    for (int k0 = 0; k0 <= qmax; k0 += 64) {
        __syncthreads();
        for (int i = tid; i < 64 * 16; i += 256) {
            int j = i >> 4, d4 = (i & 15) * 4;
            size_t src = (basebt + k0 + j) * 2304 + h * 64 + d4;
            bf16x4 kv = *(const bf16x4*)&qkv[src + 768];
            bf16x4 vv = *(const bf16x4*)&qkv[src + 1536];
#pragma unroll
            for (int jj = 0; jj < 4; ++jj) {
                Kc[j][d4 + jj] = (float)kv[jj];
                Vc[j][d4 + jj] = (float)vv[jj];
            }
        }
        __syncthreads();
#pragma unroll
        for (int r = 0; r < 4; ++r) {
            int q = q0 + wid * 4 + r;
            if (k0 > q) continue;
            float s = 0.f;
#pragma unroll
            for (int d = 0; d < 64; ++d) s += qs[wid * 4 + r][d] * Kc[lane][d];
            bool masked = (k0 + lane > q);
            if (masked) s = -1e30f;
            float cm = s;
            for (int off = 32; off; off >>= 1) cm = fmaxf(cm, __shfl_xor(cm, off));
            float mn = fmaxf(m[r], cm);
            float sc = __expf(m[r] - mn);
            float p = masked ? 0.f : __expf(s - mn);
            float ps = p;
            for (int off = 32; off; off >>= 1) ps += __shfl_xor(ps, off);
            l[r] = l[r] * sc + ps;
            float a = acc[r] * sc;
            for (int j = 0; j < 64; ++j) {
                float pj = __shfl(p, j);
                a += pj * Vc[j][lane];
            }
            acc[r] = a;
            m[r] = mn;
        }
    }
#pragma unroll
    for (int r = 0; r < 4; ++r) {
        int q = q0 + wid * 4 + r;
        o[(basebt + q) * DD + h * 64 + lane] = (bf16)(acc[r] / l[r]);
    }
}

// ---------------- launcher ----------------
extern "C" void kernel_launch(void* const* d_in, const int* in_sizes, int n_in,
                              void* d_out, int out_size, void* d_ws, size_t ws_size,
                              hipStream_t stream) {
    (void)in_sizes; (void)n_in; (void)out_size; (void)ws_size;
    const int*   idx  = (const int*)d_in[0];
    const float* tok  = (const float*)d_in[1];
    const float* pos  = (const float*)d_in[2];
    const float* Wqkv = (const float*)d_in[3];
    const float* bqkv = (const float*)d_in[4];
    const float* Wo   = (const float*)d_in[5];
    const float* bo   = (const float*)d_in[6];
    const float* ln1g = (const float*)d_in[7];
    const float* ln1b = (const float*)d_in[8];
    const float* ln2g = (const float*)d_in[9];
    const float* ln2b = (const float*)d_in[10];
    const float* W1   = (const float*)d_in[11];
    const float* b1   = (const float*)d_in[12];
    const float* W2   = (const float*)d_in[13];
    const float* b2   = (const float*)d_in[14];
    const float* lnfg = (const float*)d_in[15];
    const float* lnfb = (const float*)d_in[16];
    const float* Wlm  = (const float*)d_in[17];
    float* out = (float*)d_out;

    char* ws = (char*)d_ws;
    float* x     = (float*)(ws);                                   // 6,291,456 B
    bf16*  abuf0 = (bf16*)(ws + 6291456);                          // 12,582,912 B
    bf16*  abuf1 = (bf16*)(ws + 6291456 + 12582912);               // 12,582,912 B
    bf16*  qkvb  = (bf16*)(ws + 6291456 + 2 * 12582912);           // 9,437,184 B
    bf16*  wbuf  = (bf16*)(ws + 6291456 + 2 * 12582912 + 9437184); // 49,152,000 B

    embed_kernel<<<NTOK, 256, 0, stream>>>(idx, tok, pos, x);

    for (int l = 0; l < LLAY; ++l) {
        ln_kernel<<<NTOK, 256, 0, stream>>>(x, ln1g + l * DD, ln1b + l * DD, abuf0);
        convT_kernel<<<dim3(3 * DD / 32, DD / 32), 256, 0, stream>>>(
            Wqkv + (size_t)l * DD * 3 * DD, wbuf, DD, 3 * DD);
        mgemm<128, 1><<<dim3(3 * DD / 128, NTOK / 128), 256, 0, stream>>>(
            abuf0, wbuf, bqkv + (size_t)l * 3 * DD, nullptr, qkvb, NTOK, 3 * DD, DD);
        attn_kernel<<<dim3(TT / 16, BB * HH), 256, 0, stream>>>(qkvb, abuf0);
        convT_kernel<<<dim3(DD / 32, DD / 32), 256, 0, stream>>>(
            Wo + (size_t)l * DD * DD, wbuf, DD, DD);
        mgemm<64, 2><<<dim3(DD / 128, NTOK / 64), 256, 0, stream>>>(
            abuf0, wbuf, bo + (size_t)l * DD, x, x, NTOK, DD, DD);
        ln_kernel<<<NTOK, 256, 0, stream>>>(x, ln2g + l * DD, ln2b + l * DD, abuf0);
        convT_kernel<<<dim3(DFFN / 32, DD / 32), 256, 0, stream>>>(
            W1 + (size_t)l * DD * DFFN, wbuf, DD, DFFN);
        mgemm<128, 3><<<dim3(DFFN / 128, NTOK / 128), 256, 0, stream>>>(
            abuf0, wbuf, b1 + (size_t)l * DFFN, nullptr, abuf1, NTOK, DFFN, DD);
        convT_kernel<<<dim3(DD / 32, DFFN / 32), 256, 0, stream>>>(
            W2 + (size_t)l * DFFN * DD, wbuf, DFFN, DD);
        mgemm<64, 2><<<dim3(DD / 128, NTOK / 64), 256, 0, stream>>>(
            abuf1, wbuf, b2 + (size_t)l * DD, x, x, NTOK, DD, DFFN);
    }
    ln_kernel<<<NTOK, 256, 0, stream>>>(x, lnfg, lnfb, abuf0);
    convT_kernel<<<dim3(32000 / 32, DD / 32), 256, 0, stream>>>(Wlm, wbuf, DD, 32000);
    mgemm<128, 0><<<dim3(32000 / 128, NTOK / 128), 256, 0, stream>>>(
        abuf0, wbuf, nullptr, nullptr, out, NTOK, 32000, DD);
}

// Round 3
// 2252.267 us; speedup vs baseline: 3.2679x; 2.1641x over previous
//
#include <hip/hip_runtime.h>
#include <math.h>

#define TT   1024
#define DD   768
#define HH   12
#define LLAY 6
#define DFFN 3072
#define BB   2
#define NTOK (BB*TT)   // 2048

typedef __bf16 bf16;
typedef __attribute__((ext_vector_type(8))) __bf16 bf16x8;
typedef __attribute__((ext_vector_type(4))) __bf16 bf16x4;
typedef __attribute__((ext_vector_type(4))) float f32x4;

__device__ inline unsigned pack_bf16x2(float a, float b) {
    union { bf16 h[2]; unsigned u; } un;
    un.h[0] = (bf16)a; un.h[1] = (bf16)b;
    return un.u;
}

// ---------------- embedding ----------------
__global__ __launch_bounds__(256) void embed_kernel(const int* __restrict__ idx,
                                                    const float* __restrict__ tok,
                                                    const float* __restrict__ pos,
                                                    float* __restrict__ x) {
    int bt = blockIdx.x;
    int t  = bt % TT;
    int id = idx[bt];
    const float* te = tok + (size_t)id * DD;
    const float* pe = pos + (size_t)t * DD;
    float* xr = x + (size_t)bt * DD;
    for (int d = threadIdx.x; d < DD; d += 256) xr[d] = te[d] + pe[d];
}

// ---------------- layernorm: f32 in -> bf16 out ----------------
__global__ __launch_bounds__(256) void ln_kernel(const float* __restrict__ in,
                                                 const float* __restrict__ g,
                                                 const float* __restrict__ b,
                                                 bf16* __restrict__ out) {
    int row = blockIdx.x;
    const float* xr = in + (size_t)row * DD;
    float s = 0.f, s2 = 0.f;
    for (int d = threadIdx.x; d < DD; d += 256) { float v = xr[d]; s += v; s2 += v * v; }
    for (int off = 32; off; off >>= 1) { s += __shfl_down(s, off); s2 += __shfl_down(s2, off); }
    __shared__ float aS[4], aS2[4];
    __shared__ float mu_s, rs_s;
    int wid = threadIdx.x >> 6, lane = threadIdx.x & 63;
    if (lane == 0) { aS[wid] = s; aS2[wid] = s2; }
    __syncthreads();
    if (threadIdx.x == 0) {
        float t1 = aS[0] + aS[1] + aS[2] + aS[3];
        float t2 = aS2[0] + aS2[1] + aS2[2] + aS2[3];
        float mu = t1 / (float)DD;
        float var = t2 / (float)DD - mu * mu;
        mu_s = mu; rs_s = rsqrtf(var + 1e-5f);
    }
    __syncthreads();
    float mu = mu_s, rs = rs_s;
    bf16* orow = out + (size_t)row * DD;
    for (int d = threadIdx.x; d < DD; d += 256)
        orow[d] = (bf16)((xr[d] - mu) * rs * g[d] + b[d]);
}

// ---------------- weight transpose+convert: f32 [K][N] -> bf16 [N][K] ----------
__global__ __launch_bounds__(256) void convT_kernel(const float* __restrict__ in,
                                                    bf16* __restrict__ out,
                                                    int K, int N) {
    __shared__ float tile[32][33];
    int n0 = blockIdx.x * 32, k0 = blockIdx.y * 32;
    int tn = threadIdx.x & 31, tk = threadIdx.x >> 5;   // tk 0..7
#pragma unroll
    for (int i = 0; i < 4; ++i)
        tile[tk + i * 8][tn] = in[(size_t)(k0 + tk + i * 8) * N + n0 + tn];
    __syncthreads();
#pragma unroll
    for (int i = 0; i < 4; ++i)
        out[(size_t)(n0 + tk + i * 8) * K + k0 + tn] = (bf16)tile[tn][tk + i * 8];
}

// ---------------- bf16 MFMA GEMM: C = epi(A[M,K] @ Bt[N,K]^T + bias) ----------
// EPI: 0 plain f32; 1 +bias bf16; 2 +bias+res f32; 3 +bias GELU bf16;
//      4 qkv: Q cols (<768) scaled 0.125 bf16, K cols bf16, V cols -> vtout transposed
template<int BM, int EPI>
__global__ __launch_bounds__(256) void mgemm(const bf16* __restrict__ A,
                                             const bf16* __restrict__ Bt,
                                             const float* __restrict__ bias,
                                             const float* __restrict__ res,
                                             void* __restrict__ Cout,
                                             bf16* __restrict__ vtout,
                                             int M, int N, int K) {
    constexpr int MF = BM / 32;
    constexpr int NF = 4;
    constexpr int AIT = BM / 64;
    __shared__ bf16 As[BM * 32];
    __shared__ bf16 Bs[128 * 32];
    int bm = blockIdx.y * BM, bn = blockIdx.x * 128;
    int tid = threadIdx.x;
    int lane = tid & 63;
    int wid = tid >> 6;
    int wr = wid >> 1, wc = wid & 1;

    f32x4 acc[MF][NF];
#pragma unroll
    for (int m = 0; m < MF; ++m)
#pragma unroll
        for (int n = 0; n < NF; ++n) acc[m][n] = (f32x4){0.f, 0.f, 0.f, 0.f};

    int srow = tid >> 2, skoff = (tid & 3) * 8;
    const bf16* Ag = A + (size_t)(bm + srow) * K + skoff;
    const bf16* Bg = Bt + (size_t)(bn + srow) * K + skoff;

    uint4 ra[AIT], rb[2];
#pragma unroll
    for (int it = 0; it < AIT; ++it) ra[it] = *(const uint4*)(Ag + (size_t)it * 64 * K);
    rb[0] = *(const uint4*)(Bg);
    rb[1] = *(const uint4*)(Bg + (size_t)64 * K);

    int l15 = lane & 15, kq = (lane >> 4) * 8;

    for (int k0 = 0; k0 < K; k0 += 32) {
        __syncthreads();
#pragma unroll
        for (int it = 0; it < AIT; ++it)
            *(uint4*)&As[(it * 64 + srow) * 32 + skoff] = ra[it];
        *(uint4*)&Bs[srow * 32 + skoff] = rb[0];
        *(uint4*)&Bs[(64 + srow) * 32 + skoff] = rb[1];
        __syncthreads();
        int kn = k0 + 32;
        if (kn < K) {
#pragma unroll
            for (int it = 0; it < AIT; ++it) ra[it] = *(const uint4*)(Ag + (size_t)it * 64 * K + kn);
            rb[0] = *(const uint4*)(Bg + kn);
            rb[1] = *(const uint4*)(Bg + (size_t)64 * K + kn);
        }
        bf16x8 af[MF], bfv[NF];
#pragma unroll
        for (int m = 0; m < MF; ++m)
            af[m] = *(const bf16x8*)&As[(wr * (BM / 2) + m * 16 + l15) * 32 + kq];
#pragma unroll
        for (int n = 0; n < NF; ++n)
            bfv[n] = *(const bf16x8*)&Bs[(wc * 64 + n * 16 + l15) * 32 + kq];
#pragma unroll
        for (int m = 0; m < MF; ++m)
#pragma unroll
            for (int n = 0; n < NF; ++n)
                acc[m][n] = __builtin_amdgcn_mfma_f32_16x16x32_bf16(af[m], bfv[n], acc[m][n], 0, 0, 0);
    }

    int lq = (lane >> 4) * 4;
#pragma unroll
    for (int m = 0; m < MF; ++m) {
#pragma unroll
        for (int n = 0; n < NF; ++n) {
            int col = bn + wc * 64 + n * 16 + l15;
            float bv = (EPI >= 1) ? bias[col] : 0.f;
            if (EPI == 4 && col >= 2 * DD) {
                // V columns: transposed pack store to vtout[b*768 + (col-1536)][t]
                int row0 = bm + wr * (BM / 2) + m * 16 + lq;
                int b = row0 >> 10, t0 = row0 & 1023;
                int hd = col - 2 * DD;
                union { bf16 h[4]; unsigned long long u; } pk;
#pragma unroll
                for (int j = 0; j < 4; ++j) pk.h[j] = (bf16)(acc[m][n][j] + bv);
                *(unsigned long long*)&vtout[((size_t)(b * DD + hd)) * TT + t0] = pk.u;
            } else {
#pragma unroll
                for (int j = 0; j < 4; ++j) {
                    int row = bm + wr * (BM / 2) + m * 16 + lq + j;
                    float v = acc[m][n][j] + bv;
                    if (EPI == 2) {
                        ((float*)Cout)[(size_t)row * N + col] = v + res[(size_t)row * N + col];
                    } else if (EPI == 3) {
                        v = 0.5f * v * (1.f + erff(v * 0.70710678118654752f));
                        ((bf16*)Cout)[(size_t)row * N + col] = (bf16)v;
                    } else if (EPI == 1) {
                        ((bf16*)Cout)[(size_t)row * N + col] = (bf16)v;
                    } else if (EPI == 4) {
                        if (col < DD) v *= 0.125f;   // pre-scale Q by 1/sqrt(64)
                        ((bf16*)Cout)[(size_t)row * N + col] = (bf16)v;
                    } else {
                        ((float*)Cout)[(size_t)row * N + col] = v;
                    }
                }
            }
        }
    }
}

// ---------------- MFMA flash attention ----------------
// qkv: [2048][2304] bf16 (Q prescaled by 0.125), vt: [B*D][T] = [b*768+h*64+d][t]
// out: [2048][768] bf16
__global__ __launch_bounds__(256) void fattn_kernel(const bf16* __restrict__ qkv,
                                                    const bf16* __restrict__ vt,
                                                    bf16* __restrict__ o) {
    const int bh = blockIdx.y;           // 0..23
    const int b = bh / HH, h = bh % HH;
    const int q0 = blockIdx.x * 64;
    const int tid = threadIdx.x;
    const int w = tid >> 6, lane = tid & 63;
    const int l15 = lane & 15, g = lane >> 4;

    __shared__ __align__(16) bf16 Ks[64 * 64];      // [k][d], XOR-swizzled 128B rows
    __shared__ __align__(16) bf16 Vs[64 * 64];      // [d][k], XOR-swizzled
    __shared__ __align__(16) bf16 Ps[4][16 * 64];   // per-wave P[q][k], XOR-swizzled

    const size_t basebt = (size_t)b * TT;
    const int qw = q0 + w * 16;
    const int qg = qw + l15;             // this lane's softmax-state row

    bf16x8 bq0, bq1;
    {
        const bf16* qp = qkv + (basebt + qw + l15) * 2304 + h * 64 + g * 8;
        bq0 = *(const bf16x8*)(qp);
        bq1 = *(const bf16x8*)(qp + 32);
    }

    float mstate = -1e30f, lstate = 0.f;
    f32x4 oacc[4];
#pragma unroll
    for (int nf = 0; nf < 4; ++nf) oacc[nf] = (f32x4){0.f, 0.f, 0.f, 0.f};

    const int swzA = (l15 & 7) << 4;     // read-side XOR (row = l15 + 16*frag)
    char* const psBase = (char*)&Ps[w][0];

    const int nchunk = blockIdx.x + 1;
    for (int c = 0; c < nchunk; ++c) {
        const int kc = c * 64;
        __syncthreads();
        {   // stage K[k][d] and Vt[d][k] chunks (XOR-swizzled b128 writes)
            int r0 = tid >> 3;            // 0..31
            int e0 = (tid & 7) * 8;
#pragma unroll
            for (int i = 0; i < 2; ++i) {
                int r = r0 + 32 * i;
                int swzW = (r & 7) << 4;
                bf16x8 kv = *(const bf16x8*)&qkv[(basebt + kc + r) * 2304 + DD + h * 64 + e0];
                *(bf16x8*)((char*)Ks + r * 128 + ((e0 * 2) ^ swzW)) = kv;
                bf16x8 vv = *(const bf16x8*)&vt[((size_t)bh * 64 + r) * TT + kc + e0];
                *(bf16x8*)((char*)Vs + r * 128 + ((e0 * 2) ^ swzW)) = vv;
            }
        }
        __syncthreads();
        if (kc > qw + 15) continue;      // wave-uniform skip (above diagonal)

        // S^T[k][q] = K · Q^T   (4 m-frags of k, 2 k-slices of d)
        f32x4 s[4];
#pragma unroll
        for (int mf = 0; mf < 4; ++mf) {
            char* kr = (char*)Ks + (16 * mf + l15) * 128;
            bf16x8 ka0 = *(const bf16x8*)(kr + ((16 * g) ^ swzA));
            bf16x8 ka1 = *(const bf16x8*)(kr + ((64 + 16 * g) ^ swzA));
            f32x4 a = (f32x4){0.f, 0.f, 0.f, 0.f};
            a = __builtin_amdgcn_mfma_f32_16x16x32_bf16(ka0, bq0, a, 0, 0, 0);
            a = __builtin_amdgcn_mfma_f32_16x16x32_bf16(ka1, bq1, a, 0, 0, 0);
            s[mf] = a;
        }
        if (kc + 63 > qw) {              // diagonal chunk: causal mask
#pragma unroll
            for (int mf = 0; mf < 4; ++mf)
#pragma unroll
                for (int j = 0; j < 4; ++j)
                    if (kc + 16 * mf + 4 * g + j > qg) s[mf][j] = -1e30f;
        }
        // online softmax (state per q = l15, lane-local)
        float cm = -1e30f;
#pragma unroll
        for (int mf = 0; mf < 4; ++mf)
#pragma unroll
            for (int j = 0; j < 4; ++j) cm = fmaxf(cm, s[mf][j]);
        cm = fmaxf(cm, __shfl_xor(cm, 16));
        cm = fmaxf(cm, __shfl_xor(cm, 32));
        float mnew = fmaxf(mstate, cm);
        float sc = __expf(mstate - mnew);
        mstate = mnew;
        float p[4][4];
        float psum = 0.f;
#pragma unroll
        for (int mf = 0; mf < 4; ++mf)
#pragma unroll
            for (int j = 0; j < 4; ++j) { float pv = __expf(s[mf][j] - mnew); p[mf][j] = pv; psum += pv; }
        psum += __shfl_xor(psum, 16);
        psum += __shfl_xor(psum, 32);
        lstate = lstate * sc + psum;
        // write P[q=l15][k] to per-wave LDS (bf16, swizzled)
#pragma unroll
        for (int mf = 0; mf < 4; ++mf) {
            unsigned lo = pack_bf16x2(p[mf][0], p[mf][1]);
            unsigned hi = pack_bf16x2(p[mf][2], p[mf][3]);
            char* dst = psBase + l15 * 128 + ((32 * mf + 8 * g) ^ swzA);
            *(unsigned*)dst = lo;
            *(unsigned*)(dst + 4) = hi;
        }
        // rescale O rows (row q' = 4g+j owned scale lives at lane 4g+j)
        float s0 = __shfl(sc, 4 * g + 0), s1 = __shfl(sc, 4 * g + 1);
        float s2 = __shfl(sc, 4 * g + 2), s3 = __shfl(sc, 4 * g + 3);
#pragma unroll
        for (int nf = 0; nf < 4; ++nf) {
            oacc[nf][0] *= s0; oacc[nf][1] *= s1; oacc[nf][2] *= s2; oacc[nf][3] *= s3;
        }
        // PV: O[q][d] += P · V
        bf16x8 pa0 = *(const bf16x8*)(psBase + l15 * 128 + ((16 * g) ^ swzA));
        bf16x8 pa1 = *(const bf16x8*)(psBase + l15 * 128 + ((64 + 16 * g) ^ swzA));
#pragma unroll
        for (int nf = 0; nf < 4; ++nf) {
            char* vr = (char*)Vs + (16 * nf + l15) * 128;
            bf16x8 vb0 = *(const bf16x8*)(vr + ((16 * g) ^ swzA));
            bf16x8 vb1 = *(const bf16x8*)(vr + ((64 + 16 * g) ^ swzA));
            oacc[nf] = __builtin_amdgcn_mfma_f32_16x16x32_bf16(pa0, vb0, oacc[nf], 0, 0, 0);
            oacc[nf] = __builtin_amdgcn_mfma_f32_16x16x32_bf16(pa1, vb1, oacc[nf], 0, 0, 0);
        }
    }
    // epilogue: divide by l, write O
    float linv = 1.f / lstate;
    float l0 = __shfl(linv, 4 * g + 0), l1 = __shfl(linv, 4 * g + 1);
    float l2 = __shfl(linv, 4 * g + 2), l3 = __shfl(linv, 4 * g + 3);
    float lj[4] = {l0, l1, l2, l3};
#pragma unroll
    for (int j = 0; j < 4; ++j) {
        bf16* orow = o + (size_t)(basebt + qw + 4 * g + j) * DD + h * 64 + l15;
#pragma unroll
        for (int nf = 0; nf < 4; ++nf)
            orow[16 * nf] = (bf16)(oacc[nf][j] * lj[j]);
    }
}

// ---------------- launcher ----------------
extern "C" void kernel_launch(void* const* d_in, const int* in_sizes, int n_in,
                              void* d_out, int out_size, void* d_ws, size_t ws_size,
                              hipStream_t stream) {
    (void)in_sizes; (void)n_in; (void)out_size; (void)ws_size;
    const int*   idx  = (const int*)d_in[0];
    const float* tok  = (const float*)d_in[1];
    const float* pos  = (const float*)d_in[2];
    const float* Wqkv = (const float*)d_in[3];
    const float* bqkv = (const float*)d_in[4];
    const float* Wo   = (const float*)d_in[5];
    const float* bo   = (const float*)d_in[6];
    const float* ln1g = (const float*)d_in[7];
    const float* ln1b = (const float*)d_in[8];
    const float* ln2g = (const float*)d_in[9];
    const float* ln2b = (const float*)d_in[10];
    const float* W1   = (const float*)d_in[11];
    const float* b1   = (const float*)d_in[12];
    const float* W2   = (const float*)d_in[13];
    const float* b2   = (const float*)d_in[14];
    const float* lnfg = (const float*)d_in[15];
    const float* lnfb = (const float*)d_in[16];
    const float* Wlm  = (const float*)d_in[17];
    float* out = (float*)d_out;

    char* ws = (char*)d_ws;
    float* x     = (float*)(ws);                       // 6,291,456
    bf16*  abuf0 = (bf16*)(ws + 6291456);              // 3,145,728  (ln out / attn out)
    bf16*  abuf1 = (bf16*)(ws + 9437184);              // 12,582,912 (ffn1 out)
    bf16*  qkvb  = (bf16*)(ws + 22020096);             // 9,437,184
    bf16*  vtb   = (bf16*)(ws + 31457280);             // 3,145,728
    bf16*  wbuf  = (bf16*)(ws + 34603008);             // 49,152,000

    embed_kernel<<<NTOK, 256, 0, stream>>>(idx, tok, pos, x);

    for (int l = 0; l < LLAY; ++l) {
        ln_kernel<<<NTOK, 256, 0, stream>>>(x, ln1g + l * DD, ln1b + l * DD, abuf0);
        convT_kernel<<<dim3(3 * DD / 32, DD / 32), 256, 0, stream>>>(
            Wqkv + (size_t)l * DD * 3 * DD, wbuf, DD, 3 * DD);
        mgemm<128, 4><<<dim3(3 * DD / 128, NTOK / 128), 256, 0, stream>>>(
            abuf0, wbuf, bqkv + (size_t)l * 3 * DD, nullptr, qkvb, vtb, NTOK, 3 * DD, DD);
        fattn_kernel<<<dim3(TT / 64, BB * HH), 256, 0, stream>>>(qkvb, vtb, abuf0);
        convT_kernel<<<dim3(DD / 32, DD / 32), 256, 0, stream>>>(
            Wo + (size_t)l * DD * DD, wbuf, DD, DD);
        mgemm<64, 2><<<dim3(DD / 128, NTOK / 64), 256, 0, stream>>>(
            abuf0, wbuf, bo + (size_t)l * DD, x, x, nullptr, NTOK, DD, DD);
        ln_kernel<<<NTOK, 256, 0, stream>>>(x, ln2g + l * DD, ln2b + l * DD, abuf0);
        convT_kernel<<<dim3(DFFN / 32, DD / 32), 256, 0, stream>>>(
            W1 + (size_t)l * DD * DFFN, wbuf, DD, DFFN);
        mgemm<128, 3><<<dim3(DFFN / 128, NTOK / 128), 256, 0, stream>>>(
            abuf0, wbuf, b1 + (size_t)l * DFFN, nullptr, abuf1, nullptr, NTOK, DFFN, DD);
        convT_kernel<<<dim3(DD / 32, DFFN / 32), 256, 0, stream>>>(
            W2 + (size_t)l * DFFN * DD, wbuf, DFFN, DD);
        mgemm<64, 2><<<dim3(DD / 128, NTOK / 64), 256, 0, stream>>>(
            abuf1, wbuf, b2 + (size_t)l * DD, x, x, nullptr, NTOK, DD, DFFN);
    }
    ln_kernel<<<NTOK, 256, 0, stream>>>(x, lnfg, lnfb, abuf0);
    convT_kernel<<<dim3(32000 / 32, DD / 32), 256, 0, stream>>>(Wlm, wbuf, DD, 32000);
    mgemm<128, 0><<<dim3(32000 / 128, NTOK / 128), 256, 0, stream>>>(
        abuf0, wbuf, nullptr, nullptr, out, nullptr, NTOK, 32000, DD);
}

// Round 4
// 1275.579 us; speedup vs baseline: 5.7701x; 1.7657x over previous
//
#include <hip/hip_runtime.h>
#include <math.h>

#define TT   1024
#define DD   768
#define HH   12
#define LLAY 6
#define DFFN 3072
#define BB   2
#define NTOK (BB*TT)   // 2048

typedef __bf16 bf16;
typedef __attribute__((ext_vector_type(8))) __bf16 bf16x8;
typedef __attribute__((ext_vector_type(4))) __bf16 bf16x4;
typedef __attribute__((ext_vector_type(4))) float f32x4;

__device__ inline unsigned pack_bf16x2(float a, float b) {
    union { bf16 h[2]; unsigned u; } un;
    un.h[0] = (bf16)a; un.h[1] = (bf16)b;
    return un.u;
}

// async global->LDS, 16B per lane; LDS dest must be wave-uniform base (+lane*16)
__device__ inline void gload16(const bf16* g, bf16* l) {
    __builtin_amdgcn_global_load_lds((const void*)g, (void*)l, 16, 0, 0);
}

// ---------------- embedding ----------------
__global__ __launch_bounds__(256) void embed_kernel(const int* __restrict__ idx,
                                                    const float* __restrict__ tok,
                                                    const float* __restrict__ pos,
                                                    float* __restrict__ x) {
    int bt = blockIdx.x;
    int t  = bt % TT;
    int id = idx[bt];
    const float* te = tok + (size_t)id * DD;
    const float* pe = pos + (size_t)t * DD;
    float* xr = x + (size_t)bt * DD;
    for (int d = threadIdx.x; d < DD; d += 256) xr[d] = te[d] + pe[d];
}

// ---------------- layernorm: f32 in -> bf16 out ----------------
__global__ __launch_bounds__(256) void ln_kernel(const float* __restrict__ in,
                                                 const float* __restrict__ g,
                                                 const float* __restrict__ b,
                                                 bf16* __restrict__ out) {
    int row = blockIdx.x;
    const float* xr = in + (size_t)row * DD;
    float s = 0.f, s2 = 0.f;
    for (int d = threadIdx.x; d < DD; d += 256) { float v = xr[d]; s += v; s2 += v * v; }
    for (int off = 32; off; off >>= 1) { s += __shfl_down(s, off); s2 += __shfl_down(s2, off); }
    __shared__ float aS[4], aS2[4];
    __shared__ float mu_s, rs_s;
    int wid = threadIdx.x >> 6, lane = threadIdx.x & 63;
    if (lane == 0) { aS[wid] = s; aS2[wid] = s2; }
    __syncthreads();
    if (threadIdx.x == 0) {
        float t1 = aS[0] + aS[1] + aS[2] + aS[3];
        float t2 = aS2[0] + aS2[1] + aS2[2] + aS2[3];
        float mu = t1 / (float)DD;
        float var = t2 / (float)DD - mu * mu;
        mu_s = mu; rs_s = rsqrtf(var + 1e-5f);
    }
    __syncthreads();
    float mu = mu_s, rs = rs_s;
    bf16* orow = out + (size_t)row * DD;
    for (int d = threadIdx.x; d < DD; d += 256)
        orow[d] = (bf16)((xr[d] - mu) * rs * g[d] + b[d]);
}

// ---------------- 32x32 transpose+convert tile helper ----------------
__device__ inline void convT_tile(const float* __restrict__ in, bf16* __restrict__ out,
                                  int K, int N, int k0, int n0) {
    __shared__ float tile[32][33];
    int tn = threadIdx.x & 31, tk = threadIdx.x >> 5;   // tk 0..7
#pragma unroll
    for (int i = 0; i < 4; ++i)
        tile[tk + i * 8][tn] = in[(size_t)(k0 + tk + i * 8) * N + n0 + tn];
    __syncthreads();
#pragma unroll
    for (int i = 0; i < 4; ++i)
        out[(size_t)(n0 + tk + i * 8) * K + k0 + tn] = (bf16)tile[tn][tk + i * 8];
}

// single-weight version (LM head)
__global__ __launch_bounds__(256) void convT_kernel(const float* __restrict__ in,
                                                    bf16* __restrict__ out,
                                                    int K, int N) {
    convT_tile(in, out, K, N, blockIdx.y * 32, blockIdx.x * 32);
}

// one layer's 4 weights in one launch
__global__ __launch_bounds__(256) void convT4_kernel(const float* __restrict__ w0,
                                                     const float* __restrict__ w1,
                                                     const float* __restrict__ w2,
                                                     const float* __restrict__ w3,
                                                     bf16* __restrict__ o0,
                                                     bf16* __restrict__ o1,
                                                     bf16* __restrict__ o2,
                                                     bf16* __restrict__ o3) {
    int bid = blockIdx.x;
    const float* in; bf16* out; int K, N, t;
    if (bid < 1728)      { in = w0; out = o0; K = 768;  N = 2304; t = bid; }          // Wqkv 24x72
    else if (bid < 2304) { in = w1; out = o1; K = 768;  N = 768;  t = bid - 1728; }   // Wo   24x24
    else if (bid < 4608) { in = w2; out = o2; K = 768;  N = 3072; t = bid - 2304; }   // W1   24x96
    else                 { in = w3; out = o3; K = 3072; N = 768;  t = bid - 4608; }   // W2   96x24
    int nt = N / 32;
    convT_tile(in, out, K, N, (t / nt) * 32, (t % nt) * 32);
}

// ---------------- bf16 MFMA GEMM: C = epi(A[M,K] @ Bt[N,K]^T + bias) ----------
// EPI: 0 plain f32 (LDS-transposed float4 stores); 1 +bias bf16; 2 +bias+res f32;
//      3 +bias GELU bf16; 4 qkv special (Q*0.125 bf16, K bf16, V -> vt transposed)
template<int BM, int EPI>
__global__ __launch_bounds__(256) void mgemm(const bf16* __restrict__ A,
                                             const bf16* __restrict__ Bt,
                                             const float* __restrict__ bias,
                                             const float* __restrict__ res,
                                             void* __restrict__ Cout,
                                             bf16* __restrict__ vtout,
                                             int M, int N, int K) {
    constexpr int MF = BM / 32;
    constexpr int NF = 4;
    constexpr int AIT = BM / 64;      // A gload insts per wave
    __shared__ __align__(16) bf16 As[BM * 32];
    __shared__ __align__(16) bf16 Bs[128 * 32];
    __shared__ __align__(16) float elds[EPI == 0 ? 4 * 16 * 68 : 4];
    int bm = blockIdx.y * BM, bn = blockIdx.x * 128;
    int tid = threadIdx.x;
    int lane = tid & 63;
    int w = tid >> 6;
    int wr = w >> 1, wc = w & 1;
    int l15 = lane & 15, g = lane >> 4;

    f32x4 acc[MF][NF];
#pragma unroll
    for (int m = 0; m < MF; ++m)
#pragma unroll
        for (int n = 0; n < NF; ++n) acc[m][n] = (f32x4){0.f, 0.f, 0.f, 0.f};

    int r = lane >> 2, koff = (lane & 3) * 8;
    const bf16* Ab = A + (size_t)(bm + w * 16 + r) * K + koff;
    const bf16* Bb = Bt + (size_t)(bn + w * 16 + r) * K + koff;
    bf16* Asb = &As[w * 16 * 32];
    bf16* Bsb = &Bs[w * 16 * 32];

    int kq = g * 8;
    for (int k0 = 0; k0 < K; k0 += 32) {
        __syncthreads();
#pragma unroll
        for (int it = 0; it < AIT; ++it)
            gload16(Ab + (size_t)(it * 64) * K + k0, Asb + it * 64 * 32);
#pragma unroll
        for (int it = 0; it < 2; ++it)
            gload16(Bb + (size_t)(it * 64) * K + k0, Bsb + it * 64 * 32);
        __syncthreads();
        bf16x8 af[MF], bfv[NF];
#pragma unroll
        for (int m = 0; m < MF; ++m)
            af[m] = *(const bf16x8*)&As[(wr * (BM / 2) + m * 16 + l15) * 32 + kq];
#pragma unroll
        for (int n = 0; n < NF; ++n)
            bfv[n] = *(const bf16x8*)&Bs[(wc * 64 + n * 16 + l15) * 32 + kq];
#pragma unroll
        for (int m = 0; m < MF; ++m)
#pragma unroll
            for (int n = 0; n < NF; ++n)
                acc[m][n] = __builtin_amdgcn_mfma_f32_16x16x32_bf16(af[m], bfv[n], acc[m][n], 0, 0, 0);
    }

    int lq = g * 4;
    if (EPI == 0) {
        // transposed epilogue: per-wave LDS round-trip, float4 contiguous stores
        float* eb = &elds[w * 16 * 68];
        int rr = lane >> 2, c0 = (lane & 3) * 16;
#pragma unroll
        for (int mf = 0; mf < MF; ++mf) {
#pragma unroll
            for (int n = 0; n < NF; ++n)
#pragma unroll
                for (int j = 0; j < 4; ++j)
                    eb[(lq + j) * 68 + n * 16 + l15] = acc[mf][n][j];
            __syncthreads();
            const float* src = &eb[rr * 68 + c0];
            float* dst = (float*)Cout + (size_t)(bm + wr * 64 + mf * 16 + rr) * N + bn + wc * 64 + c0;
            *(float4*)(dst + 0)  = *(const float4*)(src + 0);
            *(float4*)(dst + 4)  = *(const float4*)(src + 4);
            *(float4*)(dst + 8)  = *(const float4*)(src + 8);
            *(float4*)(dst + 12) = *(const float4*)(src + 12);
            __syncthreads();
        }
        return;
    }

#pragma unroll
    for (int m = 0; m < MF; ++m) {
#pragma unroll
        for (int n = 0; n < NF; ++n) {
            int col = bn + wc * 64 + n * 16 + l15;
            float bv = (EPI >= 1) ? bias[col] : 0.f;
            if (EPI == 4 && col >= 2 * DD) {
                int row0 = bm + wr * (BM / 2) + m * 16 + lq;
                int b = row0 >> 10, t0 = row0 & 1023;
                int hd = col - 2 * DD;
                union { bf16 h[4]; unsigned long long u; } pk;
#pragma unroll
                for (int j = 0; j < 4; ++j) pk.h[j] = (bf16)(acc[m][n][j] + bv);
                *(unsigned long long*)&vtout[((size_t)(b * DD + hd)) * TT + t0] = pk.u;
            } else {
#pragma unroll
                for (int j = 0; j < 4; ++j) {
                    int row = bm + wr * (BM / 2) + m * 16 + lq + j;
                    float v = acc[m][n][j] + bv;
                    if (EPI == 2) {
                        ((float*)Cout)[(size_t)row * N + col] = v + res[(size_t)row * N + col];
                    } else if (EPI == 3) {
                        v = 0.5f * v * (1.f + erff(v * 0.70710678118654752f));
                        ((bf16*)Cout)[(size_t)row * N + col] = (bf16)v;
                    } else if (EPI == 1) {
                        ((bf16*)Cout)[(size_t)row * N + col] = (bf16)v;
                    } else { // EPI == 4 Q/K columns
                        if (col < DD) v *= 0.125f;
                        ((bf16*)Cout)[(size_t)row * N + col] = (bf16)v;
                    }
                }
            }
        }
    }
}

// ---------------- MFMA flash attention ----------------
__global__ __launch_bounds__(256) void fattn_kernel(const bf16* __restrict__ qkv,
                                                    const bf16* __restrict__ vt,
                                                    bf16* __restrict__ o) {
    const int bh = blockIdx.y;
    const int b = bh / HH, h = bh % HH;
    const int q0 = blockIdx.x * 64;
    const int tid = threadIdx.x;
    const int w = tid >> 6, lane = tid & 63;
    const int l15 = lane & 15, g = lane >> 4;

    __shared__ __align__(16) bf16 Ks[64 * 64];
    __shared__ __align__(16) bf16 Vs[64 * 64];
    __shared__ __align__(16) bf16 Ps[4][16 * 64];

    const size_t basebt = (size_t)b * TT;
    const int qw = q0 + w * 16;
    const int qg = qw + l15;

    bf16x8 bq0, bq1;
    {
        const bf16* qp = qkv + (basebt + qw + l15) * 2304 + h * 64 + g * 8;
        bq0 = *(const bf16x8*)(qp);
        bq1 = *(const bf16x8*)(qp + 32);
    }

    float mstate = -1e30f, lstate = 0.f;
    f32x4 oacc[4];
#pragma unroll
    for (int nf = 0; nf < 4; ++nf) oacc[nf] = (f32x4){0.f, 0.f, 0.f, 0.f};

    const int swzA = (l15 & 7) << 4;
    char* const psBase = (char*)&Ps[w][0];

    const int nchunk = blockIdx.x + 1;
    for (int c = 0; c < nchunk; ++c) {
        const int kc = c * 64;
        __syncthreads();
        {
            int r0 = tid >> 3;
            int e0 = (tid & 7) * 8;
#pragma unroll
            for (int i = 0; i < 2; ++i) {
                int r = r0 + 32 * i;
                int swzW = (r & 7) << 4;
                bf16x8 kv = *(const bf16x8*)&qkv[(basebt + kc + r) * 2304 + DD + h * 64 + e0];
                *(bf16x8*)((char*)Ks + r * 128 + ((e0 * 2) ^ swzW)) = kv;
                bf16x8 vv = *(const bf16x8*)&vt[((size_t)bh * 64 + r) * TT + kc + e0];
                *(bf16x8*)((char*)Vs + r * 128 + ((e0 * 2) ^ swzW)) = vv;
            }
        }
        __syncthreads();
        if (kc > qw + 15) continue;

        f32x4 s[4];
#pragma unroll
        for (int mf = 0; mf < 4; ++mf) {
            char* kr = (char*)Ks + (16 * mf + l15) * 128;
            bf16x8 ka0 = *(const bf16x8*)(kr + ((16 * g) ^ swzA));
            bf16x8 ka1 = *(const bf16x8*)(kr + ((64 + 16 * g) ^ swzA));
            f32x4 a = (f32x4){0.f, 0.f, 0.f, 0.f};
            a = __builtin_amdgcn_mfma_f32_16x16x32_bf16(ka0, bq0, a, 0, 0, 0);
            a = __builtin_amdgcn_mfma_f32_16x16x32_bf16(ka1, bq1, a, 0, 0, 0);
            s[mf] = a;
        }
        if (kc + 63 > qw) {
#pragma unroll
            for (int mf = 0; mf < 4; ++mf)
#pragma unroll
                for (int j = 0; j < 4; ++j)
                    if (kc + 16 * mf + 4 * g + j > qg) s[mf][j] = -1e30f;
        }
        float cm = -1e30f;
#pragma unroll
        for (int mf = 0; mf < 4; ++mf)
#pragma unroll
            for (int j = 0; j < 4; ++j) cm = fmaxf(cm, s[mf][j]);
        cm = fmaxf(cm, __shfl_xor(cm, 16));
        cm = fmaxf(cm, __shfl_xor(cm, 32));
        float mnew = fmaxf(mstate, cm);
        float sc = __expf(mstate - mnew);
        mstate = mnew;
        float p[4][4];
        float psum = 0.f;
#pragma unroll
        for (int mf = 0; mf < 4; ++mf)
#pragma unroll
            for (int j = 0; j < 4; ++j) { float pv = __expf(s[mf][j] - mnew); p[mf][j] = pv; psum += pv; }
        psum += __shfl_xor(psum, 16);
        psum += __shfl_xor(psum, 32);
        lstate = lstate * sc + psum;
#pragma unroll
        for (int mf = 0; mf < 4; ++mf) {
            unsigned lo = pack_bf16x2(p[mf][0], p[mf][1]);
            unsigned hi = pack_bf16x2(p[mf][2], p[mf][3]);
            char* dst = psBase + l15 * 128 + ((32 * mf + 8 * g) ^ swzA);
            *(unsigned*)dst = lo;
            *(unsigned*)(dst + 4) = hi;
        }
        float s0 = __shfl(sc, 4 * g + 0), s1 = __shfl(sc, 4 * g + 1);
        float s2 = __shfl(sc, 4 * g + 2), s3 = __shfl(sc, 4 * g + 3);
#pragma unroll
        for (int nf = 0; nf < 4; ++nf) {
            oacc[nf][0] *= s0; oacc[nf][1] *= s1; oacc[nf][2] *= s2; oacc[nf][3] *= s3;
        }
        bf16x8 pa0 = *(const bf16x8*)(psBase + l15 * 128 + ((16 * g) ^ swzA));
        bf16x8 pa1 = *(const bf16x8*)(psBase + l15 * 128 + ((64 + 16 * g) ^ swzA));
#pragma unroll
        for (int nf = 0; nf < 4; ++nf) {
            char* vr = (char*)Vs + (16 * nf + l15) * 128;
            bf16x8 vb0 = *(const bf16x8*)(vr + ((16 * g) ^ swzA));
            bf16x8 vb1 = *(const bf16x8*)(vr + ((64 + 16 * g) ^ swzA));
            oacc[nf] = __builtin_amdgcn_mfma_f32_16x16x32_bf16(pa0, vb0, oacc[nf], 0, 0, 0);
            oacc[nf] = __builtin_amdgcn_mfma_f32_16x16x32_bf16(pa1, vb1, oacc[nf], 0, 0, 0);
        }
    }
    float linv = 1.f / lstate;
    float l0 = __shfl(linv, 4 * g + 0), l1 = __shfl(linv, 4 * g + 1);
    float l2 = __shfl(linv, 4 * g + 2), l3 = __shfl(linv, 4 * g + 3);
    float lj[4] = {l0, l1, l2, l3};
#pragma unroll
    for (int j = 0; j < 4; ++j) {
        bf16* orow = o + (size_t)(basebt + qw + 4 * g + j) * DD + h * 64 + l15;
#pragma unroll
        for (int nf = 0; nf < 4; ++nf)
            orow[16 * nf] = (bf16)(oacc[nf][j] * lj[j]);
    }
}

// ---------------- launcher ----------------
extern "C" void kernel_launch(void* const* d_in, const int* in_sizes, int n_in,
                              void* d_out, int out_size, void* d_ws, size_t ws_size,
                              hipStream_t stream) {
    (void)in_sizes; (void)n_in; (void)out_size; (void)ws_size;
    const int*   idx  = (const int*)d_in[0];
    const float* tok  = (const float*)d_in[1];
    const float* pos  = (const float*)d_in[2];
    const float* Wqkv = (const float*)d_in[3];
    const float* bqkv = (const float*)d_in[4];
    const float* Wo   = (const float*)d_in[5];
    const float* bo   = (const float*)d_in[6];
    const float* ln1g = (const float*)d_in[7];
    const float* ln1b = (const float*)d_in[8];
    const float* ln2g = (const float*)d_in[9];
    const float* ln2b = (const float*)d_in[10];
    const float* W1   = (const float*)d_in[11];
    const float* b1   = (const float*)d_in[12];
    const float* W2   = (const float*)d_in[13];
    const float* b2   = (const float*)d_in[14];
    const float* lnfg = (const float*)d_in[15];
    const float* lnfb = (const float*)d_in[16];
    const float* Wlm  = (const float*)d_in[17];
    float* out = (float*)d_out;

    char* ws = (char*)d_ws;
    float* x     = (float*)(ws);                       // 6,291,456
    bf16*  abuf0 = (bf16*)(ws + 6291456);              // 3,145,728
    bf16*  abuf1 = (bf16*)(ws + 9437184);              // 12,582,912
    bf16*  qkvb  = (bf16*)(ws + 22020096);             // 9,437,184
    bf16*  vtb   = (bf16*)(ws + 31457280);             // 3,145,728
    bf16*  wbuf  = (bf16*)(ws + 34603008);             // 49,152,000

    // per-layer converted-weight offsets inside wbuf (elements)
    bf16* wq = wbuf;              // 2304x768
    bf16* wo = wbuf + 1769472;    // 768x768
    bf16* w1 = wbuf + 2359296;    // 3072x768
    bf16* w2 = wbuf + 4718592;    // 768x3072

    embed_kernel<<<NTOK, 256, 0, stream>>>(idx, tok, pos, x);

    for (int l = 0; l < LLAY; ++l) {
        convT4_kernel<<<6912, 256, 0, stream>>>(
            Wqkv + (size_t)l * DD * 3 * DD, Wo + (size_t)l * DD * DD,
            W1 + (size_t)l * DD * DFFN, W2 + (size_t)l * DFFN * DD,
            wq, wo, w1, w2);
        ln_kernel<<<NTOK, 256, 0, stream>>>(x, ln1g + l * DD, ln1b + l * DD, abuf0);
        mgemm<128, 4><<<dim3(3 * DD / 128, NTOK / 128), 256, 0, stream>>>(
            abuf0, wq, bqkv + (size_t)l * 3 * DD, nullptr, qkvb, vtb, NTOK, 3 * DD, DD);
        fattn_kernel<<<dim3(TT / 64, BB * HH), 256, 0, stream>>>(qkvb, vtb, abuf0);
        mgemm<64, 2><<<dim3(DD / 128, NTOK / 64), 256, 0, stream>>>(
            abuf0, wo, bo + (size_t)l * DD, x, x, nullptr, NTOK, DD, DD);
        ln_kernel<<<NTOK, 256, 0, stream>>>(x, ln2g + l * DD, ln2b + l * DD, abuf0);
        mgemm<128, 3><<<dim3(DFFN / 128, NTOK / 128), 256, 0, stream>>>(
            abuf0, w1, b1 + (size_t)l * DFFN, nullptr, abuf1, nullptr, NTOK, DFFN, DD);
        mgemm<64, 2><<<dim3(DD / 128, NTOK / 64), 256, 0, stream>>>(
            abuf1, w2, b2 + (size_t)l * DD, x, x, nullptr, NTOK, DD, DFFN);
    }
    ln_kernel<<<NTOK, 256, 0, stream>>>(x, lnfg, lnfb, abuf0);
    convT_kernel<<<dim3(32000 / 32, DD / 32), 256, 0, stream>>>(Wlm, wbuf, DD, 32000);
    mgemm<128, 0><<<dim3(32000 / 128, NTOK / 128), 256, 0, stream>>>(
        abuf0, wbuf, nullptr, nullptr, out, nullptr, NTOK, 32000, DD);
}

// Round 5
// 1261.143 us; speedup vs baseline: 5.8361x; 1.0114x over previous
//
#include <hip/hip_runtime.h>
#include <math.h>

#define TT   1024
#define DD   768
#define HH   12
#define LLAY 6
#define DFFN 3072
#define BB   2
#define NTOK (BB*TT)   // 2048

typedef __bf16 bf16;
typedef __attribute__((ext_vector_type(8))) __bf16 bf16x8;
typedef __attribute__((ext_vector_type(4))) __bf16 bf16x4;
typedef __attribute__((ext_vector_type(4))) float f32x4;

__device__ inline unsigned pack_bf16x2(float a, float b) {
    union { bf16 h[2]; unsigned u; } un;
    un.h[0] = (bf16)a; un.h[1] = (bf16)b;
    return un.u;
}

// async global->LDS, 16B per lane; LDS dest is wave-uniform base (+lane*16 by HW)
__device__ inline void gload16(const bf16* g, bf16* l) {
    __builtin_amdgcn_global_load_lds((const void*)g, (void*)l, 16, 0, 0);
}

// ---------------- embedding ----------------
__global__ __launch_bounds__(256) void embed_kernel(const int* __restrict__ idx,
                                                    const float* __restrict__ tok,
                                                    const float* __restrict__ pos,
                                                    float* __restrict__ x) {
    int bt = blockIdx.x;
    int t  = bt % TT;
    int id = idx[bt];
    const float* te = tok + (size_t)id * DD;
    const float* pe = pos + (size_t)t * DD;
    float* xr = x + (size_t)bt * DD;
    for (int d = threadIdx.x; d < DD; d += 256) xr[d] = te[d] + pe[d];
}

// ---------------- layernorm: f32 in -> bf16 out ----------------
__global__ __launch_bounds__(256) void ln_kernel(const float* __restrict__ in,
                                                 const float* __restrict__ g,
                                                 const float* __restrict__ b,
                                                 bf16* __restrict__ out) {
    int row = blockIdx.x;
    const float* xr = in + (size_t)row * DD;
    float s = 0.f, s2 = 0.f;
    for (int d = threadIdx.x; d < DD; d += 256) { float v = xr[d]; s += v; s2 += v * v; }
    for (int off = 32; off; off >>= 1) { s += __shfl_down(s, off); s2 += __shfl_down(s2, off); }
    __shared__ float aS[4], aS2[4];
    __shared__ float mu_s, rs_s;
    int wid = threadIdx.x >> 6, lane = threadIdx.x & 63;
    if (lane == 0) { aS[wid] = s; aS2[wid] = s2; }
    __syncthreads();
    if (threadIdx.x == 0) {
        float t1 = aS[0] + aS[1] + aS[2] + aS[3];
        float t2 = aS2[0] + aS2[1] + aS2[2] + aS2[3];
        float mu = t1 / (float)DD;
        float var = t2 / (float)DD - mu * mu;
        mu_s = mu; rs_s = rsqrtf(var + 1e-5f);
    }
    __syncthreads();
    float mu = mu_s, rs = rs_s;
    bf16* orow = out + (size_t)row * DD;
    for (int d = threadIdx.x; d < DD; d += 256)
        orow[d] = (bf16)((xr[d] - mu) * rs * g[d] + b[d]);
}

// ---------------- 32x32 transpose+convert tile helper ----------------
__device__ inline void convT_tile(const float* __restrict__ in, bf16* __restrict__ out,
                                  int K, int N, int k0, int n0) {
    __shared__ float tile[32][33];
    int tn = threadIdx.x & 31, tk = threadIdx.x >> 5;   // tk 0..7
#pragma unroll
    for (int i = 0; i < 4; ++i)
        tile[tk + i * 8][tn] = in[(size_t)(k0 + tk + i * 8) * N + n0 + tn];
    __syncthreads();
#pragma unroll
    for (int i = 0; i < 4; ++i)
        out[(size_t)(n0 + tk + i * 8) * K + k0 + tn] = (bf16)tile[tn][tk + i * 8];
}

// single-weight version (LM head)
__global__ __launch_bounds__(256) void convT_kernel(const float* __restrict__ in,
                                                    bf16* __restrict__ out,
                                                    int K, int N) {
    convT_tile(in, out, K, N, blockIdx.y * 32, blockIdx.x * 32);
}

// one layer's 4 weights in one launch
__global__ __launch_bounds__(256) void convT4_kernel(const float* __restrict__ w0,
                                                     const float* __restrict__ w1,
                                                     const float* __restrict__ w2,
                                                     const float* __restrict__ w3,
                                                     bf16* __restrict__ o0,
                                                     bf16* __restrict__ o1,
                                                     bf16* __restrict__ o2,
                                                     bf16* __restrict__ o3) {
    int bid = blockIdx.x;
    const float* in; bf16* out; int K, N, t;
    if (bid < 1728)      { in = w0; out = o0; K = 768;  N = 2304; t = bid; }          // Wqkv 24x72
    else if (bid < 2304) { in = w1; out = o1; K = 768;  N = 768;  t = bid - 1728; }   // Wo   24x24
    else if (bid < 4608) { in = w2; out = o2; K = 768;  N = 3072; t = bid - 2304; }   // W1   24x96
    else                 { in = w3; out = o3; K = 3072; N = 768;  t = bid - 4608; }   // W2   96x24
    int nt = N / 32;
    convT_tile(in, out, K, N, (t / nt) * 32, (t % nt) * 32);
}

// ---------------- bf16 MFMA GEMM: C = epi(A[M,K] @ Bt[N,K]^T + bias) ----------
// LDS tiles are XOR-swizzled: 16B chunk c of row r lives at chunk c ^ ((r>>1)&3).
// Staging keeps LDS dest linear and pre-swizzles the per-lane GLOBAL source.
// EPI: 0 plain f32 (grid-swapped, LDS-transposed float4 stores); 1 +bias bf16;
//      2 +bias+res f32; 3 +bias GELU bf16; 4 qkv special
template<int BM, int EPI>
__global__ __launch_bounds__(256) void mgemm(const bf16* __restrict__ A,
                                             const bf16* __restrict__ Bt,
                                             const float* __restrict__ bias,
                                             const float* __restrict__ res,
                                             void* __restrict__ Cout,
                                             bf16* __restrict__ vtout,
                                             int M, int N, int K) {
    constexpr int MF = BM / 32;
    constexpr int NF = 4;
    constexpr int AIT = BM / 64;
    __shared__ __align__(16) bf16 As[BM * 32];
    __shared__ __align__(16) bf16 Bs[128 * 32];
    __shared__ __align__(16) float elds[EPI == 0 ? 4 * 16 * 68 : 4];
    // EPI=0 (LM head): x = M-block so consecutive blocks share the B panel (L2)
    int bm = (EPI == 0 ? blockIdx.x : blockIdx.y) * BM;
    int bn = (EPI == 0 ? blockIdx.y : blockIdx.x) * 128;
    int tid = threadIdx.x;
    int lane = tid & 63;
    int w = tid >> 6;
    int wr = w >> 1, wc = w & 1;
    int l15 = lane & 15, g = lane >> 4;

    f32x4 acc[MF][NF];
#pragma unroll
    for (int m = 0; m < MF; ++m)
#pragma unroll
        for (int n = 0; n < NF; ++n) acc[m][n] = (f32x4){0.f, 0.f, 0.f, 0.f};

    int r = lane >> 2;
    int koff = ((lane & 3) ^ ((r >> 1) & 3)) * 8;     // pre-swizzled global source
    const bf16* Ab = A + (size_t)(bm + w * 16 + r) * K + koff;
    const bf16* Bb = Bt + (size_t)(bn + w * 16 + r) * K + koff;
    bf16* Asb = &As[w * 16 * 32];
    bf16* Bsb = &Bs[w * 16 * 32];

    for (int k0 = 0; k0 < K; k0 += 32) {
        __syncthreads();
#pragma unroll
        for (int it = 0; it < AIT; ++it)
            gload16(Ab + (size_t)(it * 64) * K + k0, Asb + it * 64 * 32);
#pragma unroll
        for (int it = 0; it < 2; ++it)
            gload16(Bb + (size_t)(it * 64) * K + k0, Bsb + it * 64 * 32);
        __syncthreads();
        bf16x8 af[MF], bfv[NF];
#pragma unroll
        for (int m = 0; m < MF; ++m) {
            int row = wr * (BM / 2) + m * 16 + l15;
            int gs = g ^ ((row >> 1) & 3);            // read-side swizzle
            af[m] = *(const bf16x8*)&As[row * 32 + gs * 8];
        }
#pragma unroll
        for (int n = 0; n < NF; ++n) {
            int row = wc * 64 + n * 16 + l15;
            int gs = g ^ ((row >> 1) & 3);
            bfv[n] = *(const bf16x8*)&Bs[row * 32 + gs * 8];
        }
#pragma unroll
        for (int m = 0; m < MF; ++m)
#pragma unroll
            for (int n = 0; n < NF; ++n)
                acc[m][n] = __builtin_amdgcn_mfma_f32_16x16x32_bf16(af[m], bfv[n], acc[m][n], 0, 0, 0);
    }

    int lq = g * 4;
    if (EPI == 0) {
        // transposed epilogue: per-wave LDS round-trip, float4 contiguous stores
        float* eb = &elds[w * 16 * 68];
        int rr = lane >> 2, c0 = (lane & 3) * 16;
#pragma unroll
        for (int mf = 0; mf < MF; ++mf) {
#pragma unroll
            for (int n = 0; n < NF; ++n)
#pragma unroll
                for (int j = 0; j < 4; ++j)
                    eb[(lq + j) * 68 + n * 16 + l15] = acc[mf][n][j];
            __syncthreads();
            const float* src = &eb[rr * 68 + c0];
            float* dst = (float*)Cout + (size_t)(bm + wr * 64 + mf * 16 + rr) * N + bn + wc * 64 + c0;
            *(float4*)(dst + 0)  = *(const float4*)(src + 0);
            *(float4*)(dst + 4)  = *(const float4*)(src + 4);
            *(float4*)(dst + 8)  = *(const float4*)(src + 8);
            *(float4*)(dst + 12) = *(const float4*)(src + 12);
            __syncthreads();
        }
        return;
    }

#pragma unroll
    for (int m = 0; m < MF; ++m) {
#pragma unroll
        for (int n = 0; n < NF; ++n) {
            int col = bn + wc * 64 + n * 16 + l15;
            float bv = (EPI >= 1) ? bias[col] : 0.f;
            if (EPI == 4 && col >= 2 * DD) {
                int row0 = bm + wr * (BM / 2) + m * 16 + lq;
                int b = row0 >> 10, t0 = row0 & 1023;
                int hd = col - 2 * DD;
                union { bf16 h[4]; unsigned long long u; } pk;
#pragma unroll
                for (int j = 0; j < 4; ++j) pk.h[j] = (bf16)(acc[m][n][j] + bv);
                *(unsigned long long*)&vtout[((size_t)(b * DD + hd)) * TT + t0] = pk.u;
            } else {
#pragma unroll
                for (int j = 0; j < 4; ++j) {
                    int row = bm + wr * (BM / 2) + m * 16 + lq + j;
                    float v = acc[m][n][j] + bv;
                    if (EPI == 2) {
                        ((float*)Cout)[(size_t)row * N + col] = v + res[(size_t)row * N + col];
                    } else if (EPI == 3) {
                        v = 0.5f * v * (1.f + erff(v * 0.70710678118654752f));
                        ((bf16*)Cout)[(size_t)row * N + col] = (bf16)v;
                    } else if (EPI == 1) {
                        ((bf16*)Cout)[(size_t)row * N + col] = (bf16)v;
                    } else { // EPI == 4 Q/K columns
                        if (col < DD) v *= 0.125f;
                        ((bf16*)Cout)[(size_t)row * N + col] = (bf16)v;
                    }
                }
            }
        }
    }
}

// ---------------- MFMA flash attention ----------------
__global__ __launch_bounds__(256) void fattn_kernel(const bf16* __restrict__ qkv,
                                                    const bf16* __restrict__ vt,
                                                    bf16* __restrict__ o) {
    const int bh = blockIdx.y;
    const int b = bh / HH, h = bh % HH;
    const int q0 = blockIdx.x * 64;
    const int tid = threadIdx.x;
    const int w = tid >> 6, lane = tid & 63;
    const int l15 = lane & 15, g = lane >> 4;

    __shared__ __align__(16) bf16 Ks[64 * 64];
    __shared__ __align__(16) bf16 Vs[64 * 64];
    __shared__ __align__(16) bf16 Ps[4][16 * 64];

    const size_t basebt = (size_t)b * TT;
    const int qw = q0 + w * 16;
    const int qg = qw + l15;

    bf16x8 bq0, bq1;
    {
        const bf16* qp = qkv + (basebt + qw + l15) * 2304 + h * 64 + g * 8;
        bq0 = *(const bf16x8*)(qp);
        bq1 = *(const bf16x8*)(qp + 32);
    }

    float mstate = -1e30f, lstate = 0.f;
    f32x4 oacc[4];
#pragma unroll
    for (int nf = 0; nf < 4; ++nf) oacc[nf] = (f32x4){0.f, 0.f, 0.f, 0.f};

    const int swzA = (l15 & 7) << 4;
    char* const psBase = (char*)&Ps[w][0];

    const int nchunk = blockIdx.x + 1;
    for (int c = 0; c < nchunk; ++c) {
        const int kc = c * 64;
        __syncthreads();
        {
            int r0 = tid >> 3;
            int e0 = (tid & 7) * 8;
#pragma unroll
            for (int i = 0; i < 2; ++i) {
                int r = r0 + 32 * i;
                int swzW = (r & 7) << 4;
                bf16x8 kv = *(const bf16x8*)&qkv[(basebt + kc + r) * 2304 + DD + h * 64 + e0];
                *(bf16x8*)((char*)Ks + r * 128 + ((e0 * 2) ^ swzW)) = kv;
                bf16x8 vv = *(const bf16x8*)&vt[((size_t)bh * 64 + r) * TT + kc + e0];
                *(bf16x8*)((char*)Vs + r * 128 + ((e0 * 2) ^ swzW)) = vv;
            }
        }
        __syncthreads();
        if (kc > qw + 15) continue;

        f32x4 s[4];
#pragma unroll
        for (int mf = 0; mf < 4; ++mf) {
            char* kr = (char*)Ks + (16 * mf + l15) * 128;
            bf16x8 ka0 = *(const bf16x8*)(kr + ((16 * g) ^ swzA));
            bf16x8 ka1 = *(const bf16x8*)(kr + ((64 + 16 * g) ^ swzA));
            f32x4 a = (f32x4){0.f, 0.f, 0.f, 0.f};
            a = __builtin_amdgcn_mfma_f32_16x16x32_bf16(ka0, bq0, a, 0, 0, 0);
            a = __builtin_amdgcn_mfma_f32_16x16x32_bf16(ka1, bq1, a, 0, 0, 0);
            s[mf] = a;
        }
        if (kc + 63 > qw) {
#pragma unroll
            for (int mf = 0; mf < 4; ++mf)
#pragma unroll
                for (int j = 0; j < 4; ++j)
                    if (kc + 16 * mf + 4 * g + j > qg) s[mf][j] = -1e30f;
        }
        float cm = -1e30f;
#pragma unroll
        for (int mf = 0; mf < 4; ++mf)
#pragma unroll
            for (int j = 0; j < 4; ++j) cm = fmaxf(cm, s[mf][j]);
        cm = fmaxf(cm, __shfl_xor(cm, 16));
        cm = fmaxf(cm, __shfl_xor(cm, 32));
        float mnew = fmaxf(mstate, cm);
        float sc = __expf(mstate - mnew);
        mstate = mnew;
        float p[4][4];
        float psum = 0.f;
#pragma unroll
        for (int mf = 0; mf < 4; ++mf)
#pragma unroll
            for (int j = 0; j < 4; ++j) { float pv = __expf(s[mf][j] - mnew); p[mf][j] = pv; psum += pv; }
        psum += __shfl_xor(psum, 16);
        psum += __shfl_xor(psum, 32);
        lstate = lstate * sc + psum;
#pragma unroll
        for (int mf = 0; mf < 4; ++mf) {
            unsigned lo = pack_bf16x2(p[mf][0], p[mf][1]);
            unsigned hi = pack_bf16x2(p[mf][2], p[mf][3]);
            char* dst = psBase + l15 * 128 + ((32 * mf + 8 * g) ^ swzA);
            *(unsigned*)dst = lo;
            *(unsigned*)(dst + 4) = hi;
        }
        float s0 = __shfl(sc, 4 * g + 0), s1 = __shfl(sc, 4 * g + 1);
        float s2 = __shfl(sc, 4 * g + 2), s3 = __shfl(sc, 4 * g + 3);
#pragma unroll
        for (int nf = 0; nf < 4; ++nf) {
            oacc[nf][0] *= s0; oacc[nf][1] *= s1; oacc[nf][2] *= s2; oacc[nf][3] *= s3;
        }
        bf16x8 pa0 = *(const bf16x8*)(psBase + l15 * 128 + ((16 * g) ^ swzA));
        bf16x8 pa1 = *(const bf16x8*)(psBase + l15 * 128 + ((64 + 16 * g) ^ swzA));
#pragma unroll
        for (int nf = 0; nf < 4; ++nf) {
            char* vr = (char*)Vs + (16 * nf + l15) * 128;
            bf16x8 vb0 = *(const bf16x8*)(vr + ((16 * g) ^ swzA));
            bf16x8 vb1 = *(const bf16x8*)(vr + ((64 + 16 * g) ^ swzA));
            oacc[nf] = __builtin_amdgcn_mfma_f32_16x16x32_bf16(pa0, vb0, oacc[nf], 0, 0, 0);
            oacc[nf] = __builtin_amdgcn_mfma_f32_16x16x32_bf16(pa1, vb1, oacc[nf], 0, 0, 0);
        }
    }
    float linv = 1.f / lstate;
    float l0 = __shfl(linv, 4 * g + 0), l1 = __shfl(linv, 4 * g + 1);
    float l2 = __shfl(linv, 4 * g + 2), l3 = __shfl(linv, 4 * g + 3);
    float lj[4] = {l0, l1, l2, l3};
#pragma unroll
    for (int j = 0; j < 4; ++j) {
        bf16* orow = o + (size_t)(basebt + qw + 4 * g + j) * DD + h * 64 + l15;
#pragma unroll
        for (int nf = 0; nf < 4; ++nf)
            orow[16 * nf] = (bf16)(oacc[nf][j] * lj[j]);
    }
}

// ---------------- launcher ----------------
extern "C" void kernel_launch(void* const* d_in, const int* in_sizes, int n_in,
                              void* d_out, int out_size, void* d_ws, size_t ws_size,
                              hipStream_t stream) {
    (void)in_sizes; (void)n_in; (void)out_size; (void)ws_size;
    const int*   idx  = (const int*)d_in[0];
    const float* tok  = (const float*)d_in[1];
    const float* pos  = (const float*)d_in[2];
    const float* Wqkv = (const float*)d_in[3];
    const float* bqkv = (const float*)d_in[4];
    const float* Wo   = (const float*)d_in[5];
    const float* bo   = (const float*)d_in[6];
    const float* ln1g = (const float*)d_in[7];
    const float* ln1b = (const float*)d_in[8];
    const float* ln2g = (const float*)d_in[9];
    const float* ln2b = (const float*)d_in[10];
    const float* W1   = (const float*)d_in[11];
    const float* b1   = (const float*)d_in[12];
    const float* W2   = (const float*)d_in[13];
    const float* b2   = (const float*)d_in[14];
    const float* lnfg = (const float*)d_in[15];
    const float* lnfb = (const float*)d_in[16];
    const float* Wlm  = (const float*)d_in[17];
    float* out = (float*)d_out;

    char* ws = (char*)d_ws;
    float* x     = (float*)(ws);                       // 6,291,456
    bf16*  abuf0 = (bf16*)(ws + 6291456);              // 3,145,728
    bf16*  abuf1 = (bf16*)(ws + 9437184);              // 12,582,912
    bf16*  qkvb  = (bf16*)(ws + 22020096);             // 9,437,184
    bf16*  vtb   = (bf16*)(ws + 31457280);             // 3,145,728
    bf16*  wbuf  = (bf16*)(ws + 34603008);             // 49,152,000

    bf16* wq = wbuf;              // 2304x768
    bf16* wo = wbuf + 1769472;    // 768x768
    bf16* w1 = wbuf + 2359296;    // 3072x768
    bf16* w2 = wbuf + 4718592;    // 768x3072

    embed_kernel<<<NTOK, 256, 0, stream>>>(idx, tok, pos, x);

    for (int l = 0; l < LLAY; ++l) {
        convT4_kernel<<<6912, 256, 0, stream>>>(
            Wqkv + (size_t)l * DD * 3 * DD, Wo + (size_t)l * DD * DD,
            W1 + (size_t)l * DD * DFFN, W2 + (size_t)l * DFFN * DD,
            wq, wo, w1, w2);
        ln_kernel<<<NTOK, 256, 0, stream>>>(x, ln1g + l * DD, ln1b + l * DD, abuf0);
        mgemm<128, 4><<<dim3(3 * DD / 128, NTOK / 128), 256, 0, stream>>>(
            abuf0, wq, bqkv + (size_t)l * 3 * DD, nullptr, qkvb, vtb, NTOK, 3 * DD, DD);
        fattn_kernel<<<dim3(TT / 64, BB * HH), 256, 0, stream>>>(qkvb, vtb, abuf0);
        mgemm<64, 2><<<dim3(DD / 128, NTOK / 64), 256, 0, stream>>>(
            abuf0, wo, bo + (size_t)l * DD, x, x, nullptr, NTOK, DD, DD);
        ln_kernel<<<NTOK, 256, 0, stream>>>(x, ln2g + l * DD, ln2b + l * DD, abuf0);
        mgemm<128, 3><<<dim3(DFFN / 128, NTOK / 128), 256, 0, stream>>>(
            abuf0, w1, b1 + (size_t)l * DFFN, nullptr, abuf1, nullptr, NTOK, DFFN, DD);
        mgemm<64, 2><<<dim3(DD / 128, NTOK / 64), 256, 0, stream>>>(
            abuf1, w2, b2 + (size_t)l * DD, x, x, nullptr, NTOK, DD, DFFN);
    }
    ln_kernel<<<NTOK, 256, 0, stream>>>(x, lnfg, lnfb, abuf0);
    convT_kernel<<<dim3(32000 / 32, DD / 32), 256, 0, stream>>>(Wlm, wbuf, DD, 32000);
    // LM head: grid swapped (x = M-blocks) so consecutive blocks share B panel
    mgemm<128, 0><<<dim3(NTOK / 128, 32000 / 128), 256, 0, stream>>>(
        abuf0, wbuf, nullptr, nullptr, out, nullptr, NTOK, 32000, DD);
}

// Round 6
// 1149.186 us; speedup vs baseline: 6.4047x; 1.0974x over previous
//
#include <hip/hip_runtime.h>
#include <math.h>

#define TT   1024
#define DD   768
#define HH   12
#define LLAY 6
#define DFFN 3072
#define BB   2
#define NTOK (BB*TT)   // 2048

typedef __bf16 bf16;
typedef __attribute__((ext_vector_type(8))) __bf16 bf16x8;
typedef __attribute__((ext_vector_type(4))) __bf16 bf16x4;
typedef __attribute__((ext_vector_type(4))) float f32x4;

__device__ inline unsigned pack_bf16x2(float a, float b) {
    union { bf16 h[2]; unsigned u; } un;
    un.h[0] = (bf16)a; un.h[1] = (bf16)b;
    return un.u;
}

// async global->LDS, 16B per lane; LDS dest is wave-uniform base (+lane*16 by HW)
__device__ inline void gload16(const bf16* g, bf16* l) {
    __builtin_amdgcn_global_load_lds((const void*)g, (void*)l, 16, 0, 0);
}

// ---------------- embedding ----------------
__global__ __launch_bounds__(256) void embed_kernel(const int* __restrict__ idx,
                                                    const float* __restrict__ tok,
                                                    const float* __restrict__ pos,
                                                    float* __restrict__ x) {
    int bt = blockIdx.x;
    int t  = bt % TT;
    int id = idx[bt];
    const float* te = tok + (size_t)id * DD;
    const float* pe = pos + (size_t)t * DD;
    float* xr = x + (size_t)bt * DD;
    for (int d = threadIdx.x; d < DD; d += 256) xr[d] = te[d] + pe[d];
}

// ---------------- layernorm: f32 in -> bf16 out ----------------
__global__ __launch_bounds__(256) void ln_kernel(const float* __restrict__ in,
                                                 const float* __restrict__ g,
                                                 const float* __restrict__ b,
                                                 bf16* __restrict__ out) {
    int row = blockIdx.x;
    const float* xr = in + (size_t)row * DD;
    float s = 0.f, s2 = 0.f;
    for (int d = threadIdx.x; d < DD; d += 256) { float v = xr[d]; s += v; s2 += v * v; }
    for (int off = 32; off; off >>= 1) { s += __shfl_down(s, off); s2 += __shfl_down(s2, off); }
    __shared__ float aS[4], aS2[4];
    __shared__ float mu_s, rs_s;
    int wid = threadIdx.x >> 6, lane = threadIdx.x & 63;
    if (lane == 0) { aS[wid] = s; aS2[wid] = s2; }
    __syncthreads();
    if (threadIdx.x == 0) {
        float t1 = aS[0] + aS[1] + aS[2] + aS[3];
        float t2 = aS2[0] + aS2[1] + aS2[2] + aS2[3];
        float mu = t1 / (float)DD;
        float var = t2 / (float)DD - mu * mu;
        mu_s = mu; rs_s = rsqrtf(var + 1e-5f);
    }
    __syncthreads();
    float mu = mu_s, rs = rs_s;
    bf16* orow = out + (size_t)row * DD;
    for (int d = threadIdx.x; d < DD; d += 256)
        orow[d] = (bf16)((xr[d] - mu) * rs * g[d] + b[d]);
}

// ---------------- 32x32 transpose+convert tile helper ----------------
__device__ inline void convT_tile(const float* __restrict__ in, bf16* __restrict__ out,
                                  int K, int N, int k0, int n0) {
    __shared__ float tile[32][33];
    int tn = threadIdx.x & 31, tk = threadIdx.x >> 5;   // tk 0..7
#pragma unroll
    for (int i = 0; i < 4; ++i)
        tile[tk + i * 8][tn] = in[(size_t)(k0 + tk + i * 8) * N + n0 + tn];
    __syncthreads();
#pragma unroll
    for (int i = 0; i < 4; ++i)
        out[(size_t)(n0 + tk + i * 8) * K + k0 + tn] = (bf16)tile[tn][tk + i * 8];
}

// single-weight version (LM head)
__global__ __launch_bounds__(256) void convT_kernel(const float* __restrict__ in,
                                                    bf16* __restrict__ out,
                                                    int K, int N) {
    convT_tile(in, out, K, N, blockIdx.y * 32, blockIdx.x * 32);
}

// one layer's 4 weights in one launch
__global__ __launch_bounds__(256) void convT4_kernel(const float* __restrict__ w0,
                                                     const float* __restrict__ w1,
                                                     const float* __restrict__ w2,
                                                     const float* __restrict__ w3,
                                                     bf16* __restrict__ o0,
                                                     bf16* __restrict__ o1,
                                                     bf16* __restrict__ o2,
                                                     bf16* __restrict__ o3) {
    int bid = blockIdx.x;
    const float* in; bf16* out; int K, N, t;
    if (bid < 1728)      { in = w0; out = o0; K = 768;  N = 2304; t = bid; }          // Wqkv 24x72
    else if (bid < 2304) { in = w1; out = o1; K = 768;  N = 768;  t = bid - 1728; }   // Wo   24x24
    else if (bid < 4608) { in = w2; out = o2; K = 768;  N = 3072; t = bid - 2304; }   // W1   24x96
    else                 { in = w3; out = o3; K = 3072; N = 768;  t = bid - 4608; }   // W2   96x24
    int nt = N / 32;
    convT_tile(in, out, K, N, (t / nt) * 32, (t % nt) * 32);
}

// ---------------- bf16 MFMA GEMM: C = epi(A[M,K] @ Bt[N,K]^T + bias) ----------
// 2-phase double-buffered K-loop (T3 minimum recipe): per step
//   ds_read buf[cur] -> issue STAGE(buf[cur^1], k0+32) -> MFMA -> vmcnt(0)+s_barrier
// LDS tiles XOR-swizzled (chunk c of row r at c ^ ((r>>1)&3)); staging keeps LDS
// dest linear and pre-swizzles the per-lane GLOBAL source.
// EPI: 0 plain f32 (grid-swapped, LDS-transposed float4 stores); 1 +bias bf16;
//      2 +bias+res f32; 3 +bias GELU bf16; 4 qkv special
template<int BM, int EPI>
__global__ __launch_bounds__(256) void mgemm(const bf16* __restrict__ A,
                                             const bf16* __restrict__ Bt,
                                             const float* __restrict__ bias,
                                             const float* __restrict__ res,
                                             void* __restrict__ Cout,
                                             bf16* __restrict__ vtout,
                                             int M, int N, int K) {
    constexpr int MF = BM / 32;
    constexpr int NF = 4;
    constexpr int AIT = BM / 64;
    constexpr int ASZ = BM * 32;          // elements
    constexpr int BUFE = ASZ + 128 * 32;  // elements per phase buffer
    __shared__ __align__(16) bf16 smem[2 * BUFE];
    // EPI=0 (LM head): x = M-block so consecutive blocks share the B panel (L2)
    int bm = (EPI == 0 ? blockIdx.x : blockIdx.y) * BM;
    int bn = (EPI == 0 ? blockIdx.y : blockIdx.x) * 128;
    int tid = threadIdx.x;
    int lane = tid & 63;
    int w = tid >> 6;
    int wr = w >> 1, wc = w & 1;
    int l15 = lane & 15, g = lane >> 4;

    f32x4 acc[MF][NF];
#pragma unroll
    for (int m = 0; m < MF; ++m)
#pragma unroll
        for (int n = 0; n < NF; ++n) acc[m][n] = (f32x4){0.f, 0.f, 0.f, 0.f};

    int r = lane >> 2;
    int koff = ((lane & 3) ^ ((r >> 1) & 3)) * 8;     // pre-swizzled global source
    const bf16* Ab = A + (size_t)(bm + w * 16 + r) * K + koff;
    const bf16* Bb = Bt + (size_t)(bn + w * 16 + r) * K + koff;

    auto stage = [&](int p, int k0) {
        bf16* base = smem + p * BUFE;
        bf16* Asb = base + w * 16 * 32;
        bf16* Bsb = base + ASZ + w * 16 * 32;
#pragma unroll
        for (int it = 0; it < AIT; ++it)
            gload16(Ab + (size_t)(it * 64) * K + k0, Asb + it * 64 * 32);
#pragma unroll
        for (int it = 0; it < 2; ++it)
            gload16(Bb + (size_t)(it * 64) * K + k0, Bsb + it * 64 * 32);
    };

    stage(0, 0);
    __syncthreads();          // drains vmcnt(0), buf0 ready
    int cur = 0;

    for (int k0 = 0; k0 < K; k0 += 32) {
        const bf16* Ac = smem + cur * BUFE;
        const bf16* Bc = Ac + ASZ;
        bf16x8 af[MF], bfv[NF];
#pragma unroll
        for (int m = 0; m < MF; ++m) {
            int row = wr * (BM / 2) + m * 16 + l15;
            int gs = g ^ ((row >> 1) & 3);            // read-side swizzle
            af[m] = *(const bf16x8*)&Ac[row * 32 + gs * 8];
        }
#pragma unroll
        for (int n = 0; n < NF; ++n) {
            int row = wc * 64 + n * 16 + l15;
            int gs = g ^ ((row >> 1) & 3);
            bfv[n] = *(const bf16x8*)&Bc[row * 32 + gs * 8];
        }
        if (k0 + 32 < K) stage(cur ^ 1, k0 + 32);     // prefetch overlaps MFMA
#pragma unroll
        for (int m = 0; m < MF; ++m)
#pragma unroll
            for (int n = 0; n < NF; ++n)
                acc[m][n] = __builtin_amdgcn_mfma_f32_16x16x32_bf16(af[m], bfv[n], acc[m][n], 0, 0, 0);
        asm volatile("s_waitcnt vmcnt(0)" ::: "memory");   // next-tile stage landed
        __builtin_amdgcn_s_barrier();
        cur ^= 1;
    }

    int lq = g * 4;
    if (EPI == 0) {
        // transposed epilogue: per-wave LDS round-trip (aliased onto staging smem)
        float* elds = (float*)smem;
        float* eb = &elds[w * 16 * 68];
        int rr = lane >> 2, c0 = (lane & 3) * 16;
#pragma unroll
        for (int mf = 0; mf < MF; ++mf) {
#pragma unroll
            for (int n = 0; n < NF; ++n)
#pragma unroll
                for (int j = 0; j < 4; ++j)
                    eb[(lq + j) * 68 + n * 16 + l15] = acc[mf][n][j];
            __syncthreads();
            const float* src = &eb[rr * 68 + c0];
            float* dst = (float*)Cout + (size_t)(bm + wr * 64 + mf * 16 + rr) * N + bn + wc * 64 + c0;
            *(float4*)(dst + 0)  = *(const float4*)(src + 0);
            *(float4*)(dst + 4)  = *(const float4*)(src + 4);
            *(float4*)(dst + 8)  = *(const float4*)(src + 8);
            *(float4*)(dst + 12) = *(const float4*)(src + 12);
            __syncthreads();
        }
        return;
    }

#pragma unroll
    for (int m = 0; m < MF; ++m) {
#pragma unroll
        for (int n = 0; n < NF; ++n) {
            int col = bn + wc * 64 + n * 16 + l15;
            float bv = (EPI >= 1) ? bias[col] : 0.f;
            if (EPI == 4 && col >= 2 * DD) {
                int row0 = bm + wr * (BM / 2) + m * 16 + lq;
                int b = row0 >> 10, t0 = row0 & 1023;
                int hd = col - 2 * DD;
                union { bf16 h[4]; unsigned long long u; } pk;
#pragma unroll
                for (int j = 0; j < 4; ++j) pk.h[j] = (bf16)(acc[m][n][j] + bv);
                *(unsigned long long*)&vtout[((size_t)(b * DD + hd)) * TT + t0] = pk.u;
            } else {
#pragma unroll
                for (int j = 0; j < 4; ++j) {
                    int row = bm + wr * (BM / 2) + m * 16 + lq + j;
                    float v = acc[m][n][j] + bv;
                    if (EPI == 2) {
                        ((float*)Cout)[(size_t)row * N + col] = v + res[(size_t)row * N + col];
                    } else if (EPI == 3) {
                        v = 0.5f * v * (1.f + erff(v * 0.70710678118654752f));
                        ((bf16*)Cout)[(size_t)row * N + col] = (bf16)v;
                    } else if (EPI == 1) {
                        ((bf16*)Cout)[(size_t)row * N + col] = (bf16)v;
                    } else { // EPI == 4 Q/K columns
                        if (col < DD) v *= 0.125f;
                        ((bf16*)Cout)[(size_t)row * N + col] = (bf16)v;
                    }
                }
            }
        }
    }
}

// ---------------- MFMA flash attention ----------------
__global__ __launch_bounds__(256) void fattn_kernel(const bf16* __restrict__ qkv,
                                                    const bf16* __restrict__ vt,
                                                    bf16* __restrict__ o) {
    const int bh = blockIdx.y;
    const int b = bh / HH, h = bh % HH;
    const int q0 = blockIdx.x * 64;
    const int tid = threadIdx.x;
    const int w = tid >> 6, lane = tid & 63;
    const int l15 = lane & 15, g = lane >> 4;

    __shared__ __align__(16) bf16 Ks[64 * 64];
    __shared__ __align__(16) bf16 Vs[64 * 64];
    __shared__ __align__(16) bf16 Ps[4][16 * 64];

    const size_t basebt = (size_t)b * TT;
    const int qw = q0 + w * 16;
    const int qg = qw + l15;

    bf16x8 bq0, bq1;
    {
        const bf16* qp = qkv + (basebt + qw + l15) * 2304 + h * 64 + g * 8;
        bq0 = *(const bf16x8*)(qp);
        bq1 = *(const bf16x8*)(qp + 32);
    }

    float mstate = -1e30f, lstate = 0.f;
    f32x4 oacc[4];
#pragma unroll
    for (int nf = 0; nf < 4; ++nf) oacc[nf] = (f32x4){0.f, 0.f, 0.f, 0.f};

    const int swzA = (l15 & 7) << 4;
    char* const psBase = (char*)&Ps[w][0];

    const int nchunk = blockIdx.x + 1;
    for (int c = 0; c < nchunk; ++c) {
        const int kc = c * 64;
        __syncthreads();
        {
            int r0 = tid >> 3;
            int e0 = (tid & 7) * 8;
#pragma unroll
            for (int i = 0; i < 2; ++i) {
                int r = r0 + 32 * i;
                int swzW = (r & 7) << 4;
                bf16x8 kv = *(const bf16x8*)&qkv[(basebt + kc + r) * 2304 + DD + h * 64 + e0];
                *(bf16x8*)((char*)Ks + r * 128 + ((e0 * 2) ^ swzW)) = kv;
                bf16x8 vv = *(const bf16x8*)&vt[((size_t)bh * 64 + r) * TT + kc + e0];
                *(bf16x8*)((char*)Vs + r * 128 + ((e0 * 2) ^ swzW)) = vv;
            }
        }
        __syncthreads();
        if (kc > qw + 15) continue;

        f32x4 s[4];
#pragma unroll
        for (int mf = 0; mf < 4; ++mf) {
            char* kr = (char*)Ks + (16 * mf + l15) * 128;
            bf16x8 ka0 = *(const bf16x8*)(kr + ((16 * g) ^ swzA));
            bf16x8 ka1 = *(const bf16x8*)(kr + ((64 + 16 * g) ^ swzA));
            f32x4 a = (f32x4){0.f, 0.f, 0.f, 0.f};
            a = __builtin_amdgcn_mfma_f32_16x16x32_bf16(ka0, bq0, a, 0, 0, 0);
            a = __builtin_amdgcn_mfma_f32_16x16x32_bf16(ka1, bq1, a, 0, 0, 0);
            s[mf] = a;
        }
        if (kc + 63 > qw) {
#pragma unroll
            for (int mf = 0; mf < 4; ++mf)
#pragma unroll
                for (int j = 0; j < 4; ++j)
                    if (kc + 16 * mf + 4 * g + j > qg) s[mf][j] = -1e30f;
        }
        float cm = -1e30f;
#pragma unroll
        for (int mf = 0; mf < 4; ++mf)
#pragma unroll
            for (int j = 0; j < 4; ++j) cm = fmaxf(cm, s[mf][j]);
        cm = fmaxf(cm, __shfl_xor(cm, 16));
        cm = fmaxf(cm, __shfl_xor(cm, 32));
        float mnew = fmaxf(mstate, cm);
        float sc = __expf(mstate - mnew);
        mstate = mnew;
        float p[4][4];
        float psum = 0.f;
#pragma unroll
        for (int mf = 0; mf < 4; ++mf)
#pragma unroll
            for (int j = 0; j < 4; ++j) { float pv = __expf(s[mf][j] - mnew); p[mf][j] = pv; psum += pv; }
        psum += __shfl_xor(psum, 16);
        psum += __shfl_xor(psum, 32);
        lstate = lstate * sc + psum;
#pragma unroll
        for (int mf = 0; mf < 4; ++mf) {
            unsigned lo = pack_bf16x2(p[mf][0], p[mf][1]);
            unsigned hi = pack_bf16x2(p[mf][2], p[mf][3]);
            char* dst = psBase + l15 * 128 + ((32 * mf + 8 * g) ^ swzA);
            *(unsigned*)dst = lo;
            *(unsigned*)(dst + 4) = hi;
        }
        float s0 = __shfl(sc, 4 * g + 0), s1 = __shfl(sc, 4 * g + 1);
        float s2 = __shfl(sc, 4 * g + 2), s3 = __shfl(sc, 4 * g + 3);
#pragma unroll
        for (int nf = 0; nf < 4; ++nf) {
            oacc[nf][0] *= s0; oacc[nf][1] *= s1; oacc[nf][2] *= s2; oacc[nf][3] *= s3;
        }
        bf16x8 pa0 = *(const bf16x8*)(psBase + l15 * 128 + ((16 * g) ^ swzA));
        bf16x8 pa1 = *(const bf16x8*)(psBase + l15 * 128 + ((64 + 16 * g) ^ swzA));
#pragma unroll
        for (int nf = 0; nf < 4; ++nf) {
            char* vr = (char*)Vs + (16 * nf + l15) * 128;
            bf16x8 vb0 = *(const bf16x8*)(vr + ((16 * g) ^ swzA));
            bf16x8 vb1 = *(const bf16x8*)(vr + ((64 + 16 * g) ^ swzA));
            oacc[nf] = __builtin_amdgcn_mfma_f32_16x16x32_bf16(pa0, vb0, oacc[nf], 0, 0, 0);
            oacc[nf] = __builtin_amdgcn_mfma_f32_16x16x32_bf16(pa1, vb1, oacc[nf], 0, 0, 0);
        }
    }
    float linv = 1.f / lstate;
    float l0 = __shfl(linv, 4 * g + 0), l1 = __shfl(linv, 4 * g + 1);
    float l2 = __shfl(linv, 4 * g + 2), l3 = __shfl(linv, 4 * g + 3);
    float lj[4] = {l0, l1, l2, l3};
#pragma unroll
    for (int j = 0; j < 4; ++j) {
        bf16* orow = o + (size_t)(basebt + qw + 4 * g + j) * DD + h * 64 + l15;
#pragma unroll
        for (int nf = 0; nf < 4; ++nf)
            orow[16 * nf] = (bf16)(oacc[nf][j] * lj[j]);
    }
}

// ---------------- launcher ----------------
extern "C" void kernel_launch(void* const* d_in, const int* in_sizes, int n_in,
                              void* d_out, int out_size, void* d_ws, size_t ws_size,
                              hipStream_t stream) {
    (void)in_sizes; (void)n_in; (void)out_size; (void)ws_size;
    const int*   idx  = (const int*)d_in[0];
    const float* tok  = (const float*)d_in[1];
    const float* pos  = (const float*)d_in[2];
    const float* Wqkv = (const float*)d_in[3];
    const float* bqkv = (const float*)d_in[4];
    const float* Wo   = (const float*)d_in[5];
    const float* bo   = (const float*)d_in[6];
    const float* ln1g = (const float*)d_in[7];
    const float* ln1b = (const float*)d_in[8];
    const float* ln2g = (const float*)d_in[9];
    const float* ln2b = (const float*)d_in[10];
    const float* W1   = (const float*)d_in[11];
    const float* b1   = (const float*)d_in[12];
    const float* W2   = (const float*)d_in[13];
    const float* b2   = (const float*)d_in[14];
    const float* lnfg = (const float*)d_in[15];
    const float* lnfb = (const float*)d_in[16];
    const float* Wlm  = (const float*)d_in[17];
    float* out = (float*)d_out;

    char* ws = (char*)d_ws;
    float* x     = (float*)(ws);                       // 6,291,456
    bf16*  abuf0 = (bf16*)(ws + 6291456);              // 3,145,728
    bf16*  abuf1 = (bf16*)(ws + 9437184);              // 12,582,912
    bf16*  qkvb  = (bf16*)(ws + 22020096);             // 9,437,184
    bf16*  vtb   = (bf16*)(ws + 31457280);             // 3,145,728
    bf16*  wbuf  = (bf16*)(ws + 34603008);             // 49,152,000

    bf16* wq = wbuf;              // 2304x768
    bf16* wo = wbuf + 1769472;    // 768x768
    bf16* w1 = wbuf + 2359296;    // 3072x768
    bf16* w2 = wbuf + 4718592;    // 768x3072

    embed_kernel<<<NTOK, 256, 0, stream>>>(idx, tok, pos, x);

    for (int l = 0; l < LLAY; ++l) {
        convT4_kernel<<<6912, 256, 0, stream>>>(
            Wqkv + (size_t)l * DD * 3 * DD, Wo + (size_t)l * DD * DD,
            W1 + (size_t)l * DD * DFFN, W2 + (size_t)l * DFFN * DD,
            wq, wo, w1, w2);
        ln_kernel<<<NTOK, 256, 0, stream>>>(x, ln1g + l * DD, ln1b + l * DD, abuf0);
        mgemm<128, 4><<<dim3(3 * DD / 128, NTOK / 128), 256, 0, stream>>>(
            abuf0, wq, bqkv + (size_t)l * 3 * DD, nullptr, qkvb, vtb, NTOK, 3 * DD, DD);
        fattn_kernel<<<dim3(TT / 64, BB * HH), 256, 0, stream>>>(qkvb, vtb, abuf0);
        mgemm<64, 2><<<dim3(DD / 128, NTOK / 64), 256, 0, stream>>>(
            abuf0, wo, bo + (size_t)l * DD, x, x, nullptr, NTOK, DD, DD);
        ln_kernel<<<NTOK, 256, 0, stream>>>(x, ln2g + l * DD, ln2b + l * DD, abuf0);
        mgemm<128, 3><<<dim3(DFFN / 128, NTOK / 128), 256, 0, stream>>>(
            abuf0, w1, b1 + (size_t)l * DFFN, nullptr, abuf1, nullptr, NTOK, DFFN, DD);
        mgemm<64, 2><<<dim3(DD / 128, NTOK / 64), 256, 0, stream>>>(
            abuf1, w2, b2 + (size_t)l * DD, x, x, nullptr, NTOK, DD, DFFN);
    }
    ln_kernel<<<NTOK, 256, 0, stream>>>(x, lnfg, lnfb, abuf0);
    convT_kernel<<<dim3(32000 / 32, DD / 32), 256, 0, stream>>>(Wlm, wbuf, DD, 32000);
    // LM head: grid swapped (x = M-blocks) so consecutive blocks share B panel
    mgemm<128, 0><<<dim3(NTOK / 128, 32000 / 128), 256, 0, stream>>>(
        abuf0, wbuf, nullptr, nullptr, out, nullptr, NTOK, 32000, DD);
}

// Round 7
// 1023.697 us; speedup vs baseline: 7.1898x; 1.1226x over previous
//
#include <hip/hip_runtime.h>
#include <math.h>

#define TT   1024
#define DD   768
#define HH   12
#define LLAY 6
#define DFFN 3072
#define BB   2
#define NTOK (BB*TT)   // 2048

typedef __bf16 bf16;
typedef __attribute__((ext_vector_type(8))) __bf16 bf16x8;
typedef __attribute__((ext_vector_type(4))) __bf16 bf16x4;
typedef __attribute__((ext_vector_type(4))) float f32x4;

__device__ inline unsigned pack_bf16x2(float a, float b) {
    union { bf16 h[2]; unsigned u; } un;
    un.h[0] = (bf16)a; un.h[1] = (bf16)b;
    return un.u;
}

// async global->LDS, 16B per lane; LDS dest is wave-uniform base (+lane*16 by HW)
__device__ inline void gload16(const bf16* g, bf16* l) {
    __builtin_amdgcn_global_load_lds((const void*)g, (void*)l, 16, 0, 0);
}

template<int N> __device__ inline void waitcnt_vm() {
    if constexpr (N == 0) asm volatile("s_waitcnt vmcnt(0)" ::: "memory");
    else if constexpr (N == 3) asm volatile("s_waitcnt vmcnt(3)" ::: "memory");
    else if constexpr (N == 4) asm volatile("s_waitcnt vmcnt(4)" ::: "memory");
}

// ---------------- embedding ----------------
__global__ __launch_bounds__(256) void embed_kernel(const int* __restrict__ idx,
                                                    const float* __restrict__ tok,
                                                    const float* __restrict__ pos,
                                                    float* __restrict__ x) {
    int bt = blockIdx.x;
    int t  = bt % TT;
    int id = idx[bt];
    const float* te = tok + (size_t)id * DD;
    const float* pe = pos + (size_t)t * DD;
    float* xr = x + (size_t)bt * DD;
    for (int d = threadIdx.x; d < DD; d += 256) xr[d] = te[d] + pe[d];
}

// ---------------- layernorm: f32 in -> bf16 out ----------------
__global__ __launch_bounds__(256) void ln_kernel(const float* __restrict__ in,
                                                 const float* __restrict__ g,
                                                 const float* __restrict__ b,
                                                 bf16* __restrict__ out) {
    int row = blockIdx.x;
    const float* xr = in + (size_t)row * DD;
    float s = 0.f, s2 = 0.f;
    for (int d = threadIdx.x; d < DD; d += 256) { float v = xr[d]; s += v; s2 += v * v; }
    for (int off = 32; off; off >>= 1) { s += __shfl_down(s, off); s2 += __shfl_down(s2, off); }
    __shared__ float aS[4], aS2[4];
    __shared__ float mu_s, rs_s;
    int wid = threadIdx.x >> 6, lane = threadIdx.x & 63;
    if (lane == 0) { aS[wid] = s; aS2[wid] = s2; }
    __syncthreads();
    if (threadIdx.x == 0) {
        float t1 = aS[0] + aS[1] + aS[2] + aS[3];
        float t2 = aS2[0] + aS2[1] + aS2[2] + aS2[3];
        float mu = t1 / (float)DD;
        float var = t2 / (float)DD - mu * mu;
        mu_s = mu; rs_s = rsqrtf(var + 1e-5f);
    }
    __syncthreads();
    float mu = mu_s, rs = rs_s;
    bf16* orow = out + (size_t)row * DD;
    for (int d = threadIdx.x; d < DD; d += 256)
        orow[d] = (bf16)((xr[d] - mu) * rs * g[d] + b[d]);
}

// ---------------- 32x32 transpose+convert tile helper ----------------
__device__ inline void convT_tile(const float* __restrict__ in, bf16* __restrict__ out,
                                  int K, int N, int k0, int n0) {
    __shared__ float tile[32][33];
    int tn = threadIdx.x & 31, tk = threadIdx.x >> 5;   // tk 0..7
#pragma unroll
    for (int i = 0; i < 4; ++i)
        tile[tk + i * 8][tn] = in[(size_t)(k0 + tk + i * 8) * N + n0 + tn];
    __syncthreads();
#pragma unroll
    for (int i = 0; i < 4; ++i)
        out[(size_t)(n0 + tk + i * 8) * K + k0 + tn] = (bf16)tile[tn][tk + i * 8];
}

// single-weight version (LM head)
__global__ __launch_bounds__(256) void convT_kernel(const float* __restrict__ in,
                                                    bf16* __restrict__ out,
                                                    int K, int N) {
    convT_tile(in, out, K, N, blockIdx.y * 32, blockIdx.x * 32);
}

// one layer's 4 weights in one launch
__global__ __launch_bounds__(256) void convT4_kernel(const float* __restrict__ w0,
                                                     const float* __restrict__ w1,
                                                     const float* __restrict__ w2,
                                                     const float* __restrict__ w3,
                                                     bf16* __restrict__ o0,
                                                     bf16* __restrict__ o1,
                                                     bf16* __restrict__ o2,
                                                     bf16* __restrict__ o3) {
    int bid = blockIdx.x;
    const float* in; bf16* out; int K, N, t;
    if (bid < 1728)      { in = w0; out = o0; K = 768;  N = 2304; t = bid; }          // Wqkv 24x72
    else if (bid < 2304) { in = w1; out = o1; K = 768;  N = 768;  t = bid - 1728; }   // Wo   24x24
    else if (bid < 4608) { in = w2; out = o2; K = 768;  N = 3072; t = bid - 2304; }   // W1   24x96
    else                 { in = w3; out = o3; K = 3072; N = 768;  t = bid - 4608; }   // W2   96x24
    int nt = N / 32;
    convT_tile(in, out, K, N, (t / nt) * 32, (t % nt) * 32);
}

// ---------------- bf16 MFMA GEMM: C = epi(A[M,K] @ Bt[N,K]^T + bias) ----------
// 3-deep pipelined K-loop with COUNTED vmcnt (T4): per step
//   ds_read buf[cur] -> STAGE(buf[cur+2], k0+64) -> MFMA -> vmcnt(STG) -> barrier
// so each stage has ~2 K-steps to land. Tail steps fall back to vmcnt(0).
// LDS tiles XOR-swizzled (chunk c of row r at c ^ ((r>>1)&3)); staging keeps LDS
// dest linear and pre-swizzles the per-lane GLOBAL source.
// EPI: 0 plain f32 (grid-swapped, LDS-transposed float4 stores); 1 +bias bf16;
//      2 +bias+res f32; 3 +bias GELU bf16; 4 qkv special
template<int BM, int EPI>
__global__ __launch_bounds__(256) void mgemm(const bf16* __restrict__ A,
                                             const bf16* __restrict__ Bt,
                                             const float* __restrict__ bias,
                                             const float* __restrict__ res,
                                             void* __restrict__ Cout,
                                             bf16* __restrict__ vtout,
                                             int M, int N, int K) {
    constexpr int MF = BM / 32;
    constexpr int NF = 4;
    constexpr int AIT = BM / 64;
    constexpr int STG = AIT + 2;          // gloads per wave per stage
    constexpr int ASZ = BM * 32;          // elements
    constexpr int BUFE = ASZ + 128 * 32;  // elements per phase buffer
    __shared__ __align__(16) bf16 smem[3 * BUFE];
    // EPI=0 (LM head): x = M-block so consecutive blocks share the B panel (L2)
    int bm = (EPI == 0 ? blockIdx.x : blockIdx.y) * BM;
    int bn = (EPI == 0 ? blockIdx.y : blockIdx.x) * 128;
    int tid = threadIdx.x;
    int lane = tid & 63;
    int w = tid >> 6;
    int wr = w >> 1, wc = w & 1;
    int l15 = lane & 15, g = lane >> 4;

    f32x4 acc[MF][NF];
#pragma unroll
    for (int m = 0; m < MF; ++m)
#pragma unroll
        for (int n = 0; n < NF; ++n) acc[m][n] = (f32x4){0.f, 0.f, 0.f, 0.f};

    int r = lane >> 2;
    int koff = ((lane & 3) ^ ((r >> 1) & 3)) * 8;     // pre-swizzled global source
    const bf16* Ab = A + (size_t)(bm + w * 16 + r) * K + koff;
    const bf16* Bb = Bt + (size_t)(bn + w * 16 + r) * K + koff;

    auto stage = [&](int p, int k0) {
        bf16* base = smem + p * BUFE;
        bf16* Asb = base + w * 16 * 32;
        bf16* Bsb = base + ASZ + w * 16 * 32;
#pragma unroll
        for (int it = 0; it < AIT; ++it)
            gload16(Ab + (size_t)(it * 64) * K + k0, Asb + it * 64 * 32);
#pragma unroll
        for (int it = 0; it < 2; ++it)
            gload16(Bb + (size_t)(it * 64) * K + k0, Bsb + it * 64 * 32);
    };

    stage(0, 0);
    stage(1, 32);
    waitcnt_vm<STG>();        // buf0 landed (stage1 still in flight)
    __builtin_amdgcn_s_barrier();
    int cur = 0;

    for (int k0 = 0; k0 < K; k0 += 32) {
        const bf16* Ac = smem + cur * BUFE;
        const bf16* Bc = Ac + ASZ;
        bf16x8 af[MF], bfv[NF];
#pragma unroll
        for (int m = 0; m < MF; ++m) {
            int row = wr * (BM / 2) + m * 16 + l15;
            int gs = g ^ ((row >> 1) & 3);            // read-side swizzle
            af[m] = *(const bf16x8*)&Ac[row * 32 + gs * 8];
        }
#pragma unroll
        for (int n = 0; n < NF; ++n) {
            int row = wc * 64 + n * 16 + l15;
            int gs = g ^ ((row >> 1) & 3);
            bfv[n] = *(const bf16x8*)&Bc[row * 32 + gs * 8];
        }
        bool st = (k0 + 64 < K);
        if (st) {
            int nxt = cur + 2; if (nxt >= 3) nxt -= 3;
            stage(nxt, k0 + 64);                      // lands ~2 K-steps later
        }
#pragma unroll
        for (int m = 0; m < MF; ++m)
#pragma unroll
            for (int n = 0; n < NF; ++n)
                acc[m][n] = __builtin_amdgcn_mfma_f32_16x16x32_bf16(af[m], bfv[n], acc[m][n], 0, 0, 0);
        if (st) waitcnt_vm<STG>();    // prev stage landed; this one stays in flight
        else    waitcnt_vm<0>();
        __builtin_amdgcn_s_barrier();
        cur = (cur == 2) ? 0 : cur + 1;
    }

    int lq = g * 4;
    if (EPI == 0) {
        // transposed epilogue: per-wave LDS round-trip (aliased onto staging smem)
        float* elds = (float*)smem;
        float* eb = &elds[w * 16 * 68];
        int rr = lane >> 2, c0 = (lane & 3) * 16;
#pragma unroll
        for (int mf = 0; mf < MF; ++mf) {
#pragma unroll
            for (int n = 0; n < NF; ++n)
#pragma unroll
                for (int j = 0; j < 4; ++j)
                    eb[(lq + j) * 68 + n * 16 + l15] = acc[mf][n][j];
            __syncthreads();
            const float* src = &eb[rr * 68 + c0];
            float* dst = (float*)Cout + (size_t)(bm + wr * 64 + mf * 16 + rr) * N + bn + wc * 64 + c0;
            *(float4*)(dst + 0)  = *(const float4*)(src + 0);
            *(float4*)(dst + 4)  = *(const float4*)(src + 4);
            *(float4*)(dst + 8)  = *(const float4*)(src + 8);
            *(float4*)(dst + 12) = *(const float4*)(src + 12);
            __syncthreads();
        }
        return;
    }

#pragma unroll
    for (int m = 0; m < MF; ++m) {
#pragma unroll
        for (int n = 0; n < NF; ++n) {
            int col = bn + wc * 64 + n * 16 + l15;
            float bv = (EPI >= 1) ? bias[col] : 0.f;
            if (EPI == 4 && col >= 2 * DD) {
                int row0 = bm + wr * (BM / 2) + m * 16 + lq;
                int b = row0 >> 10, t0 = row0 & 1023;
                int hd = col - 2 * DD;
                union { bf16 h[4]; unsigned long long u; } pk;
#pragma unroll
                for (int j = 0; j < 4; ++j) pk.h[j] = (bf16)(acc[m][n][j] + bv);
                *(unsigned long long*)&vtout[((size_t)(b * DD + hd)) * TT + t0] = pk.u;
            } else {
#pragma unroll
                for (int j = 0; j < 4; ++j) {
                    int row = bm + wr * (BM / 2) + m * 16 + lq + j;
                    float v = acc[m][n][j] + bv;
                    if (EPI == 2) {
                        ((float*)Cout)[(size_t)row * N + col] = v + res[(size_t)row * N + col];
                    } else if (EPI == 3) {
                        v = 0.5f * v * (1.f + erff(v * 0.70710678118654752f));
                        ((bf16*)Cout)[(size_t)row * N + col] = (bf16)v;
                    } else if (EPI == 1) {
                        ((bf16*)Cout)[(size_t)row * N + col] = (bf16)v;
                    } else { // EPI == 4 Q/K columns
                        if (col < DD) v *= 0.125f;
                        ((bf16*)Cout)[(size_t)row * N + col] = (bf16)v;
                    }
                }
            }
        }
    }
}

// ---------------- MFMA flash attention ----------------
__global__ __launch_bounds__(256) void fattn_kernel(const bf16* __restrict__ qkv,
                                                    const bf16* __restrict__ vt,
                                                    bf16* __restrict__ o) {
    const int bh = blockIdx.y;
    const int b = bh / HH, h = bh % HH;
    const int q0 = blockIdx.x * 64;
    const int tid = threadIdx.x;
    const int w = tid >> 6, lane = tid & 63;
    const int l15 = lane & 15, g = lane >> 4;

    __shared__ __align__(16) bf16 Ks[64 * 64];
    __shared__ __align__(16) bf16 Vs[64 * 64];
    __shared__ __align__(16) bf16 Ps[4][16 * 64];

    const size_t basebt = (size_t)b * TT;
    const int qw = q0 + w * 16;
    const int qg = qw + l15;

    bf16x8 bq0, bq1;
    {
        const bf16* qp = qkv + (basebt + qw + l15) * 2304 + h * 64 + g * 8;
        bq0 = *(const bf16x8*)(qp);
        bq1 = *(const bf16x8*)(qp + 32);
    }

    float mstate = -1e30f, lstate = 0.f;
    f32x4 oacc[4];
#pragma unroll
    for (int nf = 0; nf < 4; ++nf) oacc[nf] = (f32x4){0.f, 0.f, 0.f, 0.f};

    const int swzA = (l15 & 7) << 4;
    char* const psBase = (char*)&Ps[w][0];

    const int nchunk = blockIdx.x + 1;
    for (int c = 0; c < nchunk; ++c) {
        const int kc = c * 64;
        __syncthreads();
        {
            int r0 = tid >> 3;
            int e0 = (tid & 7) * 8;
#pragma unroll
            for (int i = 0; i < 2; ++i) {
                int r = r0 + 32 * i;
                int swzW = (r & 7) << 4;
                bf16x8 kv = *(const bf16x8*)&qkv[(basebt + kc + r) * 2304 + DD + h * 64 + e0];
                *(bf16x8*)((char*)Ks + r * 128 + ((e0 * 2) ^ swzW)) = kv;
                bf16x8 vv = *(const bf16x8*)&vt[((size_t)bh * 64 + r) * TT + kc + e0];
                *(bf16x8*)((char*)Vs + r * 128 + ((e0 * 2) ^ swzW)) = vv;
            }
        }
        __syncthreads();
        if (kc > qw + 15) continue;

        f32x4 s[4];
        __builtin_amdgcn_s_setprio(1);
#pragma unroll
        for (int mf = 0; mf < 4; ++mf) {
            char* kr = (char*)Ks + (16 * mf + l15) * 128;
            bf16x8 ka0 = *(const bf16x8*)(kr + ((16 * g) ^ swzA));
            bf16x8 ka1 = *(const bf16x8*)(kr + ((64 + 16 * g) ^ swzA));
            f32x4 a = (f32x4){0.f, 0.f, 0.f, 0.f};
            a = __builtin_amdgcn_mfma_f32_16x16x32_bf16(ka0, bq0, a, 0, 0, 0);
            a = __builtin_amdgcn_mfma_f32_16x16x32_bf16(ka1, bq1, a, 0, 0, 0);
            s[mf] = a;
        }
        __builtin_amdgcn_s_setprio(0);
        if (kc + 63 > qw) {
#pragma unroll
            for (int mf = 0; mf < 4; ++mf)
#pragma unroll
                for (int j = 0; j < 4; ++j)
                    if (kc + 16 * mf + 4 * g + j > qg) s[mf][j] = -1e30f;
        }
        float cm = -1e30f;
#pragma unroll
        for (int mf = 0; mf < 4; ++mf)
#pragma unroll
            for (int j = 0; j < 4; ++j) cm = fmaxf(cm, s[mf][j]);
        cm = fmaxf(cm, __shfl_xor(cm, 16));
        cm = fmaxf(cm, __shfl_xor(cm, 32));
        float mnew = fmaxf(mstate, cm);
        float sc = __expf(mstate - mnew);
        mstate = mnew;
        float p[4][4];
        float psum = 0.f;
#pragma unroll
        for (int mf = 0; mf < 4; ++mf)
#pragma unroll
            for (int j = 0; j < 4; ++j) { float pv = __expf(s[mf][j] - mnew); p[mf][j] = pv; psum += pv; }
        psum += __shfl_xor(psum, 16);
        psum += __shfl_xor(psum, 32);
        lstate = lstate * sc + psum;
#pragma unroll
        for (int mf = 0; mf < 4; ++mf) {
            unsigned lo = pack_bf16x2(p[mf][0], p[mf][1]);
            unsigned hi = pack_bf16x2(p[mf][2], p[mf][3]);
            char* dst = psBase + l15 * 128 + ((32 * mf + 8 * g) ^ swzA);
            *(unsigned*)dst = lo;
            *(unsigned*)(dst + 4) = hi;
        }
        float s0 = __shfl(sc, 4 * g + 0), s1 = __shfl(sc, 4 * g + 1);
        float s2 = __shfl(sc, 4 * g + 2), s3 = __shfl(sc, 4 * g + 3);
#pragma unroll
        for (int nf = 0; nf < 4; ++nf) {
            oacc[nf][0] *= s0; oacc[nf][1] *= s1; oacc[nf][2] *= s2; oacc[nf][3] *= s3;
        }
        bf16x8 pa0 = *(const bf16x8*)(psBase + l15 * 128 + ((16 * g) ^ swzA));
        bf16x8 pa1 = *(const bf16x8*)(psBase + l15 * 128 + ((64 + 16 * g) ^ swzA));
        __builtin_amdgcn_s_setprio(1);
#pragma unroll
        for (int nf = 0; nf < 4; ++nf) {
            char* vr = (char*)Vs + (16 * nf + l15) * 128;
            bf16x8 vb0 = *(const bf16x8*)(vr + ((16 * g) ^ swzA));
            bf16x8 vb1 = *(const bf16x8*)(vr + ((64 + 16 * g) ^ swzA));
            oacc[nf] = __builtin_amdgcn_mfma_f32_16x16x32_bf16(pa0, vb0, oacc[nf], 0, 0, 0);
            oacc[nf] = __builtin_amdgcn_mfma_f32_16x16x32_bf16(pa1, vb1, oacc[nf], 0, 0, 0);
        }
        __builtin_amdgcn_s_setprio(0);
    }
    float linv = 1.f / lstate;
    float l0 = __shfl(linv, 4 * g + 0), l1 = __shfl(linv, 4 * g + 1);
    float l2 = __shfl(linv, 4 * g + 2), l3 = __shfl(linv, 4 * g + 3);
    float lj[4] = {l0, l1, l2, l3};
#pragma unroll
    for (int j = 0; j < 4; ++j) {
        bf16* orow = o + (size_t)(basebt + qw + 4 * g + j) * DD + h * 64 + l15;
#pragma unroll
        for (int nf = 0; nf < 4; ++nf)
            orow[16 * nf] = (bf16)(oacc[nf][j] * lj[j]);
    }
}

// ---------------- launcher ----------------
extern "C" void kernel_launch(void* const* d_in, const int* in_sizes, int n_in,
                              void* d_out, int out_size, void* d_ws, size_t ws_size,
                              hipStream_t stream) {
    (void)in_sizes; (void)n_in; (void)out_size; (void)ws_size;
    const int*   idx  = (const int*)d_in[0];
    const float* tok  = (const float*)d_in[1];
    const float* pos  = (const float*)d_in[2];
    const float* Wqkv = (const float*)d_in[3];
    const float* bqkv = (const float*)d_in[4];
    const float* Wo   = (const float*)d_in[5];
    const float* bo   = (const float*)d_in[6];
    const float* ln1g = (const float*)d_in[7];
    const float* ln1b = (const float*)d_in[8];
    const float* ln2g = (const float*)d_in[9];
    const float* ln2b = (const float*)d_in[10];
    const float* W1   = (const float*)d_in[11];
    const float* b1   = (const float*)d_in[12];
    const float* W2   = (const float*)d_in[13];
    const float* b2   = (const float*)d_in[14];
    const float* lnfg = (const float*)d_in[15];
    const float* lnfb = (const float*)d_in[16];
    const float* Wlm  = (const float*)d_in[17];
    float* out = (float*)d_out;

    char* ws = (char*)d_ws;
    float* x     = (float*)(ws);                       // 6,291,456
    bf16*  abuf0 = (bf16*)(ws + 6291456);              // 3,145,728
    bf16*  abuf1 = (bf16*)(ws + 9437184);              // 12,582,912
    bf16*  qkvb  = (bf16*)(ws + 22020096);             // 9,437,184
    bf16*  vtb   = (bf16*)(ws + 31457280);             // 3,145,728
    bf16*  wbuf  = (bf16*)(ws + 34603008);             // 49,152,000

    bf16* wq = wbuf;              // 2304x768
    bf16* wo = wbuf + 1769472;    // 768x768
    bf16* w1 = wbuf + 2359296;    // 3072x768
    bf16* w2 = wbuf + 4718592;    // 768x3072

    embed_kernel<<<NTOK, 256, 0, stream>>>(idx, tok, pos, x);

    for (int l = 0; l < LLAY; ++l) {
        convT4_kernel<<<6912, 256, 0, stream>>>(
            Wqkv + (size_t)l * DD * 3 * DD, Wo + (size_t)l * DD * DD,
            W1 + (size_t)l * DD * DFFN, W2 + (size_t)l * DFFN * DD,
            wq, wo, w1, w2);
        ln_kernel<<<NTOK, 256, 0, stream>>>(x, ln1g + l * DD, ln1b + l * DD, abuf0);
        mgemm<128, 4><<<dim3(3 * DD / 128, NTOK / 128), 256, 0, stream>>>(
            abuf0, wq, bqkv + (size_t)l * 3 * DD, nullptr, qkvb, vtb, NTOK, 3 * DD, DD);
        fattn_kernel<<<dim3(TT / 64, BB * HH), 256, 0, stream>>>(qkvb, vtb, abuf0);
        mgemm<64, 2><<<dim3(DD / 128, NTOK / 64), 256, 0, stream>>>(
            abuf0, wo, bo + (size_t)l * DD, x, x, nullptr, NTOK, DD, DD);
        ln_kernel<<<NTOK, 256, 0, stream>>>(x, ln2g + l * DD, ln2b + l * DD, abuf0);
        mgemm<128, 3><<<dim3(DFFN / 128, NTOK / 128), 256, 0, stream>>>(
            abuf0, w1, b1 + (size_t)l * DFFN, nullptr, abuf1, nullptr, NTOK, DFFN, DD);
        mgemm<64, 2><<<dim3(DD / 128, NTOK / 64), 256, 0, stream>>>(
            abuf1, w2, b2 + (size_t)l * DD, x, x, nullptr, NTOK, DD, DFFN);
    }
    ln_kernel<<<NTOK, 256, 0, stream>>>(x, lnfg, lnfb, abuf0);
    convT_kernel<<<dim3(32000 / 32, DD / 32), 256, 0, stream>>>(Wlm, wbuf, DD, 32000);
    // LM head: grid swapped (x = M-blocks) so consecutive blocks share B panel
    mgemm<128, 0><<<dim3(NTOK / 128, 32000 / 128), 256, 0, stream>>>(
        abuf0, wbuf, nullptr, nullptr, out, nullptr, NTOK, 32000, DD);
}

// Round 8
// 1008.101 us; speedup vs baseline: 7.3010x; 1.0155x over previous
//
#include <hip/hip_runtime.h>
#include <math.h>

#define TT   1024
#define DD   768
#define HH   12
#define LLAY 6
#define DFFN 3072
#define BB   2
#define NTOK (BB*TT)   // 2048

typedef __bf16 bf16;
typedef __attribute__((ext_vector_type(8))) __bf16 bf16x8;
typedef __attribute__((ext_vector_type(4))) __bf16 bf16x4;
typedef __attribute__((ext_vector_type(4))) float f32x4;

__device__ inline unsigned pack_bf16x2(float a, float b) {
    union { bf16 h[2]; unsigned u; } un;
    un.h[0] = (bf16)a; un.h[1] = (bf16)b;
    return un.u;
}

// async global->LDS, 16B per lane; LDS dest is wave-uniform base (+lane*16 by HW)
__device__ inline void gload16(const bf16* g, bf16* l) {
    __builtin_amdgcn_global_load_lds((const void*)g, (void*)l, 16, 0, 0);
}

template<int N> __device__ inline void waitcnt_vm() {
    if constexpr (N == 0) asm volatile("s_waitcnt vmcnt(0)" ::: "memory");
    else if constexpr (N == 3) asm volatile("s_waitcnt vmcnt(3)" ::: "memory");
    else if constexpr (N == 4) asm volatile("s_waitcnt vmcnt(4)" ::: "memory");
}

// ---------------- embedding ----------------
__global__ __launch_bounds__(256) void embed_kernel(const int* __restrict__ idx,
                                                    const float* __restrict__ tok,
                                                    const float* __restrict__ pos,
                                                    float* __restrict__ x) {
    int bt = blockIdx.x;
    int t  = bt % TT;
    int id = idx[bt];
    const float* te = tok + (size_t)id * DD;
    const float* pe = pos + (size_t)t * DD;
    float* xr = x + (size_t)bt * DD;
    for (int d = threadIdx.x; d < DD; d += 256) xr[d] = te[d] + pe[d];
}

// ---------------- layernorm: f32 in -> bf16 out ----------------
__global__ __launch_bounds__(256) void ln_kernel(const float* __restrict__ in,
                                                 const float* __restrict__ g,
                                                 const float* __restrict__ b,
                                                 bf16* __restrict__ out) {
    int row = blockIdx.x;
    const float* xr = in + (size_t)row * DD;
    float s = 0.f, s2 = 0.f;
    for (int d = threadIdx.x; d < DD; d += 256) { float v = xr[d]; s += v; s2 += v * v; }
    for (int off = 32; off; off >>= 1) { s += __shfl_down(s, off); s2 += __shfl_down(s2, off); }
    __shared__ float aS[4], aS2[4];
    __shared__ float mu_s, rs_s;
    int wid = threadIdx.x >> 6, lane = threadIdx.x & 63;
    if (lane == 0) { aS[wid] = s; aS2[wid] = s2; }
    __syncthreads();
    if (threadIdx.x == 0) {
        float t1 = aS[0] + aS[1] + aS[2] + aS[3];
        float t2 = aS2[0] + aS2[1] + aS2[2] + aS2[3];
        float mu = t1 / (float)DD;
        float var = t2 / (float)DD - mu * mu;
        mu_s = mu; rs_s = rsqrtf(var + 1e-5f);
    }
    __syncthreads();
    float mu = mu_s, rs = rs_s;
    bf16* orow = out + (size_t)row * DD;
    for (int d = threadIdx.x; d < DD; d += 256)
        orow[d] = (bf16)((xr[d] - mu) * rs * g[d] + b[d]);
}

// ---------------- 32x32 transpose+convert tile helper ----------------
__device__ inline void convT_tile(const float* __restrict__ in, bf16* __restrict__ out,
                                  int K, int N, int k0, int n0) {
    __shared__ float tile[32][33];
    int tn = threadIdx.x & 31, tk = threadIdx.x >> 5;   // tk 0..7
#pragma unroll
    for (int i = 0; i < 4; ++i)
        tile[tk + i * 8][tn] = in[(size_t)(k0 + tk + i * 8) * N + n0 + tn];
    __syncthreads();
#pragma unroll
    for (int i = 0; i < 4; ++i)
        out[(size_t)(n0 + tk + i * 8) * K + k0 + tn] = (bf16)tile[tn][tk + i * 8];
}

// single-weight version (LM head)
__global__ __launch_bounds__(256) void convT_kernel(const float* __restrict__ in,
                                                    bf16* __restrict__ out,
                                                    int K, int N) {
    convT_tile(in, out, K, N, blockIdx.y * 32, blockIdx.x * 32);
}

// one layer's 4 weights in one launch
__global__ __launch_bounds__(256) void convT4_kernel(const float* __restrict__ w0,
                                                     const float* __restrict__ w1,
                                                     const float* __restrict__ w2,
                                                     const float* __restrict__ w3,
                                                     bf16* __restrict__ o0,
                                                     bf16* __restrict__ o1,
                                                     bf16* __restrict__ o2,
                                                     bf16* __restrict__ o3) {
    int bid = blockIdx.x;
    const float* in; bf16* out; int K, N, t;
    if (bid < 1728)      { in = w0; out = o0; K = 768;  N = 2304; t = bid; }          // Wqkv 24x72
    else if (bid < 2304) { in = w1; out = o1; K = 768;  N = 768;  t = bid - 1728; }   // Wo   24x24
    else if (bid < 4608) { in = w2; out = o2; K = 768;  N = 3072; t = bid - 2304; }   // W1   24x96
    else                 { in = w3; out = o3; K = 3072; N = 768;  t = bid - 4608; }   // W2   96x24
    int nt = N / 32;
    convT_tile(in, out, K, N, (t / nt) * 32, (t % nt) * 32);
}

// ---------------- bf16 MFMA GEMM (layer GEMMs): 3-deep counted-vmcnt ----------
// EPI: 1 +bias bf16; 2 +bias+res f32; 3 +bias GELU bf16; 4 qkv special
template<int BM, int EPI>
__global__ __launch_bounds__(256) void mgemm(const bf16* __restrict__ A,
                                             const bf16* __restrict__ Bt,
                                             const float* __restrict__ bias,
                                             const float* __restrict__ res,
                                             void* __restrict__ Cout,
                                             bf16* __restrict__ vtout,
                                             int M, int N, int K) {
    constexpr int MF = BM / 32;
    constexpr int NF = 4;
    constexpr int AIT = BM / 64;
    constexpr int STG = AIT + 2;          // gloads per wave per stage
    constexpr int ASZ = BM * 32;          // elements
    constexpr int BUFE = ASZ + 128 * 32;  // elements per phase buffer
    __shared__ __align__(16) bf16 smem[3 * BUFE];
    int bm = blockIdx.y * BM;
    int bn = blockIdx.x * 128;
    int tid = threadIdx.x;
    int lane = tid & 63;
    int w = tid >> 6;
    int wr = w >> 1, wc = w & 1;
    int l15 = lane & 15, g = lane >> 4;

    f32x4 acc[MF][NF];
#pragma unroll
    for (int m = 0; m < MF; ++m)
#pragma unroll
        for (int n = 0; n < NF; ++n) acc[m][n] = (f32x4){0.f, 0.f, 0.f, 0.f};

    int r = lane >> 2;
    int koff = ((lane & 3) ^ ((r >> 1) & 3)) * 8;     // pre-swizzled global source
    const bf16* Ab = A + (size_t)(bm + w * 16 + r) * K + koff;
    const bf16* Bb = Bt + (size_t)(bn + w * 16 + r) * K + koff;

    auto stage = [&](int p, int k0) {
        bf16* base = smem + p * BUFE;
        bf16* Asb = base + w * 16 * 32;
        bf16* Bsb = base + ASZ + w * 16 * 32;
#pragma unroll
        for (int it = 0; it < AIT; ++it)
            gload16(Ab + (size_t)(it * 64) * K + k0, Asb + it * 64 * 32);
#pragma unroll
        for (int it = 0; it < 2; ++it)
            gload16(Bb + (size_t)(it * 64) * K + k0, Bsb + it * 64 * 32);
    };

    stage(0, 0);
    stage(1, 32);
    waitcnt_vm<STG>();        // buf0 landed (stage1 still in flight)
    __builtin_amdgcn_s_barrier();
    int cur = 0;

    for (int k0 = 0; k0 < K; k0 += 32) {
        const bf16* Ac = smem + cur * BUFE;
        const bf16* Bc = Ac + ASZ;
        bf16x8 af[MF], bfv[NF];
#pragma unroll
        for (int m = 0; m < MF; ++m) {
            int row = wr * (BM / 2) + m * 16 + l15;
            int gs = g ^ ((row >> 1) & 3);            // read-side swizzle
            af[m] = *(const bf16x8*)&Ac[row * 32 + gs * 8];
        }
#pragma unroll
        for (int n = 0; n < NF; ++n) {
            int row = wc * 64 + n * 16 + l15;
            int gs = g ^ ((row >> 1) & 3);
            bfv[n] = *(const bf16x8*)&Bc[row * 32 + gs * 8];
        }
        bool st = (k0 + 64 < K);
        if (st) {
            int nxt = cur + 2; if (nxt >= 3) nxt -= 3;
            stage(nxt, k0 + 64);                      // lands ~2 K-steps later
        }
#pragma unroll
        for (int m = 0; m < MF; ++m)
#pragma unroll
            for (int n = 0; n < NF; ++n)
                acc[m][n] = __builtin_amdgcn_mfma_f32_16x16x32_bf16(af[m], bfv[n], acc[m][n], 0, 0, 0);
        if (st) waitcnt_vm<STG>();    // prev stage landed; this one stays in flight
        else    waitcnt_vm<0>();
        __builtin_amdgcn_s_barrier();
        cur = (cur == 2) ? 0 : cur + 1;
    }

    int lq = g * 4;
#pragma unroll
    for (int m = 0; m < MF; ++m) {
#pragma unroll
        for (int n = 0; n < NF; ++n) {
            int col = bn + wc * 64 + n * 16 + l15;
            float bv = bias[col];
            if (EPI == 4 && col >= 2 * DD) {
                int row0 = bm + wr * (BM / 2) + m * 16 + lq;
                int b = row0 >> 10, t0 = row0 & 1023;
                int hd = col - 2 * DD;
                union { bf16 h[4]; unsigned long long u; } pk;
#pragma unroll
                for (int j = 0; j < 4; ++j) pk.h[j] = (bf16)(acc[m][n][j] + bv);
                *(unsigned long long*)&vtout[((size_t)(b * DD + hd)) * TT + t0] = pk.u;
            } else {
#pragma unroll
                for (int j = 0; j < 4; ++j) {
                    int row = bm + wr * (BM / 2) + m * 16 + lq + j;
                    float v = acc[m][n][j] + bv;
                    if (EPI == 2) {
                        ((float*)Cout)[(size_t)row * N + col] = v + res[(size_t)row * N + col];
                    } else if (EPI == 3) {
                        v = 0.5f * v * (1.f + erff(v * 0.70710678118654752f));
                        ((bf16*)Cout)[(size_t)row * N + col] = (bf16)v;
                    } else if (EPI == 1) {
                        ((bf16*)Cout)[(size_t)row * N + col] = (bf16)v;
                    } else { // EPI == 4 Q/K columns
                        if (col < DD) v *= 0.125f;
                        ((bf16*)Cout)[(size_t)row * N + col] = (bf16)v;
                    }
                }
            }
        }
    }
}

// ---------------- LM head GEMM: 256x256 tile, 8 waves, BK=64 ----------------
// C[2048][32000] f32 = A[2048][768] @ Bt[32000][768]^T
// Wave (wm,wn) = (w>>2, w&3) owns 128x64. acc[8][4]. 2 LDS buffers of 64KB.
// Per K-tile: issue A-stage -> ds_read ks0 -> MFMA -> issue B-stage -> ds_read
// ks1 -> MFMA -> __syncthreads (implicit vmcnt0 drain; loads were issued early).
// 8-chunk XOR swizzle: logical chunk c of row r lives at c ^ ((r>>1)&7).
__global__ __launch_bounds__(512, 2) void lmgemm(const bf16* __restrict__ A,
                                                 const bf16* __restrict__ Bt,
                                                 float* __restrict__ C) {
    constexpr int BUFE = 2 * 256 * 64;       // A+B elements per buffer
    __shared__ __align__(16) bf16 smem[2 * BUFE];   // 128 KiB
    const int tid = threadIdx.x;
    const int w = tid >> 6, lane = tid & 63;
    const int wm = w >> 2, wn = w & 3;
    const int l15 = lane & 15, g = lane >> 4;
    const int bm = blockIdx.x * 256;
    const int bn = blockIdx.y * 256;

    // fragment read offsets: row swizzle reduces to (l15>>1)&7 (mf/wm drop out)
    const int swzr = (l15 >> 1) & 7;
    const int pc0 = (g ^ swzr) * 8;          // ks0 element offset; ks1 = pc0^32

    // staging source pointers (inverse-swizzled global addresses)
    const int r8 = lane >> 3, c8 = lane & 7;
    const bf16* agp[4]; const bf16* bgp[4];
    int aldso[4], bldso[4];
#pragma unroll
    for (int j = 0; j < 4; ++j) {
        int br = w * 32 + j * 8 + r8;        // 0..255 within tile
        int swz = (br >> 1) & 7;
        agp[j] = A  + (size_t)(bm + br) * DD + (c8 ^ swz) * 8;
        bgp[j] = Bt + (size_t)(bn + br) * DD + (c8 ^ swz) * 8;
        aldso[j] = (w * 32 + j * 8) * 64;
        bldso[j] = 256 * 64 + (w * 32 + j * 8) * 64;
    }

    f32x4 acc[8][4];
#pragma unroll
    for (int m = 0; m < 8; ++m)
#pragma unroll
        for (int n = 0; n < 4; ++n) acc[m][n] = (f32x4){0.f, 0.f, 0.f, 0.f};

    {   // prologue: stage tile 0
        bf16* base = smem;
#pragma unroll
        for (int j = 0; j < 4; ++j) gload16(agp[j], base + aldso[j]);
#pragma unroll
        for (int j = 0; j < 4; ++j) gload16(bgp[j], base + bldso[j]);
    }
    __syncthreads();
    int cur = 0;

    for (int t = 0; t < 12; ++t) {
        const bf16* Ar = smem + cur * BUFE;
        const bf16* Br = Ar + 256 * 64;
        bf16* nbase = smem + (cur ^ 1) * BUFE;
        const int k0n = (t + 1) * 64;
        const bool st = (t < 11);
        if (st) {
#pragma unroll
            for (int j = 0; j < 4; ++j) gload16(agp[j] + k0n, nbase + aldso[j]);
        }
        bf16x8 af[8], bfv[4];
        // ---- ks = 0 ----
#pragma unroll
        for (int m = 0; m < 8; ++m)
            af[m] = *(const bf16x8*)&Ar[(wm * 128 + m * 16 + l15) * 64 + pc0];
#pragma unroll
        for (int n = 0; n < 4; ++n)
            bfv[n] = *(const bf16x8*)&Br[(wn * 64 + n * 16 + l15) * 64 + pc0];
        __builtin_amdgcn_s_setprio(1);
#pragma unroll
        for (int m = 0; m < 8; ++m)
#pragma unroll
            for (int n = 0; n < 4; ++n)
                acc[m][n] = __builtin_amdgcn_mfma_f32_16x16x32_bf16(af[m], bfv[n], acc[m][n], 0, 0, 0);
        __builtin_amdgcn_s_setprio(0);
        if (st) {
#pragma unroll
            for (int j = 0; j < 4; ++j) gload16(bgp[j] + k0n, nbase + bldso[j]);
        }
        // ---- ks = 1 ----
#pragma unroll
        for (int m = 0; m < 8; ++m)
            af[m] = *(const bf16x8*)&Ar[(wm * 128 + m * 16 + l15) * 64 + (pc0 ^ 32)];
#pragma unroll
        for (int n = 0; n < 4; ++n)
            bfv[n] = *(const bf16x8*)&Br[(wn * 64 + n * 16 + l15) * 64 + (pc0 ^ 32)];
        __builtin_amdgcn_s_setprio(1);
#pragma unroll
        for (int m = 0; m < 8; ++m)
#pragma unroll
            for (int n = 0; n < 4; ++n)
                acc[m][n] = __builtin_amdgcn_mfma_f32_16x16x32_bf16(af[m], bfv[n], acc[m][n], 0, 0, 0);
        __builtin_amdgcn_s_setprio(0);
        __syncthreads();            // drains vmcnt(0): next buffer published
        cur ^= 1;
    }

    // epilogue: per-wave LDS transpose, contiguous float4 stores
    float* eb = (float*)smem + w * (16 * 68);
    const int rr = lane >> 2, c0 = (lane & 3) * 16;
#pragma unroll
    for (int mf = 0; mf < 8; ++mf) {
#pragma unroll
        for (int n = 0; n < 4; ++n)
#pragma unroll
            for (int j = 0; j < 4; ++j)
                eb[(g * 4 + j) * 68 + n * 16 + l15] = acc[mf][n][j];
        __syncthreads();
        const float* src = &eb[rr * 68 + c0];
        float* dst = C + (size_t)(bm + wm * 128 + mf * 16 + rr) * 32000 + bn + wn * 64 + c0;
        *(float4*)(dst + 0)  = *(const float4*)(src + 0);
        *(float4*)(dst + 4)  = *(const float4*)(src + 4);
        *(float4*)(dst + 8)  = *(const float4*)(src + 8);
        *(float4*)(dst + 12) = *(const float4*)(src + 12);
        __syncthreads();
    }
}

// ---------------- MFMA flash attention ----------------
__global__ __launch_bounds__(256) void fattn_kernel(const bf16* __restrict__ qkv,
                                                    const bf16* __restrict__ vt,
                                                    bf16* __restrict__ o) {
    const int bh = blockIdx.y;
    const int b = bh / HH, h = bh % HH;
    const int q0 = blockIdx.x * 64;
    const int tid = threadIdx.x;
    const int w = tid >> 6, lane = tid & 63;
    const int l15 = lane & 15, g = lane >> 4;

    __shared__ __align__(16) bf16 Ks[64 * 64];
    __shared__ __align__(16) bf16 Vs[64 * 64];
    __shared__ __align__(16) bf16 Ps[4][16 * 64];

    const size_t basebt = (size_t)b * TT;
    const int qw = q0 + w * 16;
    const int qg = qw + l15;

    bf16x8 bq0, bq1;
    {
        const bf16* qp = qkv + (basebt + qw + l15) * 2304 + h * 64 + g * 8;
        bq0 = *(const bf16x8*)(qp);
        bq1 = *(const bf16x8*)(qp + 32);
    }

    float mstate = -1e30f, lstate = 0.f;
    f32x4 oacc[4];
#pragma unroll
    for (int nf = 0; nf < 4; ++nf) oacc[nf] = (f32x4){0.f, 0.f, 0.f, 0.f};

    const int swzA = (l15 & 7) << 4;
    char* const psBase = (char*)&Ps[w][0];

    const int nchunk = blockIdx.x + 1;
    for (int c = 0; c < nchunk; ++c) {
        const int kc = c * 64;
        __syncthreads();
        {
            int r0 = tid >> 3;
            int e0 = (tid & 7) * 8;
#pragma unroll
            for (int i = 0; i < 2; ++i) {
                int r = r0 + 32 * i;
                int swzW = (r & 7) << 4;
                bf16x8 kv = *(const bf16x8*)&qkv[(basebt + kc + r) * 2304 + DD + h * 64 + e0];
                *(bf16x8*)((char*)Ks + r * 128 + ((e0 * 2) ^ swzW)) = kv;
                bf16x8 vv = *(const bf16x8*)&vt[((size_t)bh * 64 + r) * TT + kc + e0];
                *(bf16x8*)((char*)Vs + r * 128 + ((e0 * 2) ^ swzW)) = vv;
            }
        }
        __syncthreads();
        if (kc > qw + 15) continue;

        f32x4 s[4];
        __builtin_amdgcn_s_setprio(1);
#pragma unroll
        for (int mf = 0; mf < 4; ++mf) {
            char* kr = (char*)Ks + (16 * mf + l15) * 128;
            bf16x8 ka0 = *(const bf16x8*)(kr + ((16 * g) ^ swzA));
            bf16x8 ka1 = *(const bf16x8*)(kr + ((64 + 16 * g) ^ swzA));
            f32x4 a = (f32x4){0.f, 0.f, 0.f, 0.f};
            a = __builtin_amdgcn_mfma_f32_16x16x32_bf16(ka0, bq0, a, 0, 0, 0);
            a = __builtin_amdgcn_mfma_f32_16x16x32_bf16(ka1, bq1, a, 0, 0, 0);
            s[mf] = a;
        }
        __builtin_amdgcn_s_setprio(0);
        if (kc + 63 > qw) {
#pragma unroll
            for (int mf = 0; mf < 4; ++mf)
#pragma unroll
                for (int j = 0; j < 4; ++j)
                    if (kc + 16 * mf + 4 * g + j > qg) s[mf][j] = -1e30f;
        }
        float cm = -1e30f;
#pragma unroll
        for (int mf = 0; mf < 4; ++mf)
#pragma unroll
            for (int j = 0; j < 4; ++j) cm = fmaxf(cm, s[mf][j]);
        cm = fmaxf(cm, __shfl_xor(cm, 16));
        cm = fmaxf(cm, __shfl_xor(cm, 32));
        float mnew = fmaxf(mstate, cm);
        float sc = __expf(mstate - mnew);
        mstate = mnew;
        float p[4][4];
        float psum = 0.f;
#pragma unroll
        for (int mf = 0; mf < 4; ++mf)
#pragma unroll
            for (int j = 0; j < 4; ++j) { float pv = __expf(s[mf][j] - mnew); p[mf][j] = pv; psum += pv; }
        psum += __shfl_xor(psum, 16);
        psum += __shfl_xor(psum, 32);
        lstate = lstate * sc + psum;
#pragma unroll
        for (int mf = 0; mf < 4; ++mf) {
            unsigned lo = pack_bf16x2(p[mf][0], p[mf][1]);
            unsigned hi = pack_bf16x2(p[mf][2], p[mf][3]);
            char* dst = psBase + l15 * 128 + ((32 * mf + 8 * g) ^ swzA);
            *(unsigned*)dst = lo;
            *(unsigned*)(dst + 4) = hi;
        }
        float s0 = __shfl(sc, 4 * g + 0), s1 = __shfl(sc, 4 * g + 1);
        float s2 = __shfl(sc, 4 * g + 2), s3 = __shfl(sc, 4 * g + 3);
#pragma unroll
        for (int nf = 0; nf < 4; ++nf) {
            oacc[nf][0] *= s0; oacc[nf][1] *= s1; oacc[nf][2] *= s2; oacc[nf][3] *= s3;
        }
        bf16x8 pa0 = *(const bf16x8*)(psBase + l15 * 128 + ((16 * g) ^ swzA));
        bf16x8 pa1 = *(const bf16x8*)(psBase + l15 * 128 + ((64 + 16 * g) ^ swzA));
        __builtin_amdgcn_s_setprio(1);
#pragma unroll
        for (int nf = 0; nf < 4; ++nf) {
            char* vr = (char*)Vs + (16 * nf + l15) * 128;
            bf16x8 vb0 = *(const bf16x8*)(vr + ((16 * g) ^ swzA));
            bf16x8 vb1 = *(const bf16x8*)(vr + ((64 + 16 * g) ^ swzA));
            oacc[nf] = __builtin_amdgcn_mfma_f32_16x16x32_bf16(pa0, vb0, oacc[nf], 0, 0, 0);
            oacc[nf] = __builtin_amdgcn_mfma_f32_16x16x32_bf16(pa1, vb1, oacc[nf], 0, 0, 0);
        }
        __builtin_amdgcn_s_setprio(0);
    }
    float linv = 1.f / lstate;
    float l0 = __shfl(linv, 4 * g + 0), l1 = __shfl(linv, 4 * g + 1);
    float l2 = __shfl(linv, 4 * g + 2), l3 = __shfl(linv, 4 * g + 3);
    float lj[4] = {l0, l1, l2, l3};
#pragma unroll
    for (int j = 0; j < 4; ++j) {
        bf16* orow = o + (size_t)(basebt + qw + 4 * g + j) * DD + h * 64 + l15;
#pragma unroll
        for (int nf = 0; nf < 4; ++nf)
            orow[16 * nf] = (bf16)(oacc[nf][j] * lj[j]);
    }
}

// ---------------- launcher ----------------
extern "C" void kernel_launch(void* const* d_in, const int* in_sizes, int n_in,
                              void* d_out, int out_size, void* d_ws, size_t ws_size,
                              hipStream_t stream) {
    (void)in_sizes; (void)n_in; (void)out_size; (void)ws_size;
    const int*   idx  = (const int*)d_in[0];
    const float* tok  = (const float*)d_in[1];
    const float* pos  = (const float*)d_in[2];
    const float* Wqkv = (const float*)d_in[3];
    const float* bqkv = (const float*)d_in[4];
    const float* Wo   = (const float*)d_in[5];
    const float* bo   = (const float*)d_in[6];
    const float* ln1g = (const float*)d_in[7];
    const float* ln1b = (const float*)d_in[8];
    const float* ln2g = (const float*)d_in[9];
    const float* ln2b = (const float*)d_in[10];
    const float* W1   = (const float*)d_in[11];
    const float* b1   = (const float*)d_in[12];
    const float* W2   = (const float*)d_in[13];
    const float* b2   = (const float*)d_in[14];
    const float* lnfg = (const float*)d_in[15];
    const float* lnfb = (const float*)d_in[16];
    const float* Wlm  = (const float*)d_in[17];
    float* out = (float*)d_out;

    char* ws = (char*)d_ws;
    float* x     = (float*)(ws);                       // 6,291,456
    bf16*  abuf0 = (bf16*)(ws + 6291456);              // 3,145,728
    bf16*  abuf1 = (bf16*)(ws + 9437184);              // 12,582,912
    bf16*  qkvb  = (bf16*)(ws + 22020096);             // 9,437,184
    bf16*  vtb   = (bf16*)(ws + 31457280);             // 3,145,728
    bf16*  wbuf  = (bf16*)(ws + 34603008);             // 49,152,000

    bf16* wq = wbuf;              // 2304x768
    bf16* wo = wbuf + 1769472;    // 768x768
    bf16* w1 = wbuf + 2359296;    // 3072x768
    bf16* w2 = wbuf + 4718592;    // 768x3072

    embed_kernel<<<NTOK, 256, 0, stream>>>(idx, tok, pos, x);

    for (int l = 0; l < LLAY; ++l) {
        convT4_kernel<<<6912, 256, 0, stream>>>(
            Wqkv + (size_t)l * DD * 3 * DD, Wo + (size_t)l * DD * DD,
            W1 + (size_t)l * DD * DFFN, W2 + (size_t)l * DFFN * DD,
            wq, wo, w1, w2);
        ln_kernel<<<NTOK, 256, 0, stream>>>(x, ln1g + l * DD, ln1b + l * DD, abuf0);
        mgemm<128, 4><<<dim3(3 * DD / 128, NTOK / 128), 256, 0, stream>>>(
            abuf0, wq, bqkv + (size_t)l * 3 * DD, nullptr, qkvb, vtb, NTOK, 3 * DD, DD);
        fattn_kernel<<<dim3(TT / 64, BB * HH), 256, 0, stream>>>(qkvb, vtb, abuf0);
        mgemm<64, 2><<<dim3(DD / 128, NTOK / 64), 256, 0, stream>>>(
            abuf0, wo, bo + (size_t)l * DD, x, x, nullptr, NTOK, DD, DD);
        ln_kernel<<<NTOK, 256, 0, stream>>>(x, ln2g + l * DD, ln2b + l * DD, abuf0);
        mgemm<128, 3><<<dim3(DFFN / 128, NTOK / 128), 256, 0, stream>>>(
            abuf0, w1, b1 + (size_t)l * DFFN, nullptr, abuf1, nullptr, NTOK, DFFN, DD);
        mgemm<64, 2><<<dim3(DD / 128, NTOK / 64), 256, 0, stream>>>(
            abuf1, w2, b2 + (size_t)l * DD, x, x, nullptr, NTOK, DD, DFFN);
    }
    ln_kernel<<<NTOK, 256, 0, stream>>>(x, lnfg, lnfb, abuf0);
    convT_kernel<<<dim3(32000 / 32, DD / 32), 256, 0, stream>>>(Wlm, wbuf, DD, 32000);
    lmgemm<<<dim3(NTOK / 256, 32000 / 256), 512, 0, stream>>>(abuf0, wbuf, out);
}

// Round 9
// 1005.212 us; speedup vs baseline: 7.3220x; 1.0029x over previous
//
#include <hip/hip_runtime.h>
#include <math.h>

#define TT   1024
#define DD   768
#define HH   12
#define LLAY 6
#define DFFN 3072
#define BB   2
#define NTOK (BB*TT)   // 2048

typedef __bf16 bf16;
typedef __attribute__((ext_vector_type(8))) __bf16 bf16x8;
typedef __attribute__((ext_vector_type(4))) __bf16 bf16x4;
typedef __attribute__((ext_vector_type(4))) float f32x4;

__device__ inline unsigned pack_bf16x2(float a, float b) {
    union { bf16 h[2]; unsigned u; } un;
    un.h[0] = (bf16)a; un.h[1] = (bf16)b;
    return un.u;
}

// async global->LDS, 16B per lane; LDS dest is wave-uniform base (+lane*16 by HW)
__device__ inline void gload16(const bf16* g, bf16* l) {
    __builtin_amdgcn_global_load_lds((const void*)g, (void*)l, 16, 0, 0);
}

template<int N> __device__ inline void waitcnt_vm() {
    if constexpr (N == 0) asm volatile("s_waitcnt vmcnt(0)" ::: "memory");
    else if constexpr (N == 3) asm volatile("s_waitcnt vmcnt(3)" ::: "memory");
    else if constexpr (N == 4) asm volatile("s_waitcnt vmcnt(4)" ::: "memory");
    else if constexpr (N == 8) asm volatile("s_waitcnt vmcnt(8)" ::: "memory");
}

// ---------------- embedding ----------------
__global__ __launch_bounds__(256) void embed_kernel(const int* __restrict__ idx,
                                                    const float* __restrict__ tok,
                                                    const float* __restrict__ pos,
                                                    float* __restrict__ x) {
    int bt = blockIdx.x;
    int t  = bt % TT;
    int id = idx[bt];
    const float* te = tok + (size_t)id * DD;
    const float* pe = pos + (size_t)t * DD;
    float* xr = x + (size_t)bt * DD;
    for (int d = threadIdx.x; d < DD; d += 256) xr[d] = te[d] + pe[d];
}

// ---------------- layernorm: wave-per-row, f32 in -> bf16 out ----------------
__global__ __launch_bounds__(256) void ln_kernel(const float* __restrict__ in,
                                                 const float* __restrict__ g,
                                                 const float* __restrict__ b,
                                                 bf16* __restrict__ out) {
    const int wid = threadIdx.x >> 6, lane = threadIdx.x & 63;
    const int row = blockIdx.x * 4 + wid;
    const float* xr = in + (size_t)row * DD;
    float4 v[3];
    float s = 0.f, s2 = 0.f;
#pragma unroll
    for (int j = 0; j < 3; ++j) {
        v[j] = *(const float4*)&xr[lane * 4 + 256 * j];
        s  += v[j].x + v[j].y + v[j].z + v[j].w;
        s2 += v[j].x * v[j].x + v[j].y * v[j].y + v[j].z * v[j].z + v[j].w * v[j].w;
    }
    for (int off = 32; off; off >>= 1) { s += __shfl_down(s, off); s2 += __shfl_down(s2, off); }
    s = __shfl(s, 0); s2 = __shfl(s2, 0);
    const float mu = s / (float)DD;
    const float rs = rsqrtf(s2 / (float)DD - mu * mu + 1e-5f);
    bf16* orow = out + (size_t)row * DD;
#pragma unroll
    for (int j = 0; j < 3; ++j) {
        float4 gg = *(const float4*)&g[lane * 4 + 256 * j];
        float4 bb = *(const float4*)&b[lane * 4 + 256 * j];
        bf16x4 o;
        o[0] = (bf16)((v[j].x - mu) * rs * gg.x + bb.x);
        o[1] = (bf16)((v[j].y - mu) * rs * gg.y + bb.y);
        o[2] = (bf16)((v[j].z - mu) * rs * gg.z + bb.z);
        o[3] = (bf16)((v[j].w - mu) * rs * gg.w + bb.w);
        *(bf16x4*)&orow[lane * 4 + 256 * j] = o;
    }
}

// ---------------- 32x32 transpose+convert tile helper ----------------
__device__ inline void convT_tile(const float* __restrict__ in, bf16* __restrict__ out,
                                  int K, int N, int k0, int n0) {
    __shared__ float tile[32][33];
    int tn = threadIdx.x & 31, tk = threadIdx.x >> 5;   // tk 0..7
#pragma unroll
    for (int i = 0; i < 4; ++i)
        tile[tk + i * 8][tn] = in[(size_t)(k0 + tk + i * 8) * N + n0 + tn];
    __syncthreads();
#pragma unroll
    for (int i = 0; i < 4; ++i)
        out[(size_t)(n0 + tk + i * 8) * K + k0 + tn] = (bf16)tile[tn][tk + i * 8];
}

// single-weight version (LM head)
__global__ __launch_bounds__(256) void convT_kernel(const float* __restrict__ in,
                                                    bf16* __restrict__ out,
                                                    int K, int N) {
    convT_tile(in, out, K, N, blockIdx.y * 32, blockIdx.x * 32);
}

// one layer's 4 weights in one launch
__global__ __launch_bounds__(256) void convT4_kernel(const float* __restrict__ w0,
                                                     const float* __restrict__ w1,
                                                     const float* __restrict__ w2,
                                                     const float* __restrict__ w3,
                                                     bf16* __restrict__ o0,
                                                     bf16* __restrict__ o1,
                                                     bf16* __restrict__ o2,
                                                     bf16* __restrict__ o3) {
    int bid = blockIdx.x;
    const float* in; bf16* out; int K, N, t;
    if (bid < 1728)      { in = w0; out = o0; K = 768;  N = 2304; t = bid; }          // Wqkv 24x72
    else if (bid < 2304) { in = w1; out = o1; K = 768;  N = 768;  t = bid - 1728; }   // Wo   24x24
    else if (bid < 4608) { in = w2; out = o2; K = 768;  N = 3072; t = bid - 2304; }   // W1   24x96
    else                 { in = w3; out = o3; K = 3072; N = 768;  t = bid - 4608; }   // W2   96x24
    int nt = N / 32;
    convT_tile(in, out, K, N, (t / nt) * 32, (t % nt) * 32);
}

// ---------------- bf16 MFMA GEMM (layer GEMMs): 3-deep counted-vmcnt ----------
// EPI: 1 +bias bf16; 2 +bias+res f32; 3 +bias GELU bf16; 4 qkv special
template<int BM, int EPI>
__global__ __launch_bounds__(256) void mgemm(const bf16* __restrict__ A,
                                             const bf16* __restrict__ Bt,
                                             const float* __restrict__ bias,
                                             const float* __restrict__ res,
                                             void* __restrict__ Cout,
                                             bf16* __restrict__ vtout,
                                             int M, int N, int K) {
    constexpr int MF = BM / 32;
    constexpr int NF = 4;
    constexpr int AIT = BM / 64;
    constexpr int STG = AIT + 2;          // gloads per wave per stage
    constexpr int ASZ = BM * 32;          // elements
    constexpr int BUFE = ASZ + 128 * 32;  // elements per phase buffer
    __shared__ __align__(16) bf16 smem[3 * BUFE];
    int bm = blockIdx.y * BM;
    int bn = blockIdx.x * 128;
    int tid = threadIdx.x;
    int lane = tid & 63;
    int w = tid >> 6;
    int wr = w >> 1, wc = w & 1;
    int l15 = lane & 15, g = lane >> 4;

    f32x4 acc[MF][NF];
#pragma unroll
    for (int m = 0; m < MF; ++m)
#pragma unroll
        for (int n = 0; n < NF; ++n) acc[m][n] = (f32x4){0.f, 0.f, 0.f, 0.f};

    int r = lane >> 2;
    int koff = ((lane & 3) ^ ((r >> 1) & 3)) * 8;     // pre-swizzled global source
    const bf16* Ab = A + (size_t)(bm + w * 16 + r) * K + koff;
    const bf16* Bb = Bt + (size_t)(bn + w * 16 + r) * K + koff;

    auto stage = [&](int p, int k0) {
        bf16* base = smem + p * BUFE;
        bf16* Asb = base + w * 16 * 32;
        bf16* Bsb = base + ASZ + w * 16 * 32;
#pragma unroll
        for (int it = 0; it < AIT; ++it)
            gload16(Ab + (size_t)(it * 64) * K + k0, Asb + it * 64 * 32);
#pragma unroll
        for (int it = 0; it < 2; ++it)
            gload16(Bb + (size_t)(it * 64) * K + k0, Bsb + it * 64 * 32);
    };

    stage(0, 0);
    stage(1, 32);
    waitcnt_vm<STG>();        // buf0 landed (stage1 still in flight)
    __builtin_amdgcn_s_barrier();
    int cur = 0;

    for (int k0 = 0; k0 < K; k0 += 32) {
        const bf16* Ac = smem + cur * BUFE;
        const bf16* Bc = Ac + ASZ;
        bf16x8 af[MF], bfv[NF];
#pragma unroll
        for (int m = 0; m < MF; ++m) {
            int row = wr * (BM / 2) + m * 16 + l15;
            int gs = g ^ ((row >> 1) & 3);            // read-side swizzle
            af[m] = *(const bf16x8*)&Ac[row * 32 + gs * 8];
        }
#pragma unroll
        for (int n = 0; n < NF; ++n) {
            int row = wc * 64 + n * 16 + l15;
            int gs = g ^ ((row >> 1) & 3);
            bfv[n] = *(const bf16x8*)&Bc[row * 32 + gs * 8];
        }
        bool st = (k0 + 64 < K);
        if (st) {
            int nxt = cur + 2; if (nxt >= 3) nxt -= 3;
            stage(nxt, k0 + 64);                      // lands ~2 K-steps later
        }
#pragma unroll
        for (int m = 0; m < MF; ++m)
#pragma unroll
            for (int n = 0; n < NF; ++n)
                acc[m][n] = __builtin_amdgcn_mfma_f32_16x16x32_bf16(af[m], bfv[n], acc[m][n], 0, 0, 0);
        if (st) waitcnt_vm<STG>();    // prev stage landed; this one stays in flight
        else    waitcnt_vm<0>();
        __builtin_amdgcn_s_barrier();
        cur = (cur == 2) ? 0 : cur + 1;
    }

    int lq = g * 4;
#pragma unroll
    for (int m = 0; m < MF; ++m) {
#pragma unroll
        for (int n = 0; n < NF; ++n) {
            int col = bn + wc * 64 + n * 16 + l15;
            float bv = bias[col];
            if (EPI == 4 && col >= 2 * DD) {
                int row0 = bm + wr * (BM / 2) + m * 16 + lq;
                int b = row0 >> 10, t0 = row0 & 1023;
                int hd = col - 2 * DD;
                union { bf16 h[4]; unsigned long long u; } pk;
#pragma unroll
                for (int j = 0; j < 4; ++j) pk.h[j] = (bf16)(acc[m][n][j] + bv);
                *(unsigned long long*)&vtout[((size_t)(b * DD + hd)) * TT + t0] = pk.u;
            } else {
#pragma unroll
                for (int j = 0; j < 4; ++j) {
                    int row = bm + wr * (BM / 2) + m * 16 + lq + j;
                    float v = acc[m][n][j] + bv;
                    if (EPI == 2) {
                        ((float*)Cout)[(size_t)row * N + col] = v + res[(size_t)row * N + col];
                    } else if (EPI == 3) {
                        v = 0.5f * v * (1.f + erff(v * 0.70710678118654752f));
                        ((bf16*)Cout)[(size_t)row * N + col] = (bf16)v;
                    } else if (EPI == 1) {
                        ((bf16*)Cout)[(size_t)row * N + col] = (bf16)v;
                    } else { // EPI == 4 Q/K columns
                        if (col < DD) v *= 0.125f;
                        ((bf16*)Cout)[(size_t)row * N + col] = (bf16)v;
                    }
                }
            }
        }
    }
}

// ---------------- LM head GEMM: 256x256 tile, BK=32, 4-buffer counted vmcnt ----
// C[2048][32000] f32 = A[2048][768] @ Bt[32000][768]^T. 512 thr / 8 waves (2Mx4N).
// Per step t: ds_read buf[t&3] -> stage buf[(t+3)&3] (4 gloads) -> 32 MFMA ->
// vmcnt(8) [stage t+1 landed, 8 loads stay in flight] -> s_barrier. Main loop
// never drains; tail (last 3 steps) after one vmcnt(0)+barrier, barrier-free.
// Swizzle: 16B chunk c of row r stored at c ^ ((r>>1)&3); global source
// pre-swizzled, read side applies same XOR (both-sides, rule #21).
__global__ __launch_bounds__(512, 2) void lmgemm(const bf16* __restrict__ A,
                                                 const bf16* __restrict__ Bt,
                                                 float* __restrict__ C) {
    constexpr int ABUF = 256 * 32;           // A elements per buffer (16KB)
    constexpr int BUFE = 2 * ABUF;           // A+B per buffer (32KB)
    __shared__ __align__(16) bf16 smem[4 * BUFE];   // 128 KiB
    const int tid = threadIdx.x;
    const int w = tid >> 6, lane = tid & 63;
    const int wm = w >> 2, wn = w & 3;
    const int l15 = lane & 15, g = lane >> 4;
    const int bm = blockIdx.x * 256;
    const int bn = blockIdx.y * 256;

    // read-side swizzle: chunk (g ^ (l15>>1)&3), wave/frag offsets divide out
    const int fcol = ((g ^ ((l15 >> 1) & 3))) * 8;

    // staging: thread covers row rA=lane>>2 (+128 on 2nd gload), physical chunk lane&3
    const int rA = lane >> 2;
    const int csw = ((lane & 3) ^ ((lane >> 3) & 3)) * 8;   // inverse-swizzled source col
    const bf16* a0 = A  + (size_t)(bm + w * 16 + rA) * DD + csw;
    const bf16* b0 = Bt + (size_t)(bn + w * 16 + rA) * DD + csw;
    const int ld0 = (w * 16) * 32;           // wave-uniform LDS elem offsets
    const int ld1 = (w * 16 + 128) * 32;

    f32x4 acc[8][4];
#pragma unroll
    for (int m = 0; m < 8; ++m)
#pragma unroll
        for (int n = 0; n < 4; ++n) acc[m][n] = (f32x4){0.f, 0.f, 0.f, 0.f};

    auto stagef = [&](int p, int kelem) {
        bf16* base = smem + p * BUFE;
        gload16(a0 + kelem, base + ld0);
        gload16(a0 + (size_t)128 * DD + kelem, base + ld1);
        gload16(b0 + kelem, base + ABUF + ld0);
        gload16(b0 + (size_t)128 * DD + kelem, base + ABUF + ld1);
    };

    stagef(0, 0);
    stagef(1, 32);
    stagef(2, 64);
    waitcnt_vm<8>();                 // buf0 landed (8 loads still in flight)
    __builtin_amdgcn_s_barrier();

    for (int t = 0; t < 21; ++t) {
        const bf16* Ar = smem + (t & 3) * BUFE;
        const bf16* Br = Ar + ABUF;
        bf16x8 af[8], bfv[4];
#pragma unroll
        for (int m = 0; m < 8; ++m)
            af[m] = *(const bf16x8*)&Ar[(wm * 128 + m * 16 + l15) * 32 + fcol];
#pragma unroll
        for (int n = 0; n < 4; ++n)
            bfv[n] = *(const bf16x8*)&Br[(wn * 64 + n * 16 + l15) * 32 + fcol];
        stagef((t + 3) & 3, (t + 3) * 32);
        __builtin_amdgcn_s_setprio(1);
#pragma unroll
        for (int m = 0; m < 8; ++m)
#pragma unroll
            for (int n = 0; n < 4; ++n)
                acc[m][n] = __builtin_amdgcn_mfma_f32_16x16x32_bf16(af[m], bfv[n], acc[m][n], 0, 0, 0);
        __builtin_amdgcn_s_setprio(0);
        waitcnt_vm<8>();             // stage t+1 landed; t+2,t+3 stay in flight
        __builtin_amdgcn_s_barrier();
    }
    waitcnt_vm<0>();                 // all remaining stages landed
    __builtin_amdgcn_s_barrier();
#pragma unroll
    for (int t = 21; t < 24; ++t) {  // tail: all data resident, no barriers
        const bf16* Ar = smem + (t & 3) * BUFE;
        const bf16* Br = Ar + ABUF;
        bf16x8 af[8], bfv[4];
#pragma unroll
        for (int m = 0; m < 8; ++m)
            af[m] = *(const bf16x8*)&Ar[(wm * 128 + m * 16 + l15) * 32 + fcol];
#pragma unroll
        for (int n = 0; n < 4; ++n)
            bfv[n] = *(const bf16x8*)&Br[(wn * 64 + n * 16 + l15) * 32 + fcol];
#pragma unroll
        for (int m = 0; m < 8; ++m)
#pragma unroll
            for (int n = 0; n < 4; ++n)
                acc[m][n] = __builtin_amdgcn_mfma_f32_16x16x32_bf16(af[m], bfv[n], acc[m][n], 0, 0, 0);
    }

    __syncthreads();                 // staging region now safe to reuse
    // epilogue: per-wave LDS transpose, contiguous float4 stores
    float* eb = (float*)smem + w * (16 * 68);
    const int rr = lane >> 2, c0 = (lane & 3) * 16;
#pragma unroll
    for (int mf = 0; mf < 8; ++mf) {
#pragma unroll
        for (int n = 0; n < 4; ++n)
#pragma unroll
            for (int j = 0; j < 4; ++j)
                eb[(g * 4 + j) * 68 + n * 16 + l15] = acc[mf][n][j];
        __syncthreads();
        const float* src = &eb[rr * 68 + c0];
        float* dst = C + (size_t)(bm + wm * 128 + mf * 16 + rr) * 32000 + bn + wn * 64 + c0;
        *(float4*)(dst + 0)  = *(const float4*)(src + 0);
        *(float4*)(dst + 4)  = *(const float4*)(src + 4);
        *(float4*)(dst + 8)  = *(const float4*)(src + 8);
        *(float4*)(dst + 12) = *(const float4*)(src + 12);
        __syncthreads();
    }
}

// ---------------- MFMA flash attention ----------------
__global__ __launch_bounds__(256) void fattn_kernel(const bf16* __restrict__ qkv,
                                                    const bf16* __restrict__ vt,
                                                    bf16* __restrict__ o) {
    const int bh = blockIdx.y;
    const int b = bh / HH, h = bh % HH;
    const int qc = gridDim.x - 1 - blockIdx.x;   // longest blocks dispatch first
    const int q0 = qc * 64;
    const int tid = threadIdx.x;
    const int w = tid >> 6, lane = tid & 63;
    const int l15 = lane & 15, g = lane >> 4;

    __shared__ __align__(16) bf16 Ks[64 * 64];
    __shared__ __align__(16) bf16 Vs[64 * 64];
    __shared__ __align__(16) bf16 Ps[4][16 * 64];

    const size_t basebt = (size_t)b * TT;
    const int qw = q0 + w * 16;
    const int qg = qw + l15;

    bf16x8 bq0, bq1;
    {
        const bf16* qp = qkv + (basebt + qw + l15) * 2304 + h * 64 + g * 8;
        bq0 = *(const bf16x8*)(qp);
        bq1 = *(const bf16x8*)(qp + 32);
    }

    float mstate = -1e30f, lstate = 0.f;
    f32x4 oacc[4];
#pragma unroll
    for (int nf = 0; nf < 4; ++nf) oacc[nf] = (f32x4){0.f, 0.f, 0.f, 0.f};

    const int swzA = (l15 & 7) << 4;
    char* const psBase = (char*)&Ps[w][0];

    const int nchunk = qc + 1;
    for (int c = 0; c < nchunk; ++c) {
        const int kc = c * 64;
        __syncthreads();
        {
            int r0 = tid >> 3;
            int e0 = (tid & 7) * 8;
#pragma unroll
            for (int i = 0; i < 2; ++i) {
                int r = r0 + 32 * i;
                int swzW = (r & 7) << 4;
                bf16x8 kv = *(const bf16x8*)&qkv[(basebt + kc + r) * 2304 + DD + h * 64 + e0];
                *(bf16x8*)((char*)Ks + r * 128 + ((e0 * 2) ^ swzW)) = kv;
                bf16x8 vv = *(const bf16x8*)&vt[((size_t)bh * 64 + r) * TT + kc + e0];
                *(bf16x8*)((char*)Vs + r * 128 + ((e0 * 2) ^ swzW)) = vv;
            }
        }
        __syncthreads();
        if (kc > qw + 15) continue;

        f32x4 s[4];
        __builtin_amdgcn_s_setprio(1);
#pragma unroll
        for (int mf = 0; mf < 4; ++mf) {
            char* kr = (char*)Ks + (16 * mf + l15) * 128;
            bf16x8 ka0 = *(const bf16x8*)(kr + ((16 * g) ^ swzA));
            bf16x8 ka1 = *(const bf16x8*)(kr + ((64 + 16 * g) ^ swzA));
            f32x4 a = (f32x4){0.f, 0.f, 0.f, 0.f};
            a = __builtin_amdgcn_mfma_f32_16x16x32_bf16(ka0, bq0, a, 0, 0, 0);
            a = __builtin_amdgcn_mfma_f32_16x16x32_bf16(ka1, bq1, a, 0, 0, 0);
            s[mf] = a;
        }
        __builtin_amdgcn_s_setprio(0);
        if (kc + 63 > qw) {
#pragma unroll
            for (int mf = 0; mf < 4; ++mf)
#pragma unroll
                for (int j = 0; j < 4; ++j)
                    if (kc + 16 * mf + 4 * g + j > qg) s[mf][j] = -1e30f;
        }
        float cm = -1e30f;
#pragma unroll
        for (int mf = 0; mf < 4; ++mf)
#pragma unroll
            for (int j = 0; j < 4; ++j) cm = fmaxf(cm, s[mf][j]);
        cm = fmaxf(cm, __shfl_xor(cm, 16));
        cm = fmaxf(cm, __shfl_xor(cm, 32));
        float mnew = fmaxf(mstate, cm);
        float sc = __expf(mstate - mnew);
        mstate = mnew;
        float p[4][4];
        float psum = 0.f;
#pragma unroll
        for (int mf = 0; mf < 4; ++mf)
#pragma unroll
            for (int j = 0; j < 4; ++j) { float pv = __expf(s[mf][j] - mnew); p[mf][j] = pv; psum += pv; }
        psum += __shfl_xor(psum, 16);
        psum += __shfl_xor(psum, 32);
        lstate = lstate * sc + psum;
#pragma unroll
        for (int mf = 0; mf < 4; ++mf) {
            unsigned lo = pack_bf16x2(p[mf][0], p[mf][1]);
            unsigned hi = pack_bf16x2(p[mf][2], p[mf][3]);
            char* dst = psBase + l15 * 128 + ((32 * mf + 8 * g) ^ swzA);
            *(unsigned*)dst = lo;
            *(unsigned*)(dst + 4) = hi;
        }
        float s0 = __shfl(sc, 4 * g + 0), s1 = __shfl(sc, 4 * g + 1);
        float s2 = __shfl(sc, 4 * g + 2), s3 = __shfl(sc, 4 * g + 3);
#pragma unroll
        for (int nf = 0; nf < 4; ++nf) {
            oacc[nf][0] *= s0; oacc[nf][1] *= s1; oacc[nf][2] *= s2; oacc[nf][3] *= s3;
        }
        bf16x8 pa0 = *(const bf16x8*)(psBase + l15 * 128 + ((16 * g) ^ swzA));
        bf16x8 pa1 = *(const bf16x8*)(psBase + l15 * 128 + ((64 + 16 * g) ^ swzA));
        __builtin_amdgcn_s_setprio(1);
#pragma unroll
        for (int nf = 0; nf < 4; ++nf) {
            char* vr = (char*)Vs + (16 * nf + l15) * 128;
            bf16x8 vb0 = *(const bf16x8*)(vr + ((16 * g) ^ swzA));
            bf16x8 vb1 = *(const bf16x8*)(vr + ((64 + 16 * g) ^ swzA));
            oacc[nf] = __builtin_amdgcn_mfma_f32_16x16x32_bf16(pa0, vb0, oacc[nf], 0, 0, 0);
            oacc[nf] = __builtin_amdgcn_mfma_f32_16x16x32_bf16(pa1, vb1, oacc[nf], 0, 0, 0);
        }
        __builtin_amdgcn_s_setprio(0);
    }
    float linv = 1.f / lstate;
    float l0 = __shfl(linv, 4 * g + 0), l1 = __shfl(linv, 4 * g + 1);
    float l2 = __shfl(linv, 4 * g + 2), l3 = __shfl(linv, 4 * g + 3);
    float lj[4] = {l0, l1, l2, l3};
#pragma unroll
    for (int j = 0; j < 4; ++j) {
        bf16* orow = o + (size_t)(basebt + qw + 4 * g + j) * DD + h * 64 + l15;
#pragma unroll
        for (int nf = 0; nf < 4; ++nf)
            orow[16 * nf] = (bf16)(oacc[nf][j] * lj[j]);
    }
}

// ---------------- launcher ----------------
extern "C" void kernel_launch(void* const* d_in, const int* in_sizes, int n_in,
                              void* d_out, int out_size, void* d_ws, size_t ws_size,
                              hipStream_t stream) {
    (void)in_sizes; (void)n_in; (void)out_size; (void)ws_size;
    const int*   idx  = (const int*)d_in[0];
    const float* tok  = (const float*)d_in[1];
    const float* pos  = (const float*)d_in[2];
    const float* Wqkv = (const float*)d_in[3];
    const float* bqkv = (const float*)d_in[4];
    const float* Wo   = (const float*)d_in[5];
    const float* bo   = (const float*)d_in[6];
    const float* ln1g = (const float*)d_in[7];
    const float* ln1b = (const float*)d_in[8];
    const float* ln2g = (const float*)d_in[9];
    const float* ln2b = (const float*)d_in[10];
    const float* W1   = (const float*)d_in[11];
    const float* b1   = (const float*)d_in[12];
    const float* W2   = (const float*)d_in[13];
    const float* b2   = (const float*)d_in[14];
    const float* lnfg = (const float*)d_in[15];
    const float* lnfb = (const float*)d_in[16];
    const float* Wlm  = (const float*)d_in[17];
    float* out = (float*)d_out;

    char* ws = (char*)d_ws;
    float* x     = (float*)(ws);                       // 6,291,456
    bf16*  abuf0 = (bf16*)(ws + 6291456);              // 3,145,728
    bf16*  abuf1 = (bf16*)(ws + 9437184);              // 12,582,912
    bf16*  qkvb  = (bf16*)(ws + 22020096);             // 9,437,184
    bf16*  vtb   = (bf16*)(ws + 31457280);             // 3,145,728
    bf16*  wbuf  = (bf16*)(ws + 34603008);             // 49,152,000

    bf16* wq = wbuf;              // 2304x768
    bf16* wo = wbuf + 1769472;    // 768x768
    bf16* w1 = wbuf + 2359296;    // 3072x768
    bf16* w2 = wbuf + 4718592;    // 768x3072

    embed_kernel<<<NTOK, 256, 0, stream>>>(idx, tok, pos, x);

    for (int l = 0; l < LLAY; ++l) {
        convT4_kernel<<<6912, 256, 0, stream>>>(
            Wqkv + (size_t)l * DD * 3 * DD, Wo + (size_t)l * DD * DD,
            W1 + (size_t)l * DD * DFFN, W2 + (size_t)l * DFFN * DD,
            wq, wo, w1, w2);
        ln_kernel<<<NTOK / 4, 256, 0, stream>>>(x, ln1g + l * DD, ln1b + l * DD, abuf0);
        mgemm<128, 4><<<dim3(3 * DD / 128, NTOK / 128), 256, 0, stream>>>(
            abuf0, wq, bqkv + (size_t)l * 3 * DD, nullptr, qkvb, vtb, NTOK, 3 * DD, DD);
        fattn_kernel<<<dim3(TT / 64, BB * HH), 256, 0, stream>>>(qkvb, vtb, abuf0);
        mgemm<64, 2><<<dim3(DD / 128, NTOK / 64), 256, 0, stream>>>(
            abuf0, wo, bo + (size_t)l * DD, x, x, nullptr, NTOK, DD, DD);
        ln_kernel<<<NTOK / 4, 256, 0, stream>>>(x, ln2g + l * DD, ln2b + l * DD, abuf0);
        mgemm<128, 3><<<dim3(DFFN / 128, NTOK / 128), 256, 0, stream>>>(
            abuf0, w1, b1 + (size_t)l * DFFN, nullptr, abuf1, nullptr, NTOK, DFFN, DD);
        mgemm<64, 2><<<dim3(DD / 128, NTOK / 64), 256, 0, stream>>>(
            abuf1, w2, b2 + (size_t)l * DD, x, x, nullptr, NTOK, DD, DFFN);
    }
    ln_kernel<<<NTOK / 4, 256, 0, stream>>>(x, lnfg, lnfb, abuf0);
    convT_kernel<<<dim3(32000 / 32, DD / 32), 256, 0, stream>>>(Wlm, wbuf, DD, 32000);
    lmgemm<<<dim3(NTOK / 256, 32000 / 256), 512, 0, stream>>>(abuf0, wbuf, out);
}

// Round 10
// 992.827 us; speedup vs baseline: 7.4133x; 1.0125x over previous
//
#include <hip/hip_runtime.h>
#include <math.h>

#define TT   1024
#define DD   768
#define HH   12
#define LLAY 6
#define DFFN 3072
#define BB   2
#define NTOK (BB*TT)   // 2048

typedef __bf16 bf16;
typedef __attribute__((ext_vector_type(8))) __bf16 bf16x8;
typedef __attribute__((ext_vector_type(4))) __bf16 bf16x4;
typedef __attribute__((ext_vector_type(4))) float f32x4;

__device__ inline unsigned pack_bf16x2(float a, float b) {
    union { bf16 h[2]; unsigned u; } un;
    un.h[0] = (bf16)a; un.h[1] = (bf16)b;
    return un.u;
}

// async global->LDS, 16B per lane; LDS dest is wave-uniform base (+lane*16 by HW)
__device__ inline void gload16(const bf16* g, bf16* l) {
    __builtin_amdgcn_global_load_lds((const void*)g, (void*)l, 16, 0, 0);
}

template<int N> __device__ inline void waitcnt_vm() {
    if constexpr (N == 0) asm volatile("s_waitcnt vmcnt(0)" ::: "memory");
    else if constexpr (N == 3) asm volatile("s_waitcnt vmcnt(3)" ::: "memory");
    else if constexpr (N == 4) asm volatile("s_waitcnt vmcnt(4)" ::: "memory");
    else if constexpr (N == 8) asm volatile("s_waitcnt vmcnt(8)" ::: "memory");
}

// ---------------- embedding ----------------
__global__ __launch_bounds__(256) void embed_kernel(const int* __restrict__ idx,
                                                    const float* __restrict__ tok,
                                                    const float* __restrict__ pos,
                                                    float* __restrict__ x) {
    int bt = blockIdx.x;
    int t  = bt % TT;
    int id = idx[bt];
    const float* te = tok + (size_t)id * DD;
    const float* pe = pos + (size_t)t * DD;
    float* xr = x + (size_t)bt * DD;
    for (int d = threadIdx.x; d < DD; d += 256) xr[d] = te[d] + pe[d];
}

// ---------------- layernorm: wave-per-row, f32 in -> bf16 out ----------------
__global__ __launch_bounds__(256) void ln_kernel(const float* __restrict__ in,
                                                 const float* __restrict__ g,
                                                 const float* __restrict__ b,
                                                 bf16* __restrict__ out) {
    const int wid = threadIdx.x >> 6, lane = threadIdx.x & 63;
    const int row = blockIdx.x * 4 + wid;
    const float* xr = in + (size_t)row * DD;
    float4 v[3];
    float s = 0.f, s2 = 0.f;
#pragma unroll
    for (int j = 0; j < 3; ++j) {
        v[j] = *(const float4*)&xr[lane * 4 + 256 * j];
        s  += v[j].x + v[j].y + v[j].z + v[j].w;
        s2 += v[j].x * v[j].x + v[j].y * v[j].y + v[j].z * v[j].z + v[j].w * v[j].w;
    }
    for (int off = 32; off; off >>= 1) { s += __shfl_down(s, off); s2 += __shfl_down(s2, off); }
    s = __shfl(s, 0); s2 = __shfl(s2, 0);
    const float mu = s / (float)DD;
    const float rs = rsqrtf(s2 / (float)DD - mu * mu + 1e-5f);
    bf16* orow = out + (size_t)row * DD;
#pragma unroll
    for (int j = 0; j < 3; ++j) {
        float4 gg = *(const float4*)&g[lane * 4 + 256 * j];
        float4 bb = *(const float4*)&b[lane * 4 + 256 * j];
        bf16x4 o;
        o[0] = (bf16)((v[j].x - mu) * rs * gg.x + bb.x);
        o[1] = (bf16)((v[j].y - mu) * rs * gg.y + bb.y);
        o[2] = (bf16)((v[j].z - mu) * rs * gg.z + bb.z);
        o[3] = (bf16)((v[j].w - mu) * rs * gg.w + bb.w);
        *(bf16x4*)&orow[lane * 4 + 256 * j] = o;
    }
}

// ---------------- 32x32 transpose+convert tile helper ----------------
__device__ inline void convT_tile(const float* __restrict__ in, bf16* __restrict__ out,
                                  int K, int N, int k0, int n0) {
    __shared__ float tile[32][33];
    int tn = threadIdx.x & 31, tk = threadIdx.x >> 5;   // tk 0..7
#pragma unroll
    for (int i = 0; i < 4; ++i)
        tile[tk + i * 8][tn] = in[(size_t)(k0 + tk + i * 8) * N + n0 + tn];
    __syncthreads();
#pragma unroll
    for (int i = 0; i < 4; ++i)
        out[(size_t)(n0 + tk + i * 8) * K + k0 + tn] = (bf16)tile[tn][tk + i * 8];
}

// single-weight version (LM head)
__global__ __launch_bounds__(256) void convT_kernel(const float* __restrict__ in,
                                                    bf16* __restrict__ out,
                                                    int K, int N) {
    convT_tile(in, out, K, N, blockIdx.y * 32, blockIdx.x * 32);
}

// one layer's 4 weights in one launch
__global__ __launch_bounds__(256) void convT4_kernel(const float* __restrict__ w0,
                                                     const float* __restrict__ w1,
                                                     const float* __restrict__ w2,
                                                     const float* __restrict__ w3,
                                                     bf16* __restrict__ o0,
                                                     bf16* __restrict__ o1,
                                                     bf16* __restrict__ o2,
                                                     bf16* __restrict__ o3) {
    int bid = blockIdx.x;
    const float* in; bf16* out; int K, N, t;
    if (bid < 1728)      { in = w0; out = o0; K = 768;  N = 2304; t = bid; }          // Wqkv 24x72
    else if (bid < 2304) { in = w1; out = o1; K = 768;  N = 768;  t = bid - 1728; }   // Wo   24x24
    else if (bid < 4608) { in = w2; out = o2; K = 768;  N = 3072; t = bid - 2304; }   // W1   24x96
    else                 { in = w3; out = o3; K = 3072; N = 768;  t = bid - 4608; }   // W2   96x24
    int nt = N / 32;
    convT_tile(in, out, K, N, (t / nt) * 32, (t % nt) * 32);
}

// ---------------- bf16 MFMA GEMM (layer GEMMs): 3-deep counted-vmcnt ----------
// EPI: 1 +bias bf16; 2 +bias+res f32; 3 +bias GELU bf16; 4 qkv special
template<int BM, int EPI>
__global__ __launch_bounds__(256) void mgemm(const bf16* __restrict__ A,
                                             const bf16* __restrict__ Bt,
                                             const float* __restrict__ bias,
                                             const float* __restrict__ res,
                                             void* __restrict__ Cout,
                                             bf16* __restrict__ vtout,
                                             int M, int N, int K) {
    constexpr int MF = BM / 32;
    constexpr int NF = 4;
    constexpr int AIT = BM / 64;
    constexpr int STG = AIT + 2;          // gloads per wave per stage
    constexpr int ASZ = BM * 32;          // elements
    constexpr int BUFE = ASZ + 128 * 32;  // elements per phase buffer
    __shared__ __align__(16) bf16 smem[3 * BUFE];
    int bm = blockIdx.y * BM;
    int bn = blockIdx.x * 128;
    int tid = threadIdx.x;
    int lane = tid & 63;
    int w = tid >> 6;
    int wr = w >> 1, wc = w & 1;
    int l15 = lane & 15, g = lane >> 4;

    f32x4 acc[MF][NF];
#pragma unroll
    for (int m = 0; m < MF; ++m)
#pragma unroll
        for (int n = 0; n < NF; ++n) acc[m][n] = (f32x4){0.f, 0.f, 0.f, 0.f};

    int r = lane >> 2;
    int koff = ((lane & 3) ^ ((r >> 1) & 3)) * 8;     // pre-swizzled global source
    const bf16* Ab = A + (size_t)(bm + w * 16 + r) * K + koff;
    const bf16* Bb = Bt + (size_t)(bn + w * 16 + r) * K + koff;

    auto stage = [&](int p, int k0) {
        bf16* base = smem + p * BUFE;
        bf16* Asb = base + w * 16 * 32;
        bf16* Bsb = base + ASZ + w * 16 * 32;
#pragma unroll
        for (int it = 0; it < AIT; ++it)
            gload16(Ab + (size_t)(it * 64) * K + k0, Asb + it * 64 * 32);
#pragma unroll
        for (int it = 0; it < 2; ++it)
            gload16(Bb + (size_t)(it * 64) * K + k0, Bsb + it * 64 * 32);
    };

    stage(0, 0);
    stage(1, 32);
    waitcnt_vm<STG>();        // buf0 landed (stage1 still in flight)
    __builtin_amdgcn_s_barrier();
    int cur = 0;

    for (int k0 = 0; k0 < K; k0 += 32) {
        const bf16* Ac = smem + cur * BUFE;
        const bf16* Bc = Ac + ASZ;
        bf16x8 af[MF], bfv[NF];
#pragma unroll
        for (int m = 0; m < MF; ++m) {
            int row = wr * (BM / 2) + m * 16 + l15;
            int gs = g ^ ((row >> 1) & 3);            // read-side swizzle
            af[m] = *(const bf16x8*)&Ac[row * 32 + gs * 8];
        }
#pragma unroll
        for (int n = 0; n < NF; ++n) {
            int row = wc * 64 + n * 16 + l15;
            int gs = g ^ ((row >> 1) & 3);
            bfv[n] = *(const bf16x8*)&Bc[row * 32 + gs * 8];
        }
        bool st = (k0 + 64 < K);
        if (st) {
            int nxt = cur + 2; if (nxt >= 3) nxt -= 3;
            stage(nxt, k0 + 64);                      // lands ~2 K-steps later
        }
#pragma unroll
        for (int m = 0; m < MF; ++m)
#pragma unroll
            for (int n = 0; n < NF; ++n)
                acc[m][n] = __builtin_amdgcn_mfma_f32_16x16x32_bf16(af[m], bfv[n], acc[m][n], 0, 0, 0);
        if (st) waitcnt_vm<STG>();    // prev stage landed; this one stays in flight
        else    waitcnt_vm<0>();
        __builtin_amdgcn_s_barrier();
        cur = (cur == 2) ? 0 : cur + 1;
    }

    int lq = g * 4;
#pragma unroll
    for (int m = 0; m < MF; ++m) {
#pragma unroll
        for (int n = 0; n < NF; ++n) {
            int col = bn + wc * 64 + n * 16 + l15;
            float bv = bias[col];
            if (EPI == 4 && col >= 2 * DD) {
                int row0 = bm + wr * (BM / 2) + m * 16 + lq;
                int b = row0 >> 10, t0 = row0 & 1023;
                int hd = col - 2 * DD;
                union { bf16 h[4]; unsigned long long u; } pk;
#pragma unroll
                for (int j = 0; j < 4; ++j) pk.h[j] = (bf16)(acc[m][n][j] + bv);
                *(unsigned long long*)&vtout[((size_t)(b * DD + hd)) * TT + t0] = pk.u;
            } else {
#pragma unroll
                for (int j = 0; j < 4; ++j) {
                    int row = bm + wr * (BM / 2) + m * 16 + lq + j;
                    float v = acc[m][n][j] + bv;
                    if (EPI == 2) {
                        ((float*)Cout)[(size_t)row * N + col] = v + res[(size_t)row * N + col];
                    } else if (EPI == 3) {
                        v = 0.5f * v * (1.f + erff(v * 0.70710678118654752f));
                        ((bf16*)Cout)[(size_t)row * N + col] = (bf16)v;
                    } else if (EPI == 1) {
                        ((bf16*)Cout)[(size_t)row * N + col] = (bf16)v;
                    } else { // EPI == 4 Q/K columns
                        if (col < DD) v *= 0.125f;
                        ((bf16*)Cout)[(size_t)row * N + col] = (bf16)v;
                    }
                }
            }
        }
    }
}

// ---------------- LM head GEMM: 256x256, BK=32, 4-buffer, 4-phase interleave ----
// C[2048][32000] f32 = A[2048][768] @ Bt[32000][768]^T. 512 thr / 8 waves (2Mx4N).
// Per K-step t (buf t&3), 4 phases, each:
//   {ds_read 2 A-frags (+4 B-frags in ph0) -> issue 1 stage gload for buf (t+3)&3
//    -> s_barrier -> lgkmcnt(0)+sched_barrier(0) -> setprio(1) 8 MFMA setprio(0)
//    -> s_barrier}; vmcnt(8) only at end of ph3 (stage t+1 landed, 8 in flight).
// Swizzle: 16B chunk c of row r at c ^ ((r>>1)&3); source pre-swizzled (rule #21).
__global__ __launch_bounds__(512, 2) void lmgemm(const bf16* __restrict__ A,
                                                 const bf16* __restrict__ Bt,
                                                 float* __restrict__ C) {
    constexpr int ABUF = 256 * 32;           // A elements per buffer (16KB)
    constexpr int BUFE = 2 * ABUF;           // A+B per buffer (32KB)
    __shared__ __align__(16) bf16 smem[4 * BUFE];   // 128 KiB
    const int tid = threadIdx.x;
    const int w = tid >> 6, lane = tid & 63;
    const int wm = w >> 2, wn = w & 3;
    const int l15 = lane & 15, g = lane >> 4;
    const int bm = blockIdx.x * 256;
    const int bn = blockIdx.y * 256;

    const int fcol = (g ^ ((l15 >> 1) & 3)) * 8;     // read-side swizzled chunk

    const int rA = lane >> 2;
    const int csw = ((lane & 3) ^ ((lane >> 3) & 3)) * 8;   // inverse-swizzled source col
    const bf16* a0 = A  + (size_t)(bm + w * 16 + rA) * DD + csw;
    const bf16* b0 = Bt + (size_t)(bn + w * 16 + rA) * DD + csw;
    const int ld0 = (w * 16) * 32;           // wave-uniform LDS elem offsets
    const int ld1 = (w * 16 + 128) * 32;

    f32x4 acc[8][4];
#pragma unroll
    for (int m = 0; m < 8; ++m)
#pragma unroll
        for (int n = 0; n < 4; ++n) acc[m][n] = (f32x4){0.f, 0.f, 0.f, 0.f};

    auto stagef = [&](int p, int kelem) {
        bf16* base = smem + p * BUFE;
        gload16(a0 + kelem, base + ld0);
        gload16(a0 + (size_t)128 * DD + kelem, base + ld1);
        gload16(b0 + kelem, base + ABUF + ld0);
        gload16(b0 + (size_t)128 * DD + kelem, base + ABUF + ld1);
    };

    stagef(0, 0);
    stagef(1, 32);
    stagef(2, 64);
    waitcnt_vm<8>();                 // buf0 landed (8 loads still in flight)
    __builtin_amdgcn_s_barrier();

#define LDA(m) (*(const bf16x8*)&Ar[(wm * 128 + (m) * 16 + l15) * 32 + fcol])
#define LDB(n) (*(const bf16x8*)&Br[(wn * 64 + (n) * 16 + l15) * 32 + fcol])
#define WAIT_LGKM0 do { asm volatile("s_waitcnt lgkmcnt(0)" ::: "memory"); \
                        __builtin_amdgcn_sched_barrier(0); } while (0)
#define MFMA8(i, j) do { __builtin_amdgcn_s_setprio(1); \
    _Pragma("unroll") \
    for (int n = 0; n < 4; ++n) { \
        acc[i][n] = __builtin_amdgcn_mfma_f32_16x16x32_bf16(af0, bfv[n], acc[i][n], 0, 0, 0); \
        acc[j][n] = __builtin_amdgcn_mfma_f32_16x16x32_bf16(af1, bfv[n], acc[j][n], 0, 0, 0); } \
    __builtin_amdgcn_s_setprio(0); } while (0)

    for (int t = 0; t < 21; ++t) {
        const bf16* Ar = smem + (t & 3) * BUFE;
        const bf16* Br = Ar + ABUF;
        bf16* nb = smem + ((t + 3) & 3) * BUFE;
        const int kel = (t + 3) * 32;
        bf16x8 af0, af1, bfv[4];
        // ---- phase 0: all B-frags + A m0,m1; stage gload 1/4 ----
        bfv[0] = LDB(0); bfv[1] = LDB(1); bfv[2] = LDB(2); bfv[3] = LDB(3);
        af0 = LDA(0); af1 = LDA(1);
        gload16(a0 + kel, nb + ld0);
        __builtin_amdgcn_s_barrier();
        WAIT_LGKM0;
        MFMA8(0, 1);
        __builtin_amdgcn_s_barrier();
        // ---- phase 1: A m2,m3; stage gload 2/4 ----
        af0 = LDA(2); af1 = LDA(3);
        gload16(a0 + (size_t)128 * DD + kel, nb + ld1);
        __builtin_amdgcn_s_barrier();
        WAIT_LGKM0;
        MFMA8(2, 3);
        __builtin_amdgcn_s_barrier();
        // ---- phase 2: A m4,m5; stage gload 3/4 ----
        af0 = LDA(4); af1 = LDA(5);
        gload16(b0 + kel, nb + ABUF + ld0);
        __builtin_amdgcn_s_barrier();
        WAIT_LGKM0;
        MFMA8(4, 5);
        __builtin_amdgcn_s_barrier();
        // ---- phase 3: A m6,m7; stage gload 4/4; counted vmcnt ----
        af0 = LDA(6); af1 = LDA(7);
        gload16(b0 + (size_t)128 * DD + kel, nb + ABUF + ld1);
        __builtin_amdgcn_s_barrier();
        WAIT_LGKM0;
        MFMA8(6, 7);
        waitcnt_vm<8>();             // stage t+1 landed; t+2,t+3 stay in flight
        __builtin_amdgcn_s_barrier();
    }
    waitcnt_vm<0>();                 // all remaining stages landed
    __builtin_amdgcn_s_barrier();
#pragma unroll
    for (int t = 21; t < 24; ++t) {  // tail: all data resident, no barriers
        const bf16* Ar = smem + (t & 3) * BUFE;
        const bf16* Br = Ar + ABUF;
        bf16x8 af[8], bfv[4];
#pragma unroll
        for (int m = 0; m < 8; ++m) af[m] = LDA(m);
#pragma unroll
        for (int n = 0; n < 4; ++n) bfv[n] = LDB(n);
#pragma unroll
        for (int m = 0; m < 8; ++m)
#pragma unroll
            for (int n = 0; n < 4; ++n)
                acc[m][n] = __builtin_amdgcn_mfma_f32_16x16x32_bf16(af[m], bfv[n], acc[m][n], 0, 0, 0);
    }
#undef LDA
#undef LDB
#undef WAIT_LGKM0
#undef MFMA8

    __syncthreads();                 // staging region now safe to reuse
    // epilogue: per-wave LDS transpose, contiguous float4 stores
    float* eb = (float*)smem + w * (16 * 68);
    const int rr = lane >> 2, c0 = (lane & 3) * 16;
#pragma unroll
    for (int mf = 0; mf < 8; ++mf) {
#pragma unroll
        for (int n = 0; n < 4; ++n)
#pragma unroll
            for (int j = 0; j < 4; ++j)
                eb[(g * 4 + j) * 68 + n * 16 + l15] = acc[mf][n][j];
        __syncthreads();
        const float* src = &eb[rr * 68 + c0];
        float* dst = C + (size_t)(bm + wm * 128 + mf * 16 + rr) * 32000 + bn + wn * 64 + c0;
        *(float4*)(dst + 0)  = *(const float4*)(src + 0);
        *(float4*)(dst + 4)  = *(const float4*)(src + 4);
        *(float4*)(dst + 8)  = *(const float4*)(src + 8);
        *(float4*)(dst + 12) = *(const float4*)(src + 12);
        __syncthreads();
    }
}

// ---------------- MFMA flash attention ----------------
__global__ __launch_bounds__(256) void fattn_kernel(const bf16* __restrict__ qkv,
                                                    const bf16* __restrict__ vt,
                                                    bf16* __restrict__ o) {
    const int bh = blockIdx.y;
    const int b = bh / HH, h = bh % HH;
    const int qc = gridDim.x - 1 - blockIdx.x;   // longest blocks dispatch first
    const int q0 = qc * 64;
    const int tid = threadIdx.x;
    const int w = tid >> 6, lane = tid & 63;
    const int l15 = lane & 15, g = lane >> 4;

    __shared__ __align__(16) bf16 Ks[64 * 64];
    __shared__ __align__(16) bf16 Vs[64 * 64];
    __shared__ __align__(16) bf16 Ps[4][16 * 64];

    const size_t basebt = (size_t)b * TT;
    const int qw = q0 + w * 16;
    const int qg = qw + l15;

    bf16x8 bq0, bq1;
    {
        const bf16* qp = qkv + (basebt + qw + l15) * 2304 + h * 64 + g * 8;
        bq0 = *(const bf16x8*)(qp);
        bq1 = *(const bf16x8*)(qp + 32);
    }

    float mstate = -1e30f, lstate = 0.f;
    f32x4 oacc[4];
#pragma unroll
    for (int nf = 0; nf < 4; ++nf) oacc[nf] = (f32x4){0.f, 0.f, 0.f, 0.f};

    const int swzA = (l15 & 7) << 4;
    char* const psBase = (char*)&Ps[w][0];

    const int nchunk = qc + 1;
    for (int c = 0; c < nchunk; ++c) {
        const int kc = c * 64;
        __syncthreads();
        {
            int r0 = tid >> 3;
            int e0 = (tid & 7) * 8;
#pragma unroll
            for (int i = 0; i < 2; ++i) {
                int r = r0 + 32 * i;
                int swzW = (r & 7) << 4;
                bf16x8 kv = *(const bf16x8*)&qkv[(basebt + kc + r) * 2304 + DD + h * 64 + e0];
                *(bf16x8*)((char*)Ks + r * 128 + ((e0 * 2) ^ swzW)) = kv;
                bf16x8 vv = *(const bf16x8*)&vt[((size_t)bh * 64 + r) * TT + kc + e0];
                *(bf16x8*)((char*)Vs + r * 128 + ((e0 * 2) ^ swzW)) = vv;
            }
        }
        __syncthreads();
        if (kc > qw + 15) continue;

        f32x4 s[4];
        __builtin_amdgcn_s_setprio(1);
#pragma unroll
        for (int mf = 0; mf < 4; ++mf) {
            char* kr = (char*)Ks + (16 * mf + l15) * 128;
            bf16x8 ka0 = *(const bf16x8*)(kr + ((16 * g) ^ swzA));
            bf16x8 ka1 = *(const bf16x8*)(kr + ((64 + 16 * g) ^ swzA));
            f32x4 a = (f32x4){0.f, 0.f, 0.f, 0.f};
            a = __builtin_amdgcn_mfma_f32_16x16x32_bf16(ka0, bq0, a, 0, 0, 0);
            a = __builtin_amdgcn_mfma_f32_16x16x32_bf16(ka1, bq1, a, 0, 0, 0);
            s[mf] = a;
        }
        __builtin_amdgcn_s_setprio(0);
        if (kc + 63 > qw) {
#pragma unroll
            for (int mf = 0; mf < 4; ++mf)
#pragma unroll
                for (int j = 0; j < 4; ++j)
                    if (kc + 16 * mf + 4 * g + j > qg) s[mf][j] = -1e30f;
        }
        float cm = -1e30f;
#pragma unroll
        for (int mf = 0; mf < 4; ++mf)
#pragma unroll
            for (int j = 0; j < 4; ++j) cm = fmaxf(cm, s[mf][j]);
        cm = fmaxf(cm, __shfl_xor(cm, 16));
        cm = fmaxf(cm, __shfl_xor(cm, 32));
        float mnew = fmaxf(mstate, cm);
        float sc = __expf(mstate - mnew);
        mstate = mnew;
        float p[4][4];
        float psum = 0.f;
#pragma unroll
        for (int mf = 0; mf < 4; ++mf)
#pragma unroll
            for (int j = 0; j < 4; ++j) { float pv = __expf(s[mf][j] - mnew); p[mf][j] = pv; psum += pv; }
        psum += __shfl_xor(psum, 16);
        psum += __shfl_xor(psum, 32);
        lstate = lstate * sc + psum;
#pragma unroll
        for (int mf = 0; mf < 4; ++mf) {
            unsigned lo = pack_bf16x2(p[mf][0], p[mf][1]);
            unsigned hi = pack_bf16x2(p[mf][2], p[mf][3]);
            char* dst = psBase + l15 * 128 + ((32 * mf + 8 * g) ^ swzA);
            *(unsigned*)dst = lo;
            *(unsigned*)(dst + 4) = hi;
        }
        float s0 = __shfl(sc, 4 * g + 0), s1 = __shfl(sc, 4 * g + 1);
        float s2 = __shfl(sc, 4 * g + 2), s3 = __shfl(sc, 4 * g + 3);
#pragma unroll
        for (int nf = 0; nf < 4; ++nf) {
            oacc[nf][0] *= s0; oacc[nf][1] *= s1; oacc[nf][2] *= s2; oacc[nf][3] *= s3;
        }
        bf16x8 pa0 = *(const bf16x8*)(psBase + l15 * 128 + ((16 * g) ^ swzA));
        bf16x8 pa1 = *(const bf16x8*)(psBase + l15 * 128 + ((64 + 16 * g) ^ swzA));
        __builtin_amdgcn_s_setprio(1);
#pragma unroll
        for (int nf = 0; nf < 4; ++nf) {
            char* vr = (char*)Vs + (16 * nf + l15) * 128;
            bf16x8 vb0 = *(const bf16x8*)(vr + ((16 * g) ^ swzA));
            bf16x8 vb1 = *(const bf16x8*)(vr + ((64 + 16 * g) ^ swzA));
            oacc[nf] = __builtin_amdgcn_mfma_f32_16x16x32_bf16(pa0, vb0, oacc[nf], 0, 0, 0);
            oacc[nf] = __builtin_amdgcn_mfma_f32_16x16x32_bf16(pa1, vb1, oacc[nf], 0, 0, 0);
        }
        __builtin_amdgcn_s_setprio(0);
    }
    float linv = 1.f / lstate;
    float l0 = __shfl(linv, 4 * g + 0), l1 = __shfl(linv, 4 * g + 1);
    float l2 = __shfl(linv, 4 * g + 2), l3 = __shfl(linv, 4 * g + 3);
    float lj[4] = {l0, l1, l2, l3};
#pragma unroll
    for (int j = 0; j < 4; ++j) {
        bf16* orow = o + (size_t)(basebt + qw + 4 * g + j) * DD + h * 64 + l15;
#pragma unroll
        for (int nf = 0; nf < 4; ++nf)
            orow[16 * nf] = (bf16)(oacc[nf][j] * lj[j]);
    }
}

// ---------------- launcher ----------------
extern "C" void kernel_launch(void* const* d_in, const int* in_sizes, int n_in,
                              void* d_out, int out_size, void* d_ws, size_t ws_size,
                              hipStream_t stream) {
    (void)in_sizes; (void)n_in; (void)out_size; (void)ws_size;
    const int*   idx  = (const int*)d_in[0];
    const float* tok  = (const float*)d_in[1];
    const float* pos  = (const float*)d_in[2];
    const float* Wqkv = (const float*)d_in[3];
    const float* bqkv = (const float*)d_in[4];
    const float* Wo   = (const float*)d_in[5];
    const float* bo   = (const float*)d_in[6];
    const float* ln1g = (const float*)d_in[7];
    const float* ln1b = (const float*)d_in[8];
    const float* ln2g = (const float*)d_in[9];
    const float* ln2b = (const float*)d_in[10];
    const float* W1   = (const float*)d_in[11];
    const float* b1   = (const float*)d_in[12];
    const float* W2   = (const float*)d_in[13];
    const float* b2   = (const float*)d_in[14];
    const float* lnfg = (const float*)d_in[15];
    const float* lnfb = (const float*)d_in[16];
    const float* Wlm  = (const float*)d_in[17];
    float* out = (float*)d_out;

    char* ws = (char*)d_ws;
    float* x     = (float*)(ws);                       // 6,291,456
    bf16*  abuf0 = (bf16*)(ws + 6291456);              // 3,145,728
    bf16*  abuf1 = (bf16*)(ws + 9437184);              // 12,582,912
    bf16*  qkvb  = (bf16*)(ws + 22020096);             // 9,437,184
    bf16*  vtb   = (bf16*)(ws + 31457280);             // 3,145,728
    bf16*  wbuf  = (bf16*)(ws + 34603008);             // 49,152,000

    bf16* wq = wbuf;              // 2304x768
    bf16* wo = wbuf + 1769472;    // 768x768
    bf16* w1 = wbuf + 2359296;    // 3072x768
    bf16* w2 = wbuf + 4718592;    // 768x3072

    embed_kernel<<<NTOK, 256, 0, stream>>>(idx, tok, pos, x);

    for (int l = 0; l < LLAY; ++l) {
        convT4_kernel<<<6912, 256, 0, stream>>>(
            Wqkv + (size_t)l * DD * 3 * DD, Wo + (size_t)l * DD * DD,
            W1 + (size_t)l * DD * DFFN, W2 + (size_t)l * DFFN * DD,
            wq, wo, w1, w2);
        ln_kernel<<<NTOK / 4, 256, 0, stream>>>(x, ln1g + l * DD, ln1b + l * DD, abuf0);
        mgemm<128, 4><<<dim3(3 * DD / 128, NTOK / 128), 256, 0, stream>>>(
            abuf0, wq, bqkv + (size_t)l * 3 * DD, nullptr, qkvb, vtb, NTOK, 3 * DD, DD);
        fattn_kernel<<<dim3(TT / 64, BB * HH), 256, 0, stream>>>(qkvb, vtb, abuf0);
        mgemm<64, 2><<<dim3(DD / 128, NTOK / 64), 256, 0, stream>>>(
            abuf0, wo, bo + (size_t)l * DD, x, x, nullptr, NTOK, DD, DD);
        ln_kernel<<<NTOK / 4, 256, 0, stream>>>(x, ln2g + l * DD, ln2b + l * DD, abuf0);
        mgemm<128, 3><<<dim3(DFFN / 128, NTOK / 128), 256, 0, stream>>>(
            abuf0, w1, b1 + (size_t)l * DFFN, nullptr, abuf1, nullptr, NTOK, DFFN, DD);
        mgemm<64, 2><<<dim3(DD / 128, NTOK / 64), 256, 0, stream>>>(
            abuf1, w2, b2 + (size_t)l * DD, x, x, nullptr, NTOK, DD, DFFN);
    }
    ln_kernel<<<NTOK / 4, 256, 0, stream>>>(x, lnfg, lnfb, abuf0);
    convT_kernel<<<dim3(32000 / 32, DD / 32), 256, 0, stream>>>(Wlm, wbuf, DD, 32000);
    lmgemm<<<dim3(NTOK / 256, 32000 / 256), 512, 0, stream>>>(abuf0, wbuf, out);
}